// Round 1
// baseline (214.653 us; speedup 1.0000x reference)
//
#include <hip/hip_runtime.h>

// ---------------- problem constants ----------------
#define DM    1024          // d_model
#define NEXP  8             // experts
#define BTOK  8192          // tokens
#define KTOP  2             // routes per token
#define NASSIGN (BTOK*KTOP) // 16384
#define CAPC  1280          // capacity (10 * 128 -> tile-aligned)
#define TILES_PER_EXP (CAPC/128)
#define MROWS (NEXP*CAPC)   // 10240 expert rows

typedef unsigned short ushort_t;
typedef __attribute__((ext_vector_type(8))) __bf16 bf16x8;
typedef __attribute__((ext_vector_type(4))) float  f32x4;

__device__ __forceinline__ ushort_t f2b(float f) {  // f32 -> bf16 RNE
  union { float f; unsigned u; } a; a.f = f;
  unsigned u = a.u;
  return (ushort_t)((u + 0x7FFFu + ((u >> 16) & 1u)) >> 16);
}
__device__ __forceinline__ float b2f(ushort_t h) {
  union { unsigned u; float f; } a; a.u = ((unsigned)h) << 16;
  return a.f;
}

#define GLOAD_LDS(g, l) __builtin_amdgcn_global_load_lds( \
    (const __attribute__((address_space(1))) void*)(g),   \
    (__attribute__((address_space(3))) void*)(l), 16, 0, 0)

// ---------------- init: slot_of = -1, nfb = 0 ----------------
__global__ void init_kernel(int* __restrict__ slot, int* __restrict__ nfb) {
  int i = blockIdx.x * 256 + threadIdx.x;
  if (i < NASSIGN) slot[i] = -1;
  if (i == 0) *nfb = 0;
}

// ---------------- routing: exact sequential capacity semantics ----------------
// One block per expert. Scan assignments in flattened (token-major, slot-minor)
// order; accept iff (# earlier assignments to this expert) < capacity.
__global__ void route_kernel(const int* __restrict__ routes, const int* __restrict__ capp,
                             int* __restrict__ gidx, int* __restrict__ slot,
                             int* __restrict__ counts) {
  const int e = blockIdx.x;
  const int t = threadIdx.x, lane = t & 63, w = t >> 6;
  int cap = *capp; if (cap > CAPC) cap = CAPC;
  __shared__ int wtot[4];
  int base = 0;
  for (int i0 = 0; i0 < NASSIGN; i0 += 256) {
    int i = i0 + t;
    int r = routes[i];
    bool mine = (r == e);
    unsigned long long mask = __ballot(mine);
    int pre = __popcll(mask & ((1ull << lane) - 1ull));
    if (lane == 0) wtot[w] = __popcll(mask);
    __syncthreads();
    int tot = 0;
#pragma unroll
    for (int j = 0; j < 4; ++j) { int c = wtot[j]; if (j < w) pre += c; tot += c; }
    if (mine) {
      int pos = base + pre;
      if (pos < cap) { gidx[e * CAPC + pos] = i >> 1; slot[i] = e * CAPC + pos; }
      // else: stays -1 (rejected)
    }
    base += tot;
    __syncthreads();
  }
  if (t == 0) counts[e] = base < cap ? base : cap;
}

// ---------------- build fallback token list (used==0) ----------------
__global__ void fb_list_kernel(const int* __restrict__ slot, int* __restrict__ fbidx,
                               int* __restrict__ nfb) {
  int t = blockIdx.x * 256 + threadIdx.x;
  if (t >= BTOK) return;
  int u = (slot[2 * t] >= 0) + (slot[2 * t + 1] >= 0);
  if (u == 0) { int p = atomicAdd(nfb, 1); fbidx[p] = t; }
}

// ---------------- f32 -> bf16 convert ----------------
__global__ void cvt_kernel(const float* __restrict__ s, ushort_t* __restrict__ d, int n4) {
  int i = blockIdx.x * 256 + threadIdx.x;
  if (i >= n4) return;
  float4 v = ((const float4*)s)[i];
  ushort4 o; o.x = f2b(v.x); o.y = f2b(v.y); o.z = f2b(v.z); o.w = f2b(v.w);
  ((ushort4*)d)[i] = o;
}

// ---------------- gather accepted token rows -> xg (bf16), zero padding ----------------
__global__ void gather_xg_kernel(const float* __restrict__ x, const int* __restrict__ gidx,
                                 const int* __restrict__ counts, ushort_t* __restrict__ xg) {
  int row = blockIdx.x;                 // 0..MROWS-1
  int e = row / CAPC, p = row % CAPC;
  int d = threadIdx.x * 4;
  ushort4 o = {0, 0, 0, 0};
  if (p < counts[e]) {
    int tok = gidx[row];
    float4 v = *(const float4*)(x + (size_t)tok * DM + d);
    o.x = f2b(v.x); o.y = f2b(v.y); o.z = f2b(v.z); o.w = f2b(v.w);
  }
  *(ushort4*)(xg + (size_t)row * DM + d) = o;
}

// ---------------- gather fallback token rows -> xf (bf16), zero pad to 128 ----------------
__global__ void gather_xf_kernel(const float* __restrict__ x, const int* __restrict__ fbidx,
                                 const int* __restrict__ nfbp, ushort_t* __restrict__ xf) {
  int row = blockIdx.x;                 // 0..BTOK-1
  int n = *nfbp;
  int nr = (n + 127) & ~127;
  if (row >= nr) return;
  int d = threadIdx.x * 4;
  ushort4 o = {0, 0, 0, 0};
  if (row < n) {
    int tok = fbidx[row];
    float4 v = *(const float4*)(x + (size_t)tok * DM + d);
    o.x = f2b(v.x); o.y = f2b(v.y); o.z = f2b(v.z); o.w = f2b(v.w);
  }
  *(ushort4*)(xf + (size_t)row * DM + d) = o;
}

// ---------------- bf16 GEMM: C[m,n] = sum_k A[m,k]*W[n,k] + bias[n] ----------------
// m97 structure: 128x128 tile, BK=32, 4 waves (2x2), 4x4 16x16x32 frags/wave,
// global_load_lds width-16 staging, linear LDS [128][32].
#define BM 128
#define BN 128
#define BK 32

template <int RELU, int SCATTER>
__global__ __launch_bounds__(256, 2) void gemm_bt(
    const ushort_t* __restrict__ A, const ushort_t* __restrict__ W,
    const float* __restrict__ bias, ushort_t* __restrict__ Cb,
    float* __restrict__ outF, const int* __restrict__ scat,
    const int* __restrict__ nrows_ptr, int tiles_per_exp) {
  if (nrows_ptr && (int)(blockIdx.x * BM) >= *nrows_ptr) return;  // fb early-exit
  const int e = tiles_per_exp ? (int)blockIdx.x / tiles_per_exp : 0;
  const int tid = threadIdx.x, lane = tid & 63, w = tid >> 6;
  const int wr = w >> 1, wc = w & 1;
  __shared__ ushort_t lA[BM * BK];
  __shared__ ushort_t lB[BN * BK];
  const size_t Abase = (size_t)blockIdx.x * BM * DM;
  const size_t Wbase = (size_t)e * DM * DM + (size_t)blockIdx.y * BN * DM;
  f32x4 acc[4][4] = {};

  const int srow = lane >> 2;        // 0..15 within 16-row chunk
  const int scol = (lane & 3) * 8;   // k-offset in elements (16B each)

  for (int kt = 0; kt < DM; kt += BK) {
#pragma unroll
    for (int j = 0; j < 2; ++j) {
      int ch = w * 2 + j;            // 8 chunks of 16 rows
      int row = ch * 16 + srow;
      GLOAD_LDS(A + Abase + (size_t)row * DM + kt + scol, &lA[ch * 16 * BK]);
      GLOAD_LDS(W + Wbase + (size_t)row * DM + kt + scol, &lB[ch * 16 * BK]);
    }
    __syncthreads();   // drains vmcnt for global_load_lds
    bf16x8 av[4], bv[4];
    const int ko = (lane >> 4) * 8;
#pragma unroll
    for (int m = 0; m < 4; ++m)
      av[m] = *(const bf16x8*)&lA[(wr * 64 + m * 16 + (lane & 15)) * BK + ko];
#pragma unroll
    for (int n = 0; n < 4; ++n)
      bv[n] = *(const bf16x8*)&lB[(wc * 64 + n * 16 + (lane & 15)) * BK + ko];
#pragma unroll
    for (int m = 0; m < 4; ++m)
#pragma unroll
      for (int n = 0; n < 4; ++n)
        acc[m][n] = __builtin_amdgcn_mfma_f32_16x16x32_bf16(av[m], bv[n], acc[m][n], 0, 0, 0);
    __syncthreads();
  }

  // epilogue: C/D layout col=lane&15, row=(lane>>4)*4+reg  [m89-verified]
  int nrows = nrows_ptr ? *nrows_ptr : 0x7fffffff;
#pragma unroll
  for (int n = 0; n < 4; ++n) {
    int col = blockIdx.y * BN + wc * 64 + n * 16 + (lane & 15);
    float bb = bias[e * DM + col];
#pragma unroll
    for (int m = 0; m < 4; ++m) {
      int row0 = blockIdx.x * BM + wr * 64 + m * 16 + (lane >> 4) * 4;
#pragma unroll
      for (int r = 0; r < 4; ++r) {
        float v = acc[m][n][r] + bb;
        if (RELU) v = v > 0.0f ? v : 0.0f;
        int row = row0 + r;
        if (SCATTER) {
          if (row < nrows) outF[(size_t)scat[row] * DM + col] = v;
        } else {
          Cb[(size_t)row * DM + col] = f2b(v);
        }
      }
    }
  }
}

// ---------------- combine accepted expert outputs per token ----------------
__global__ void combine_kernel(const ushort_t* __restrict__ Y, const int* __restrict__ slot,
                               float* __restrict__ out) {
  int t = blockIdx.x;
  int s0 = slot[2 * t], s1 = slot[2 * t + 1];
  int u = (s0 >= 0) + (s1 >= 0);
  if (u == 0) return;  // fallback GEMM writes these rows
  int d = threadIdx.x * 4;
  float a0 = 0, a1 = 0, a2 = 0, a3 = 0;
  if (s0 >= 0) {
    ushort4 q = *(const ushort4*)(Y + (size_t)s0 * DM + d);
    a0 += b2f(q.x); a1 += b2f(q.y); a2 += b2f(q.z); a3 += b2f(q.w);
  }
  if (s1 >= 0) {
    ushort4 q = *(const ushort4*)(Y + (size_t)s1 * DM + d);
    a0 += b2f(q.x); a1 += b2f(q.y); a2 += b2f(q.z); a3 += b2f(q.w);
  }
  float inv = 1.0f / (float)u;
  float4 o = make_float4(a0 * inv, a1 * inv, a2 * inv, a3 * inv);
  *(float4*)(out + (size_t)t * DM + d) = o;
}

// ---------------- launch ----------------
extern "C" void kernel_launch(void* const* d_in, const int* in_sizes, int n_in,
                              void* d_out, int out_size, void* d_ws, size_t ws_size,
                              hipStream_t stream) {
  const float* x   = (const float*)d_in[0];
  const float* W1  = (const float*)d_in[1];
  const float* b1  = (const float*)d_in[2];
  const float* W2  = (const float*)d_in[3];
  const float* b2  = (const float*)d_in[4];
  const float* Wf1 = (const float*)d_in[5];
  const float* bf1 = (const float*)d_in[6];
  const float* Wf2 = (const float*)d_in[7];
  const float* bf2 = (const float*)d_in[8];
  const int* routes = (const int*)d_in[9];
  const int* capp   = (const int*)d_in[10];
  float* out = (float*)d_out;

  char* ws = (char*)d_ws;
  size_t off = 0;
  auto alloc = [&](size_t bytes) -> void* {
    void* p = ws + off; off += (bytes + 255) & ~255ull; return p;
  };
  ushort_t* W1b  = (ushort_t*)alloc((size_t)NEXP * DM * DM * 2);
  ushort_t* W2b  = (ushort_t*)alloc((size_t)NEXP * DM * DM * 2);
  ushort_t* Wf1b = (ushort_t*)alloc((size_t)DM * DM * 2);
  ushort_t* Wf2b = (ushort_t*)alloc((size_t)DM * DM * 2);
  ushort_t* xg   = (ushort_t*)alloc((size_t)MROWS * DM * 2);
  ushort_t* H    = (ushort_t*)alloc((size_t)MROWS * DM * 2);
  ushort_t* Y    = (ushort_t*)alloc((size_t)MROWS * DM * 2);
  ushort_t* xf   = (ushort_t*)alloc((size_t)BTOK * DM * 2);
  ushort_t* Hf   = (ushort_t*)alloc((size_t)BTOK * DM * 2);
  int* gidx   = (int*)alloc(MROWS * 4);
  int* slot   = (int*)alloc(NASSIGN * 4);
  int* counts = (int*)alloc(NEXP * 4);
  int* fbidx  = (int*)alloc(BTOK * 4);
  int* nfb    = (int*)alloc(4);

  init_kernel<<<NASSIGN / 256, 256, 0, stream>>>(slot, nfb);
  route_kernel<<<NEXP, 256, 0, stream>>>(routes, capp, gidx, slot, counts);
  fb_list_kernel<<<BTOK / 256, 256, 0, stream>>>(slot, fbidx, nfb);
  cvt_kernel<<<(NEXP * DM * DM / 4 + 255) / 256, 256, 0, stream>>>(W1, W1b, NEXP * DM * DM / 4);
  cvt_kernel<<<(NEXP * DM * DM / 4 + 255) / 256, 256, 0, stream>>>(W2, W2b, NEXP * DM * DM / 4);
  cvt_kernel<<<(DM * DM / 4 + 255) / 256, 256, 0, stream>>>(Wf1, Wf1b, DM * DM / 4);
  cvt_kernel<<<(DM * DM / 4 + 255) / 256, 256, 0, stream>>>(Wf2, Wf2b, DM * DM / 4);
  gather_xg_kernel<<<MROWS, 256, 0, stream>>>(x, gidx, counts, xg);
  gather_xf_kernel<<<BTOK, 256, 0, stream>>>(x, fbidx, nfb, xf);

  dim3 ge(MROWS / BM, DM / BN);
  gemm_bt<1, 0><<<ge, 256, 0, stream>>>(xg, W1b, b1, H, nullptr, nullptr, nullptr, TILES_PER_EXP);
  gemm_bt<0, 0><<<ge, 256, 0, stream>>>(H, W2b, b2, Y, nullptr, nullptr, nullptr, TILES_PER_EXP);
  combine_kernel<<<BTOK, 256, 0, stream>>>(Y, slot, out);

  dim3 gf(BTOK / BM, DM / BN);
  gemm_bt<1, 0><<<gf, 256, 0, stream>>>(xf, Wf1b, bf1, Hf, nullptr, nullptr, nfb, 0);
  gemm_bt<0, 1><<<gf, 256, 0, stream>>>(Hf, Wf2b, bf2, nullptr, out, fbidx, nfb, 0);
}

// Round 2
// 209.949 us; speedup vs baseline: 1.0224x; 1.0224x over previous
//
#include <hip/hip_runtime.h>

// ---------------- problem constants ----------------
#define DM    1024          // d_model
#define NEXP  8             // experts
#define BTOK  8192          // tokens
#define KTOP  2             // routes per token
#define NASSIGN (BTOK*KTOP) // 16384
#define CAPC  1280          // capacity (10 * 128 -> tile-aligned)
#define TILES_PER_EXP (CAPC/128)
#define MROWS (NEXP*CAPC)   // 10240 expert rows

typedef unsigned short ushort_t;
typedef __attribute__((ext_vector_type(8))) __bf16 bf16x8;
typedef __attribute__((ext_vector_type(4))) float  f32x4;

__device__ __forceinline__ ushort_t f2b(float f) {  // f32 -> bf16 RNE
  union { float f; unsigned u; } a; a.f = f;
  unsigned u = a.u;
  return (ushort_t)((u + 0x7FFFu + ((u >> 16) & 1u)) >> 16);
}
__device__ __forceinline__ float b2f(ushort_t h) {
  union { unsigned u; float f; } a; a.u = ((unsigned)h) << 16;
  return a.f;
}

#define GLOAD_LDS(g, l) __builtin_amdgcn_global_load_lds( \
    (const __attribute__((address_space(1))) void*)(g),   \
    (__attribute__((address_space(3))) void*)(l), 16, 0, 0)

// ---------------- routing: exact sequential capacity semantics ----------------
// One 1024-thread block per expert. Scan assignments in flattened order;
// accept iff (# earlier valid assignments to this expert) < capacity.
// Writes slot[] for every assignment it owns (-1 if rejected).
__global__ void route_kernel(const int* __restrict__ routes, const int* __restrict__ capp,
                             int* __restrict__ gidx, int* __restrict__ slot,
                             int* __restrict__ counts, int* __restrict__ nfb) {
  const int e = blockIdx.x;
  const int t = threadIdx.x, lane = t & 63, w = t >> 6;
  int cap = *capp; if (cap > CAPC) cap = CAPC;
  if (e == 0 && t == 0) *nfb = 0;
  __shared__ int wtot[16];
  int base = 0;
  for (int i0 = 0; i0 < NASSIGN; i0 += 1024) {
    int i = i0 + t;
    int r = routes[i];
    bool mine = (r == e);
    unsigned long long mask = __ballot(mine);
    int pre = __popcll(mask & ((1ull << lane) - 1ull));
    if (lane == 0) wtot[w] = __popcll(mask);
    __syncthreads();
    int tot = 0;
#pragma unroll
    for (int j = 0; j < 16; ++j) { int c = wtot[j]; if (j < w) pre += c; tot += c; }
    if (e == 0 && (unsigned)r >= NEXP) slot[i] = -1;  // defensive (invalid route)
    if (mine) {
      int pos = base + pre;
      if (pos < cap) { gidx[e * CAPC + pos] = i >> 1; slot[i] = e * CAPC + pos; }
      else slot[i] = -1;
    }
    base += tot;
    __syncthreads();
  }
  if (t == 0) counts[e] = base < cap ? base : cap;
}

// ---------------- build fallback token list (used==0) ----------------
__global__ void fb_list_kernel(const int* __restrict__ slot, int* __restrict__ fbidx,
                               int* __restrict__ nfb) {
  int t = blockIdx.x * 256 + threadIdx.x;
  if (t >= BTOK) return;
  int u = (slot[2 * t] >= 0) + (slot[2 * t + 1] >= 0);
  if (u == 0) { int p = atomicAdd(nfb, 1); fbidx[p] = t; }
}

// ---------------- f32 -> bf16 convert, all four weight tensors in one launch ----------------
// W1: 8192 blocks, W2: 8192, Wf1: 1024, Wf2: 1024  (256 thr, 1 float4/thr)
__global__ void cvt_all_kernel(const float* __restrict__ W1, const float* __restrict__ W2,
                               const float* __restrict__ Wf1, const float* __restrict__ Wf2,
                               ushort_t* __restrict__ o1, ushort_t* __restrict__ o2,
                               ushort_t* __restrict__ of1, ushort_t* __restrict__ of2) {
  int b = blockIdx.x;
  const float* s; ushort_t* d; int idx;
  if (b < 8192)       { s = W1;  d = o1;  idx = b; }
  else if (b < 16384) { s = W2;  d = o2;  idx = b - 8192; }
  else if (b < 17408) { s = Wf1; d = of1; idx = b - 16384; }
  else                { s = Wf2; d = of2; idx = b - 17408; }
  int i = idx * 256 + threadIdx.x;
  float4 v = ((const float4*)s)[i];
  ushort4 o; o.x = f2b(v.x); o.y = f2b(v.y); o.z = f2b(v.z); o.w = f2b(v.w);
  ((ushort4*)d)[i] = o;
}

// ---------------- gather accepted token rows -> xg (bf16), zero padding ----------------
__global__ void gather_xg_kernel(const float* __restrict__ x, const int* __restrict__ gidx,
                                 const int* __restrict__ counts, ushort_t* __restrict__ xg) {
  int row = blockIdx.x;                 // 0..MROWS-1
  int e = row / CAPC, p = row % CAPC;
  int d = threadIdx.x * 4;
  ushort4 o = {0, 0, 0, 0};
  if (p < counts[e]) {
    int tok = gidx[row];
    float4 v = *(const float4*)(x + (size_t)tok * DM + d);
    o.x = f2b(v.x); o.y = f2b(v.y); o.z = f2b(v.z); o.w = f2b(v.w);
  }
  *(ushort4*)(xg + (size_t)row * DM + d) = o;
}

// ---------------- gather fallback token rows -> xf (bf16), zero pad to 128 ----------------
__global__ void gather_xf_kernel(const float* __restrict__ x, const int* __restrict__ fbidx,
                                 const int* __restrict__ nfbp, ushort_t* __restrict__ xf) {
  int row = blockIdx.x;                 // 0..BTOK-1
  int n = *nfbp;
  int nr = (n + 127) & ~127;
  if (row >= nr) return;
  int d = threadIdx.x * 4;
  ushort4 o = {0, 0, 0, 0};
  if (row < n) {
    int tok = fbidx[row];
    float4 v = *(const float4*)(x + (size_t)tok * DM + d);
    o.x = f2b(v.x); o.y = f2b(v.y); o.z = f2b(v.z); o.w = f2b(v.w);
  }
  *(ushort4*)(xf + (size_t)row * DM + d) = o;
}

// ---------------- bf16 GEMM: C[m,n] = sum_k A[m,k]*W[n,k] + bias[n] ----------------
// 128x128 tile, BK=32, 4 waves (2x2), 4x4 16x16x32 frags/wave.
// RING-4 deep prefetch: prologue stages 3 K-tiles; each iter: counted
// s_waitcnt vmcnt(8) -> raw s_barrier -> stage tile t+3 (into the buffer
// whose reads finished in iter t-1, i.e. before the barrier) -> ds_read ->
// setprio(1) + MFMA.  LDS k-slot XOR-swizzle (slot ^= (row>>1)&3) applied
// on BOTH the global source address (linear LDS dest, rule #21) and the
// ds_read address -> 2-way bank access (free).
#define BM 128
#define BN 128
#define BK 32
#define RING 4

template <int RELU, int SCATTER>
__global__ __launch_bounds__(256, 2) void gemm_bt(
    const ushort_t* __restrict__ A, const ushort_t* __restrict__ W,
    const float* __restrict__ bias, ushort_t* __restrict__ Cb,
    float* __restrict__ outF, const int* __restrict__ scat,
    const int* __restrict__ nrows_ptr, int tiles_per_exp) {
  if (nrows_ptr && (int)(blockIdx.x * BM) >= *nrows_ptr) return;  // fb early-exit
  const int e = tiles_per_exp ? (int)blockIdx.x / tiles_per_exp : 0;
  const int tid = threadIdx.x, lane = tid & 63, w = tid >> 6;
  const int wr = w >> 1, wc = w & 1;
  __shared__ ushort_t lA[RING][BM * BK];
  __shared__ ushort_t lB[RING][BN * BK];
  const size_t Abase = (size_t)blockIdx.x * BM * DM;
  const size_t Wbase = (size_t)e * DM * DM + (size_t)blockIdx.y * BN * DM;
  f32x4 acc[4][4] = {};

  // staging geometry: per K-tile, each operand = 8 segs of 1KB (16 rows x 32k);
  // wave w stages segs w*2, w*2+1 for both A and B (4 vmem instrs/wave/tile).
  const int sub  = lane >> 2;                         // row within seg, 0..15
  const int slt  = lane & 3;                          // 16B k-slot this lane fills
  const int gcol = (slt ^ ((sub >> 1) & 3)) * 8;      // inverse-swizzled global k-slot
  const int r0 = (w * 2)     * 16 + sub;
  const int r1 = (w * 2 + 1) * 16 + sub;

#define STAGE(T, BUF) do {                                                    \
    int kt_ = (T) * BK;                                                       \
    GLOAD_LDS(A + Abase + (size_t)r0 * DM + kt_ + gcol, &lA[BUF][(w*2)   * 512]); \
    GLOAD_LDS(A + Abase + (size_t)r1 * DM + kt_ + gcol, &lA[BUF][(w*2+1) * 512]); \
    GLOAD_LDS(W + Wbase + (size_t)r0 * DM + kt_ + gcol, &lB[BUF][(w*2)   * 512]); \
    GLOAD_LDS(W + Wbase + (size_t)r1 * DM + kt_ + gcol, &lB[BUF][(w*2+1) * 512]); \
  } while (0)

  const int fr    = lane & 15;
  const int rslot = ((lane >> 4) ^ ((fr >> 1) & 3)) * 8;  // swizzled read k-offset
  const int NT = DM / BK;  // 32

  STAGE(0, 0); STAGE(1, 1); STAGE(2, 2);   // 12 vmem instrs in flight

  for (int t = 0; t < NT; ++t) {
    // tile t landed  <=>  outstanding <= issued - 4*(t+1); steady state = 8
    if (t < NT - 2)       asm volatile("s_waitcnt vmcnt(8)" ::: "memory");
    else if (t == NT - 2) asm volatile("s_waitcnt vmcnt(4)" ::: "memory");
    else                  asm volatile("s_waitcnt vmcnt(0)" ::: "memory");
    __builtin_amdgcn_s_barrier();
    if (t + 3 < NT) STAGE(t + 3, (t + 3) & RING - 1);
    const ushort_t* bufA = lA[t & (RING - 1)];
    const ushort_t* bufB = lB[t & (RING - 1)];
    bf16x8 av[4], bv[4];
#pragma unroll
    for (int m = 0; m < 4; ++m)
      av[m] = *(const bf16x8*)&bufA[(wr * 64 + m * 16 + fr) * BK + rslot];
#pragma unroll
    for (int n = 0; n < 4; ++n)
      bv[n] = *(const bf16x8*)&bufB[(wc * 64 + n * 16 + fr) * BK + rslot];
    __builtin_amdgcn_s_setprio(1);
#pragma unroll
    for (int m = 0; m < 4; ++m)
#pragma unroll
      for (int n = 0; n < 4; ++n)
        acc[m][n] = __builtin_amdgcn_mfma_f32_16x16x32_bf16(av[m], bv[n], acc[m][n], 0, 0, 0);
    __builtin_amdgcn_s_setprio(0);
  }
#undef STAGE

  // epilogue: C/D layout col=lane&15, row=(lane>>4)*4+reg  [m89-verified]
  int nrows = nrows_ptr ? *nrows_ptr : 0x7fffffff;
#pragma unroll
  for (int n = 0; n < 4; ++n) {
    int col = blockIdx.y * BN + wc * 64 + n * 16 + (lane & 15);
    float bb = bias[e * DM + col];
#pragma unroll
    for (int m = 0; m < 4; ++m) {
      int row0 = blockIdx.x * BM + wr * 64 + m * 16 + (lane >> 4) * 4;
#pragma unroll
      for (int r = 0; r < 4; ++r) {
        float v = acc[m][n][r] + bb;
        if (RELU) v = v > 0.0f ? v : 0.0f;
        int row = row0 + r;
        if (SCATTER) {
          if (row < nrows) outF[(size_t)scat[row] * DM + col] = v;
        } else {
          Cb[(size_t)row * DM + col] = f2b(v);
        }
      }
    }
  }
}

// ---------------- combine accepted expert outputs per token ----------------
__global__ void combine_kernel(const ushort_t* __restrict__ Y, const int* __restrict__ slot,
                               float* __restrict__ out) {
  int t = blockIdx.x;
  int s0 = slot[2 * t], s1 = slot[2 * t + 1];
  int u = (s0 >= 0) + (s1 >= 0);
  if (u == 0) return;  // fallback GEMM writes these rows
  int d = threadIdx.x * 4;
  float a0 = 0, a1 = 0, a2 = 0, a3 = 0;
  if (s0 >= 0) {
    ushort4 q = *(const ushort4*)(Y + (size_t)s0 * DM + d);
    a0 += b2f(q.x); a1 += b2f(q.y); a2 += b2f(q.z); a3 += b2f(q.w);
  }
  if (s1 >= 0) {
    ushort4 q = *(const ushort4*)(Y + (size_t)s1 * DM + d);
    a0 += b2f(q.x); a1 += b2f(q.y); a2 += b2f(q.z); a3 += b2f(q.w);
  }
  float inv = 1.0f / (float)u;
  float4 o = make_float4(a0 * inv, a1 * inv, a2 * inv, a3 * inv);
  *(float4*)(out + (size_t)t * DM + d) = o;
}

// ---------------- launch ----------------
extern "C" void kernel_launch(void* const* d_in, const int* in_sizes, int n_in,
                              void* d_out, int out_size, void* d_ws, size_t ws_size,
                              hipStream_t stream) {
  const float* x   = (const float*)d_in[0];
  const float* W1  = (const float*)d_in[1];
  const float* b1  = (const float*)d_in[2];
  const float* W2  = (const float*)d_in[3];
  const float* b2  = (const float*)d_in[4];
  const float* Wf1 = (const float*)d_in[5];
  const float* bf1 = (const float*)d_in[6];
  const float* Wf2 = (const float*)d_in[7];
  const float* bf2 = (const float*)d_in[8];
  const int* routes = (const int*)d_in[9];
  const int* capp   = (const int*)d_in[10];
  float* out = (float*)d_out;

  char* ws = (char*)d_ws;
  size_t off = 0;
  auto alloc = [&](size_t bytes) -> void* {
    void* p = ws + off; off += (bytes + 255) & ~255ull; return p;
  };
  ushort_t* W1b  = (ushort_t*)alloc((size_t)NEXP * DM * DM * 2);
  ushort_t* W2b  = (ushort_t*)alloc((size_t)NEXP * DM * DM * 2);
  ushort_t* Wf1b = (ushort_t*)alloc((size_t)DM * DM * 2);
  ushort_t* Wf2b = (ushort_t*)alloc((size_t)DM * DM * 2);
  ushort_t* xg   = (ushort_t*)alloc((size_t)MROWS * DM * 2);
  ushort_t* H    = (ushort_t*)alloc((size_t)MROWS * DM * 2);
  ushort_t* Y    = (ushort_t*)alloc((size_t)MROWS * DM * 2);
  ushort_t* xf   = (ushort_t*)alloc((size_t)BTOK * DM * 2);
  ushort_t* Hf   = (ushort_t*)alloc((size_t)BTOK * DM * 2);
  int* gidx   = (int*)alloc(MROWS * 4);
  int* slot   = (int*)alloc(NASSIGN * 4);
  int* counts = (int*)alloc(NEXP * 4);
  int* fbidx  = (int*)alloc(BTOK * 4);
  int* nfb    = (int*)alloc(4);

  route_kernel<<<NEXP, 1024, 0, stream>>>(routes, capp, gidx, slot, counts, nfb);
  fb_list_kernel<<<BTOK / 256, 256, 0, stream>>>(slot, fbidx, nfb);
  cvt_all_kernel<<<18432, 256, 0, stream>>>(W1, W2, Wf1, Wf2, W1b, W2b, Wf1b, Wf2b);
  gather_xg_kernel<<<MROWS, 256, 0, stream>>>(x, gidx, counts, xg);
  gather_xf_kernel<<<BTOK, 256, 0, stream>>>(x, fbidx, nfb, xf);

  dim3 ge(MROWS / BM, DM / BN);
  gemm_bt<1, 0><<<ge, 256, 0, stream>>>(xg, W1b, b1, H, nullptr, nullptr, nullptr, TILES_PER_EXP);
  gemm_bt<0, 0><<<ge, 256, 0, stream>>>(H, W2b, b2, Y, nullptr, nullptr, nullptr, TILES_PER_EXP);
  combine_kernel<<<BTOK, 256, 0, stream>>>(Y, slot, out);

  dim3 gf(BTOK / BM, DM / BN);
  gemm_bt<1, 0><<<gf, 256, 0, stream>>>(xf, Wf1b, bf1, Hf, nullptr, nullptr, nfb, 0);
  gemm_bt<0, 1><<<gf, 256, 0, stream>>>(Hf, Wf2b, bf2, nullptr, out, fbidx, nfb, 0);
}

// Round 3
// 189.742 us; speedup vs baseline: 1.1313x; 1.1065x over previous
//
#include <hip/hip_runtime.h>

// ---------------- problem constants ----------------
#define DM    1024          // d_model
#define NEXP  8             // experts
#define BTOK  8192          // tokens
#define KTOP  2             // routes per token
#define NASSIGN (BTOK*KTOP) // 16384
#define CAPC  1280          // capacity (10 * 128 -> tile-aligned)
#define MROWS (NEXP*CAPC)   // 10240 expert rows

// GEMM geometry: 128M x 64N tile, BK=32, 4 waves (2x2), acc[4][2]
#define MTILES_E (MROWS/128)   // 80
#define NTILES   (DM/64)       // 16
#define EXPB     (MTILES_E*NTILES)      // 1280
#define FBB      ((BTOK/128)*NTILES)    // 1024
#define GRID_L   (EXPB+FBB)             // 2304
#define CHUNK    (GRID_L/8)             // 288 (bijective XCD swizzle)

typedef unsigned short ushort_t;
typedef __attribute__((ext_vector_type(8))) __bf16 bf16x8;
typedef __attribute__((ext_vector_type(4))) float  f32x4;

__device__ __forceinline__ ushort_t f2b(float f) {  // f32 -> bf16 RNE
  union { float f; unsigned u; } a; a.f = f;
  unsigned u = a.u;
  return (ushort_t)((u + 0x7FFFu + ((u >> 16) & 1u)) >> 16);
}
__device__ __forceinline__ float b2f(ushort_t h) {
  union { unsigned u; float f; } a; a.u = ((unsigned)h) << 16;
  return a.f;
}

#define GLOAD_LDS(g, l) __builtin_amdgcn_global_load_lds( \
    (const __attribute__((address_space(1))) void*)(g),   \
    (__attribute__((address_space(3))) void*)(l), 16, 0, 0)

// ---------------- routing: exact sequential capacity semantics ----------------
__global__ void route_kernel(const int* __restrict__ routes, const int* __restrict__ capp,
                             int* __restrict__ gidx, int* __restrict__ slot,
                             int* __restrict__ counts, int* __restrict__ nfb) {
  const int e = blockIdx.x;
  const int t = threadIdx.x, lane = t & 63, w = t >> 6;
  int cap = *capp; if (cap > CAPC) cap = CAPC;
  if (e == 0 && t == 0) *nfb = 0;
  __shared__ int wtot[16];
  int base = 0;
  for (int i0 = 0; i0 < NASSIGN; i0 += 1024) {
    int i = i0 + t;
    int r = routes[i];
    bool mine = (r == e);
    unsigned long long mask = __ballot(mine);
    int pre = __popcll(mask & ((1ull << lane) - 1ull));
    if (lane == 0) wtot[w] = __popcll(mask);
    __syncthreads();
    int tot = 0;
#pragma unroll
    for (int j = 0; j < 16; ++j) { int c = wtot[j]; if (j < w) pre += c; tot += c; }
    if (e == 0 && (unsigned)r >= NEXP) slot[i] = -1;  // defensive (never triggers)
    if (mine) {
      int pos = base + pre;
      if (pos < cap) { gidx[e * CAPC + pos] = i >> 1; slot[i] = e * CAPC + pos; }
      else slot[i] = -1;
    }
    base += tot;
    __syncthreads();
  }
  if (t == 0) counts[e] = base < cap ? base : cap;
}

// ---------------- build fallback token list (used==0) ----------------
__global__ void fb_list_kernel(const int* __restrict__ slot, int* __restrict__ fbidx,
                               int* __restrict__ nfb) {
  int t = blockIdx.x * 256 + threadIdx.x;
  if (t >= BTOK) return;
  int u = (slot[2 * t] >= 0) + (slot[2 * t + 1] >= 0);
  if (u == 0) { int p = atomicAdd(nfb, 1); fbidx[p] = t; }
}

// ---------------- fused prep: weight cvt + both gathers ----------------
// blocks [0,8192) W1 cvt, [8192,16384) W2, [16384,17408) Wf1, [17408,18432) Wf2,
// [18432,28672) gather_xg rows, [28672,36864) gather_xf rows.
__global__ void prep_kernel(const float* __restrict__ W1, const float* __restrict__ W2,
                            const float* __restrict__ Wf1, const float* __restrict__ Wf2,
                            ushort_t* __restrict__ o1, ushort_t* __restrict__ o2,
                            ushort_t* __restrict__ of1, ushort_t* __restrict__ of2,
                            const float* __restrict__ x, const int* __restrict__ gidx,
                            const int* __restrict__ counts, ushort_t* __restrict__ xg,
                            const int* __restrict__ fbidx, const int* __restrict__ nfbp,
                            ushort_t* __restrict__ xf) {
  int b = blockIdx.x, t = threadIdx.x;
  if (b < 18432) {                       // weight f32 -> bf16
    const float* s; ushort_t* d; int idx;
    if (b < 8192)       { s = W1;  d = o1;  idx = b; }
    else if (b < 16384) { s = W2;  d = o2;  idx = b - 8192; }
    else if (b < 17408) { s = Wf1; d = of1; idx = b - 16384; }
    else                { s = Wf2; d = of2; idx = b - 17408; }
    int i = idx * 256 + t;
    float4 v = ((const float4*)s)[i];
    ushort4 o; o.x = f2b(v.x); o.y = f2b(v.y); o.z = f2b(v.z); o.w = f2b(v.w);
    ((ushort4*)d)[i] = o;
  } else if (b < 28672) {                // gather accepted rows -> xg
    int row = b - 18432;
    int e = row / CAPC, p = row % CAPC;
    int d = t * 4;
    ushort4 o = {0, 0, 0, 0};
    if (p < counts[e]) {
      int tok = gidx[row];
      float4 v = *(const float4*)(x + (size_t)tok * DM + d);
      o.x = f2b(v.x); o.y = f2b(v.y); o.z = f2b(v.z); o.w = f2b(v.w);
    }
    *(ushort4*)(xg + (size_t)row * DM + d) = o;
  } else {                               // gather fallback rows -> xf
    int row = b - 28672;
    int n = *nfbp;
    int nr = (n + 127) & ~127;
    if (row >= nr) return;
    int d = t * 4;
    ushort4 o = {0, 0, 0, 0};
    if (row < n) {
      int tok = fbidx[row];
      float4 v = *(const float4*)(x + (size_t)tok * DM + d);
      o.x = f2b(v.x); o.y = f2b(v.y); o.z = f2b(v.z); o.w = f2b(v.w);
    }
    *(ushort4*)(xf + (size_t)row * DM + d) = o;
  }
}

// ---------------- fused layer GEMM: expert part + fallback part ----------------
// C[m,n] = A[m,k]*W[n,k] + bias[n]; 128x64 tile, 2-phase dbuf (T3-minimum),
// swizzled LDS (rule #21: inverse-swizzled global source + swizzled ds_read).
// FBSCAT=1: fallback part scatters f32 rows into outF via scat[].
template <int RELU, int FBSCAT>
__global__ __launch_bounds__(256, 4) void layer_kernel(
    const ushort_t* __restrict__ Ae, const ushort_t* __restrict__ We,
    const float* __restrict__ be, ushort_t* __restrict__ Ce,
    const ushort_t* __restrict__ Af, const ushort_t* __restrict__ Wf,
    const float* __restrict__ bfp, ushort_t* __restrict__ Cf,
    float* __restrict__ outF, const int* __restrict__ scat,
    const int* __restrict__ nfbp) {
  int lb = ((int)blockIdx.x & 7) * CHUNK + ((int)blockIdx.x >> 3);  // XCD swizzle
  const ushort_t* A; const ushort_t* W; const float* bias; ushort_t* C;
  int mgrp, ntile; bool isfb;
  if (lb < EXPB) {
    mgrp = lb >> 4; ntile = lb & 15;
    int e = mgrp / 10;
    A = Ae; W = We + (size_t)e * DM * DM; bias = be + e * DM; C = Ce; isfb = false;
  } else {
    lb -= EXPB; mgrp = lb >> 4; ntile = lb & 15;
    if (mgrp * 128 >= *nfbp) return;
    A = Af; W = Wf; bias = bfp; C = Cf; isfb = true;
  }
  const int tid = threadIdx.x, lane = tid & 63, w = tid >> 6;
  const int wr = w >> 1, wc = w & 1;
  __shared__ ushort_t lA[2][128 * 32];
  __shared__ ushort_t lB[2][64 * 32];
  const size_t Abase = (size_t)mgrp * 128 * DM;
  const size_t Wbase = (size_t)ntile * 64 * DM;
  f32x4 acc[4][2] = {};

  // staging: A = 8 segs of 16 rows (wave stages segs 2w,2w+1), B = 4 segs (seg w).
  const int sub  = lane >> 2;                     // row within 16-row seg
  const int slt  = lane & 3;                      // 16B k-slot
  const int gcol = (slt ^ ((sub >> 1) & 3)) * 8;  // inverse-swizzled global k-off
  const int ra0 = (w * 2)     * 16 + sub;
  const int ra1 = (w * 2 + 1) * 16 + sub;
  const int rbw = w * 16 + sub;

#define STAGE(T, BUF) do { int kt_ = (T) * 32;                                  \
    GLOAD_LDS(A + Abase + (size_t)ra0 * DM + kt_ + gcol, &lA[BUF][(w*2)  *512]); \
    GLOAD_LDS(A + Abase + (size_t)ra1 * DM + kt_ + gcol, &lA[BUF][(w*2+1)*512]); \
    GLOAD_LDS(W + Wbase + (size_t)rbw * DM + kt_ + gcol, &lB[BUF][w*512]);       \
  } while (0)

  const int fr    = lane & 15;
  const int rslot = ((lane >> 4) ^ ((fr >> 1) & 3)) * 8;  // swizzled read k-off

  STAGE(0, 0);
  for (int t = 0; t < 32; ++t) {
    __syncthreads();                       // drains vmcnt: tile t landed, buf^1 reads done
    if (t + 1 < 32) STAGE(t + 1, (t + 1) & 1);
    const ushort_t* bA = lA[t & 1];
    const ushort_t* bB = lB[t & 1];
    bf16x8 av[4], bv[2];
#pragma unroll
    for (int m = 0; m < 4; ++m)
      av[m] = *(const bf16x8*)&bA[(wr * 64 + m * 16 + fr) * 32 + rslot];
#pragma unroll
    for (int n = 0; n < 2; ++n)
      bv[n] = *(const bf16x8*)&bB[(wc * 32 + n * 16 + fr) * 32 + rslot];
#pragma unroll
    for (int m = 0; m < 4; ++m)
#pragma unroll
      for (int n = 0; n < 2; ++n)
        acc[m][n] = __builtin_amdgcn_mfma_f32_16x16x32_bf16(av[m], bv[n], acc[m][n], 0, 0, 0);
  }
#undef STAGE

  // epilogue: C/D layout col=lane&15, row=(lane>>4)*4+reg  [m89-verified]
  int nfbv = (FBSCAT && isfb) ? *nfbp : 0;
#pragma unroll
  for (int n = 0; n < 2; ++n) {
    int col = ntile * 64 + wc * 32 + n * 16 + fr;
    float bb = bias[col];
#pragma unroll
    for (int m = 0; m < 4; ++m) {
      int row0 = mgrp * 128 + wr * 64 + m * 16 + (lane >> 4) * 4;
#pragma unroll
      for (int r = 0; r < 4; ++r) {
        float v = acc[m][n][r] + bb;
        if (RELU) v = v > 0.0f ? v : 0.0f;
        int row = row0 + r;
        if (FBSCAT && isfb) {
          if (row < nfbv) outF[(size_t)scat[row] * DM + col] = v;
        } else {
          C[(size_t)row * DM + col] = f2b(v);
        }
      }
    }
  }
}

// ---------------- combine accepted expert outputs per token ----------------
__global__ void combine_kernel(const ushort_t* __restrict__ Y, const int* __restrict__ slot,
                               float* __restrict__ out) {
  int t = blockIdx.x;
  int s0 = slot[2 * t], s1 = slot[2 * t + 1];
  int u = (s0 >= 0) + (s1 >= 0);
  if (u == 0) return;  // fallback GEMM scatter writes these rows
  int d = threadIdx.x * 4;
  float a0 = 0, a1 = 0, a2 = 0, a3 = 0;
  if (s0 >= 0) {
    ushort4 q = *(const ushort4*)(Y + (size_t)s0 * DM + d);
    a0 += b2f(q.x); a1 += b2f(q.y); a2 += b2f(q.z); a3 += b2f(q.w);
  }
  if (s1 >= 0) {
    ushort4 q = *(const ushort4*)(Y + (size_t)s1 * DM + d);
    a0 += b2f(q.x); a1 += b2f(q.y); a2 += b2f(q.z); a3 += b2f(q.w);
  }
  float inv = 1.0f / (float)u;
  float4 o = make_float4(a0 * inv, a1 * inv, a2 * inv, a3 * inv);
  *(float4*)(out + (size_t)t * DM + d) = o;
}

// ---------------- launch ----------------
extern "C" void kernel_launch(void* const* d_in, const int* in_sizes, int n_in,
                              void* d_out, int out_size, void* d_ws, size_t ws_size,
                              hipStream_t stream) {
  const float* x   = (const float*)d_in[0];
  const float* W1  = (const float*)d_in[1];
  const float* b1  = (const float*)d_in[2];
  const float* W2  = (const float*)d_in[3];
  const float* b2  = (const float*)d_in[4];
  const float* Wf1 = (const float*)d_in[5];
  const float* bf1 = (const float*)d_in[6];
  const float* Wf2 = (const float*)d_in[7];
  const float* bf2 = (const float*)d_in[8];
  const int* routes = (const int*)d_in[9];
  const int* capp   = (const int*)d_in[10];
  float* out = (float*)d_out;

  char* ws = (char*)d_ws;
  size_t off = 0;
  auto alloc = [&](size_t bytes) -> void* {
    void* p = ws + off; off += (bytes + 255) & ~255ull; return p;
  };
  ushort_t* W1b  = (ushort_t*)alloc((size_t)NEXP * DM * DM * 2);
  ushort_t* W2b  = (ushort_t*)alloc((size_t)NEXP * DM * DM * 2);
  ushort_t* Wf1b = (ushort_t*)alloc((size_t)DM * DM * 2);
  ushort_t* Wf2b = (ushort_t*)alloc((size_t)DM * DM * 2);
  ushort_t* xg   = (ushort_t*)alloc((size_t)MROWS * DM * 2);
  ushort_t* H    = (ushort_t*)alloc((size_t)MROWS * DM * 2);
  ushort_t* Y    = (ushort_t*)alloc((size_t)MROWS * DM * 2);
  ushort_t* xf   = (ushort_t*)alloc((size_t)BTOK * DM * 2);
  ushort_t* Hf   = (ushort_t*)alloc((size_t)BTOK * DM * 2);
  int* gidx   = (int*)alloc(MROWS * 4);
  int* slot   = (int*)alloc(NASSIGN * 4);
  int* counts = (int*)alloc(NEXP * 4);
  int* fbidx  = (int*)alloc(BTOK * 4);
  int* nfb    = (int*)alloc(4);

  route_kernel<<<NEXP, 1024, 0, stream>>>(routes, capp, gidx, slot, counts, nfb);
  fb_list_kernel<<<BTOK / 256, 256, 0, stream>>>(slot, fbidx, nfb);
  prep_kernel<<<36864, 256, 0, stream>>>(W1, W2, Wf1, Wf2, W1b, W2b, Wf1b, Wf2b,
                                         x, gidx, counts, xg, fbidx, nfb, xf);
  layer_kernel<1, 0><<<GRID_L, 256, 0, stream>>>(xg, W1b, b1, H, xf, Wf1b, bf1, Hf,
                                                 nullptr, nullptr, nfb);
  layer_kernel<0, 1><<<GRID_L, 256, 0, stream>>>(H, W2b, b2, Y, Hf, Wf2b, bf2, nullptr,
                                                 out, fbidx, nfb);
  combine_kernel<<<BTOK, 256, 0, stream>>>(Y, slot, out);
}

// Round 4
// 180.689 us; speedup vs baseline: 1.1880x; 1.0501x over previous
//
#include <hip/hip_runtime.h>

// ---------------- problem constants ----------------
#define DM    1024          // d_model
#define NEXP  8             // experts
#define BTOK  8192          // tokens
#define KTOP  2             // routes per token
#define NASSIGN (BTOK*KTOP) // 16384
#define CAPC  1280          // capacity (10 * 128 -> tile-aligned)
#define MROWS (NEXP*CAPC)   // 10240 expert rows

// GEMM geometry: 128M x 128N tile, BK=32, 4 waves (2x2), acc[4][4]
#define MTILES_E (MROWS/128)   // 80
#define NTILES   (DM/128)      // 8
#define EXPB     (MTILES_E*NTILES)      // 640
#define FBB      ((BTOK/128)*NTILES)    // 512
#define GRID_L   (EXPB+FBB)             // 1152
#define CHUNK    (GRID_L/8)             // 144 (bijective XCD swizzle)

typedef unsigned short ushort_t;
typedef __attribute__((ext_vector_type(8))) __bf16 bf16x8;
typedef __attribute__((ext_vector_type(4))) float  f32x4;

__device__ __forceinline__ ushort_t f2b(float f) {  // f32 -> bf16 RNE
  union { float f; unsigned u; } a; a.f = f;
  unsigned u = a.u;
  return (ushort_t)((u + 0x7FFFu + ((u >> 16) & 1u)) >> 16);
}
__device__ __forceinline__ float b2f(ushort_t h) {
  union { unsigned u; float f; } a; a.u = ((unsigned)h) << 16;
  return a.f;
}

#define GLOAD_LDS(g, l) __builtin_amdgcn_global_load_lds( \
    (const __attribute__((address_space(1))) void*)(g),   \
    (__attribute__((address_space(3))) void*)(l), 16, 0, 0)

// ---------------- routing: exact sequential capacity semantics ----------------
__global__ void route_kernel(const int* __restrict__ routes, const int* __restrict__ capp,
                             int* __restrict__ gidx, int* __restrict__ slot,
                             int* __restrict__ counts, int* __restrict__ nfb) {
  const int e = blockIdx.x;
  const int t = threadIdx.x, lane = t & 63, w = t >> 6;
  int cap = *capp; if (cap > CAPC) cap = CAPC;
  if (e == 0 && t == 0) *nfb = 0;
  __shared__ int wtot[16];
  int base = 0;
  for (int i0 = 0; i0 < NASSIGN; i0 += 1024) {
    int i = i0 + t;
    int r = routes[i];
    bool mine = (r == e);
    unsigned long long mask = __ballot(mine);
    int pre = __popcll(mask & ((1ull << lane) - 1ull));
    if (lane == 0) wtot[w] = __popcll(mask);
    __syncthreads();
    int tot = 0;
#pragma unroll
    for (int j = 0; j < 16; ++j) { int c = wtot[j]; if (j < w) pre += c; tot += c; }
    if (e == 0 && (unsigned)r >= NEXP) slot[i] = -1;  // defensive (never triggers)
    if (mine) {
      int pos = base + pre;
      if (pos < cap) { gidx[e * CAPC + pos] = i >> 1; slot[i] = e * CAPC + pos; }
      else slot[i] = -1;
    }
    base += tot;
    __syncthreads();
  }
  if (t == 0) counts[e] = base < cap ? base : cap;
}

// ---------------- build fallback token list (used==0) ----------------
__global__ void fb_list_kernel(const int* __restrict__ slot, int* __restrict__ fbidx,
                               int* __restrict__ nfb) {
  int t = blockIdx.x * 256 + threadIdx.x;
  if (t >= BTOK) return;
  int u = (slot[2 * t] >= 0) + (slot[2 * t + 1] >= 0);
  if (u == 0) { int p = atomicAdd(nfb, 1); fbidx[p] = t; }
}

// ---------------- fused prep: weight cvt + both gathers ----------------
__global__ void prep_kernel(const float* __restrict__ W1, const float* __restrict__ W2,
                            const float* __restrict__ Wf1, const float* __restrict__ Wf2,
                            ushort_t* __restrict__ o1, ushort_t* __restrict__ o2,
                            ushort_t* __restrict__ of1, ushort_t* __restrict__ of2,
                            const float* __restrict__ x, const int* __restrict__ gidx,
                            const int* __restrict__ counts, ushort_t* __restrict__ xg,
                            const int* __restrict__ fbidx, const int* __restrict__ nfbp,
                            ushort_t* __restrict__ xf) {
  int b = blockIdx.x, t = threadIdx.x;
  if (b < 18432) {                       // weight f32 -> bf16
    const float* s; ushort_t* d; int idx;
    if (b < 8192)       { s = W1;  d = o1;  idx = b; }
    else if (b < 16384) { s = W2;  d = o2;  idx = b - 8192; }
    else if (b < 17408) { s = Wf1; d = of1; idx = b - 16384; }
    else                { s = Wf2; d = of2; idx = b - 17408; }
    int i = idx * 256 + t;
    float4 v = ((const float4*)s)[i];
    ushort4 o; o.x = f2b(v.x); o.y = f2b(v.y); o.z = f2b(v.z); o.w = f2b(v.w);
    ((ushort4*)d)[i] = o;
  } else if (b < 28672) {                // gather accepted rows -> xg
    int row = b - 18432;
    int e = row / CAPC, p = row % CAPC;
    int d = t * 4;
    ushort4 o = {0, 0, 0, 0};
    if (p < counts[e]) {
      int tok = gidx[row];
      float4 v = *(const float4*)(x + (size_t)tok * DM + d);
      o.x = f2b(v.x); o.y = f2b(v.y); o.z = f2b(v.z); o.w = f2b(v.w);
    }
    *(ushort4*)(xg + (size_t)row * DM + d) = o;
  } else {                               // gather fallback rows -> xf
    int row = b - 28672;
    int n = *nfbp;
    int nr = (n + 127) & ~127;
    if (row >= nr) return;
    int d = t * 4;
    ushort4 o = {0, 0, 0, 0};
    if (row < n) {
      int tok = fbidx[row];
      float4 v = *(const float4*)(x + (size_t)tok * DM + d);
      o.x = f2b(v.x); o.y = f2b(v.y); o.z = f2b(v.z); o.w = f2b(v.w);
    }
    *(ushort4*)(xf + (size_t)row * DM + d) = o;
  }
}

// ---------------- fused layer GEMM: expert part + fallback part ----------------
// C[m,n] = A[m,k]*W[n,k] + bias[n]; 128x128 tile, BK=32, 2-phase dbuf, one
// barrier per K-step (16 MFMA per barrier), swizzled LDS (rule #21:
// inverse-swizzled global source + swizzled ds_read; conflicts measured 0).
template <int RELU, int FBSCAT>
__global__ __launch_bounds__(256, 2) void layer_kernel(
    const ushort_t* __restrict__ Ae, const ushort_t* __restrict__ We,
    const float* __restrict__ be, ushort_t* __restrict__ Ce,
    const ushort_t* __restrict__ Af, const ushort_t* __restrict__ Wf,
    const float* __restrict__ bfp, ushort_t* __restrict__ Cf,
    float* __restrict__ outF, const int* __restrict__ scat,
    const int* __restrict__ nfbp) {
  int lb = ((int)blockIdx.x & 7) * CHUNK + ((int)blockIdx.x >> 3);  // XCD swizzle
  const ushort_t* A; const ushort_t* W; const float* bias; ushort_t* C;
  int mgrp, ntile; bool isfb;
  if (lb < EXPB) {
    mgrp = lb >> 3; ntile = lb & 7;
    int e = mgrp / 10;
    A = Ae; W = We + (size_t)e * DM * DM; bias = be + e * DM; C = Ce; isfb = false;
  } else {
    lb -= EXPB; mgrp = lb >> 3; ntile = lb & 7;
    if (mgrp * 128 >= *nfbp) return;
    A = Af; W = Wf; bias = bfp; C = Cf; isfb = true;
  }
  const int tid = threadIdx.x, lane = tid & 63, w = tid >> 6;
  const int wr = w >> 1, wc = w & 1;
  __shared__ ushort_t lA[2][128 * 32];
  __shared__ ushort_t lB[2][128 * 32];
  const size_t Abase = (size_t)mgrp * 128 * DM;
  const size_t Wbase = (size_t)ntile * 128 * DM;
  f32x4 acc[4][4] = {};

  // staging: each operand = 8 segs of 16 rows x 32k (1KB); wave w stages
  // segs {2w, 2w+1} of A and of B -> 4 global_load_lds per wave per K-tile.
  const int sub  = lane >> 2;                     // row within 16-row seg
  const int slt  = lane & 3;                      // 16B k-slot
  const int gcol = (slt ^ ((sub >> 1) & 3)) * 8;  // inverse-swizzled global k-off
  const int r0 = (w * 2)     * 16 + sub;
  const int r1 = (w * 2 + 1) * 16 + sub;

#define STAGE(T, BUF) do { int kt_ = (T) * 32;                                   \
    GLOAD_LDS(A + Abase + (size_t)r0 * DM + kt_ + gcol, &lA[BUF][(w*2)  *512]);  \
    GLOAD_LDS(A + Abase + (size_t)r1 * DM + kt_ + gcol, &lA[BUF][(w*2+1)*512]);  \
    GLOAD_LDS(W + Wbase + (size_t)r0 * DM + kt_ + gcol, &lB[BUF][(w*2)  *512]);  \
    GLOAD_LDS(W + Wbase + (size_t)r1 * DM + kt_ + gcol, &lB[BUF][(w*2+1)*512]);  \
  } while (0)

  const int fr    = lane & 15;
  const int rslot = ((lane >> 4) ^ ((fr >> 1) & 3)) * 8;  // swizzled read k-off

  STAGE(0, 0);
  for (int t = 0; t < 32; ++t) {
    __syncthreads();                 // drains vmcnt: tile t landed; buf[t&1]'s
                                     // prior readers all passed this barrier
    if (t + 1 < 32) STAGE(t + 1, (t + 1) & 1);
    const ushort_t* bA = lA[t & 1];
    const ushort_t* bB = lB[t & 1];
    bf16x8 av[4], bv[4];
#pragma unroll
    for (int m = 0; m < 4; ++m)
      av[m] = *(const bf16x8*)&bA[(wr * 64 + m * 16 + fr) * 32 + rslot];
#pragma unroll
    for (int n = 0; n < 4; ++n)
      bv[n] = *(const bf16x8*)&bB[(wc * 64 + n * 16 + fr) * 32 + rslot];
    __builtin_amdgcn_s_setprio(1);
#pragma unroll
    for (int m = 0; m < 4; ++m)
#pragma unroll
      for (int n = 0; n < 4; ++n)
        acc[m][n] = __builtin_amdgcn_mfma_f32_16x16x32_bf16(av[m], bv[n], acc[m][n], 0, 0, 0);
    __builtin_amdgcn_s_setprio(0);
  }
#undef STAGE

  // epilogue: C/D layout col=lane&15, row=(lane>>4)*4+reg  [m89-verified]
  int nfbv = (FBSCAT && isfb) ? *nfbp : 0;
#pragma unroll
  for (int n = 0; n < 4; ++n) {
    int col = ntile * 128 + wc * 64 + n * 16 + fr;
    float bb = bias[col];
#pragma unroll
    for (int m = 0; m < 4; ++m) {
      int row0 = mgrp * 128 + wr * 64 + m * 16 + (lane >> 4) * 4;
#pragma unroll
      for (int r = 0; r < 4; ++r) {
        float v = acc[m][n][r] + bb;
        if (RELU) v = v > 0.0f ? v : 0.0f;
        int row = row0 + r;
        if (FBSCAT && isfb) {
          if (row < nfbv) outF[(size_t)scat[row] * DM + col] = v;
        } else {
          C[(size_t)row * DM + col] = f2b(v);
        }
      }
    }
  }
}

// ---------------- combine accepted expert outputs per token ----------------
__global__ void combine_kernel(const ushort_t* __restrict__ Y, const int* __restrict__ slot,
                               float* __restrict__ out) {
  int t = blockIdx.x;
  int s0 = slot[2 * t], s1 = slot[2 * t + 1];
  int u = (s0 >= 0) + (s1 >= 0);
  if (u == 0) return;  // fallback GEMM scatter writes these rows
  int d = threadIdx.x * 4;
  float a0 = 0, a1 = 0, a2 = 0, a3 = 0;
  if (s0 >= 0) {
    ushort4 q = *(const ushort4*)(Y + (size_t)s0 * DM + d);
    a0 += b2f(q.x); a1 += b2f(q.y); a2 += b2f(q.z); a3 += b2f(q.w);
  }
  if (s1 >= 0) {
    ushort4 q = *(const ushort4*)(Y + (size_t)s1 * DM + d);
    a0 += b2f(q.x); a1 += b2f(q.y); a2 += b2f(q.z); a3 += b2f(q.w);
  }
  float inv = 1.0f / (float)u;
  float4 o = make_float4(a0 * inv, a1 * inv, a2 * inv, a3 * inv);
  *(float4*)(out + (size_t)t * DM + d) = o;
}

// ---------------- launch ----------------
extern "C" void kernel_launch(void* const* d_in, const int* in_sizes, int n_in,
                              void* d_out, int out_size, void* d_ws, size_t ws_size,
                              hipStream_t stream) {
  const float* x   = (const float*)d_in[0];
  const float* W1  = (const float*)d_in[1];
  const float* b1  = (const float*)d_in[2];
  const float* W2  = (const float*)d_in[3];
  const float* b2  = (const float*)d_in[4];
  const float* Wf1 = (const float*)d_in[5];
  const float* bf1 = (const float*)d_in[6];
  const float* Wf2 = (const float*)d_in[7];
  const float* bf2 = (const float*)d_in[8];
  const int* routes = (const int*)d_in[9];
  const int* capp   = (const int*)d_in[10];
  float* out = (float*)d_out;

  char* ws = (char*)d_ws;
  size_t off = 0;
  auto alloc = [&](size_t bytes) -> void* {
    void* p = ws + off; off += (bytes + 255) & ~255ull; return p;
  };
  ushort_t* W1b  = (ushort_t*)alloc((size_t)NEXP * DM * DM * 2);
  ushort_t* W2b  = (ushort_t*)alloc((size_t)NEXP * DM * DM * 2);
  ushort_t* Wf1b = (ushort_t*)alloc((size_t)DM * DM * 2);
  ushort_t* Wf2b = (ushort_t*)alloc((size_t)DM * DM * 2);
  ushort_t* xg   = (ushort_t*)alloc((size_t)MROWS * DM * 2);
  ushort_t* H    = (ushort_t*)alloc((size_t)MROWS * DM * 2);
  ushort_t* Y    = (ushort_t*)alloc((size_t)MROWS * DM * 2);
  ushort_t* xf   = (ushort_t*)alloc((size_t)BTOK * DM * 2);
  ushort_t* Hf   = (ushort_t*)alloc((size_t)BTOK * DM * 2);
  int* gidx   = (int*)alloc(MROWS * 4);
  int* slot   = (int*)alloc(NASSIGN * 4);
  int* counts = (int*)alloc(NEXP * 4);
  int* fbidx  = (int*)alloc(BTOK * 4);
  int* nfb    = (int*)alloc(4);

  route_kernel<<<NEXP, 1024, 0, stream>>>(routes, capp, gidx, slot, counts, nfb);
  fb_list_kernel<<<BTOK / 256, 256, 0, stream>>>(slot, fbidx, nfb);
  prep_kernel<<<36864, 256, 0, stream>>>(W1, W2, Wf1, Wf2, W1b, W2b, Wf1b, Wf2b,
                                         x, gidx, counts, xg, fbidx, nfb, xf);
  layer_kernel<1, 0><<<GRID_L, 256, 0, stream>>>(xg, W1b, b1, H, xf, Wf1b, bf1, Hf,
                                                 nullptr, nullptr, nfb);
  layer_kernel<0, 1><<<GRID_L, 256, 0, stream>>>(H, W2b, b2, Y, Hf, Wf2b, bf2, nullptr,
                                                 out, fbidx, nfb);
  combine_kernel<<<BTOK, 256, 0, stream>>>(Y, slot, out);
}

// Round 5
// 172.880 us; speedup vs baseline: 1.2416x; 1.0452x over previous
//
#include <hip/hip_runtime.h>

// ---------------- problem constants ----------------
#define DM    1024          // d_model
#define NEXP  8             // experts
#define BTOK  8192          // tokens
#define KTOP  2             // routes per token
#define NASSIGN (BTOK*KTOP) // 16384
#define CAPC  1280          // capacity (10 * 128 -> tile-aligned)
#define MROWS (NEXP*CAPC)   // 10240 expert rows

// GEMM geometry: 128M x 128N tile, BK=32, 4 waves (2x2), acc[4][4]
#define MTILES_E (MROWS/128)   // 80
#define MTILES_F (BTOK/128)    // 64
#define MTILES   (MTILES_E+MTILES_F)  // 144
#define NTILES   (DM/128)      // 8

typedef unsigned short ushort_t;
typedef __attribute__((ext_vector_type(8))) __bf16 bf16x8;
typedef __attribute__((ext_vector_type(4))) float  f32x4;

__device__ __forceinline__ ushort_t f2b(float f) {  // f32 -> bf16 RNE
  union { float f; unsigned u; } a; a.f = f;
  unsigned u = a.u;
  return (ushort_t)((u + 0x7FFFu + ((u >> 16) & 1u)) >> 16);
}
__device__ __forceinline__ float b2f(ushort_t h) {
  union { unsigned u; float f; } a; a.u = ((unsigned)h) << 16;
  return a.f;
}

#define GLOAD_LDS(g, l) __builtin_amdgcn_global_load_lds( \
    (const __attribute__((address_space(1))) void*)(g),   \
    (__attribute__((address_space(3))) void*)(l), 16, 0, 0)

// ---------------- routing: exact sequential capacity semantics ----------------
__global__ void route_kernel(const int* __restrict__ routes, const int* __restrict__ capp,
                             int* __restrict__ gidx, int* __restrict__ slot,
                             int* __restrict__ counts, int* __restrict__ nfb) {
  const int e = blockIdx.x;
  const int t = threadIdx.x, lane = t & 63, w = t >> 6;
  int cap = *capp; if (cap > CAPC) cap = CAPC;
  if (e == 0 && t == 0) *nfb = 0;
  __shared__ int wtot[16];
  int base = 0;
  for (int i0 = 0; i0 < NASSIGN; i0 += 1024) {
    int i = i0 + t;
    int r = routes[i];
    bool mine = (r == e);
    unsigned long long mask = __ballot(mine);
    int pre = __popcll(mask & ((1ull << lane) - 1ull));
    if (lane == 0) wtot[w] = __popcll(mask);
    __syncthreads();
    int tot = 0;
#pragma unroll
    for (int j = 0; j < 16; ++j) { int c = wtot[j]; if (j < w) pre += c; tot += c; }
    if (e == 0 && (unsigned)r >= NEXP) slot[i] = -1;  // defensive (never triggers)
    if (mine) {
      int pos = base + pre;
      if (pos < cap) { gidx[e * CAPC + pos] = i >> 1; slot[i] = e * CAPC + pos; }
      else slot[i] = -1;
    }
    base += tot;
    __syncthreads();
  }
  if (t == 0) counts[e] = base < cap ? base : cap;
}

// ---------------- build fallback token list (used==0) ----------------
__global__ void fb_list_kernel(const int* __restrict__ slot, int* __restrict__ fbidx,
                               int* __restrict__ nfb) {
  int t = blockIdx.x * 256 + threadIdx.x;
  if (t >= BTOK) return;
  int u = (slot[2 * t] >= 0) + (slot[2 * t + 1] >= 0);
  if (u == 0) { int p = atomicAdd(nfb, 1); fbidx[p] = t; }
}

// ---------------- fused prep: weight cvt + both gathers ----------------
__global__ void prep_kernel(const float* __restrict__ W1, const float* __restrict__ W2,
                            const float* __restrict__ Wf1, const float* __restrict__ Wf2,
                            ushort_t* __restrict__ o1, ushort_t* __restrict__ o2,
                            ushort_t* __restrict__ of1, ushort_t* __restrict__ of2,
                            const float* __restrict__ x, const int* __restrict__ gidx,
                            const int* __restrict__ counts, ushort_t* __restrict__ xg,
                            const int* __restrict__ fbidx, const int* __restrict__ nfbp,
                            ushort_t* __restrict__ xf) {
  int b = blockIdx.x, t = threadIdx.x;
  if (b < 18432) {                       // weight f32 -> bf16
    const float* s; ushort_t* d; int idx;
    if (b < 8192)       { s = W1;  d = o1;  idx = b; }
    else if (b < 16384) { s = W2;  d = o2;  idx = b - 8192; }
    else if (b < 17408) { s = Wf1; d = of1; idx = b - 16384; }
    else                { s = Wf2; d = of2; idx = b - 17408; }
    int i = idx * 256 + t;
    float4 v = ((const float4*)s)[i];
    ushort4 o; o.x = f2b(v.x); o.y = f2b(v.y); o.z = f2b(v.z); o.w = f2b(v.w);
    ((ushort4*)d)[i] = o;
  } else if (b < 28672) {                // gather accepted rows -> xg
    int row = b - 18432;
    int e = row / CAPC, p = row % CAPC;
    int d = t * 4;
    ushort4 o = {0, 0, 0, 0};
    if (p < counts[e]) {
      int tok = gidx[row];
      float4 v = *(const float4*)(x + (size_t)tok * DM + d);
      o.x = f2b(v.x); o.y = f2b(v.y); o.z = f2b(v.z); o.w = f2b(v.w);
    }
    *(ushort4*)(xg + (size_t)row * DM + d) = o;
  } else {                               // gather fallback rows -> xf
    int row = b - 28672;
    int n = *nfbp;
    int nr = (n + 127) & ~127;
    if (row >= nr) return;
    int d = t * 4;
    ushort4 o = {0, 0, 0, 0};
    if (row < n) {
      int tok = fbidx[row];
      float4 v = *(const float4*)(x + (size_t)tok * DM + d);
      o.x = f2b(v.x); o.y = f2b(v.y); o.z = f2b(v.z); o.w = f2b(v.w);
    }
    *(ushort4*)(xf + (size_t)row * DM + d) = o;
  }
}

// ---------------- fused layer GEMM: expert part + fallback part ----------------
// C[m,n] = A[m,k]*W[n,k] + bias[n]; 128x128 tile, BK=32.
// RING-3 LDS (48KB -> 3 blocks/CU), counted s_waitcnt vmcnt(4), one barrier
// per K-step, stage issued AFTER the barrier (race-free: reads of buf X for
// tile t are in (bar_t, bar_{t+1}); the rewrite of X for tile t+3 is issued
// after bar_{t+1}).  Prefetch distance 2 iters (~600cy latency cover).
// Block order: blockIdx.x = M-tile (fastest) so ~10 consecutive blocks share
// one 0.25MB W panel -> staging stays L2-hit (r1's fast layout; the r3/r4
// chunked XCD swizzle pushed W into LLC and regressed).
// LDS k-slot XOR-swizzle both-sides (conflicts measured 0).
template <int RELU, int FBSCAT>
__global__ __launch_bounds__(256, 3) void layer_kernel(
    const ushort_t* __restrict__ Ae, const ushort_t* __restrict__ We,
    const float* __restrict__ be, ushort_t* __restrict__ Ce,
    const ushort_t* __restrict__ Af, const ushort_t* __restrict__ Wf,
    const float* __restrict__ bfp, ushort_t* __restrict__ Cf,
    float* __restrict__ outF, const int* __restrict__ scat,
    const int* __restrict__ nfbp) {
  const int mt = blockIdx.x, ntile = blockIdx.y;
  const ushort_t* A; const ushort_t* W; const float* bias; ushort_t* C;
  int mgrp; bool isfb;
  if (mt < MTILES_E) {
    mgrp = mt;
    int e = mgrp / 10;
    A = Ae; W = We + (size_t)e * DM * DM; bias = be + e * DM; C = Ce; isfb = false;
  } else {
    mgrp = mt - MTILES_E;
    if (mgrp * 128 >= *nfbp) return;
    A = Af; W = Wf; bias = bfp; C = Cf; isfb = true;
  }
  const int tid = threadIdx.x, lane = tid & 63, w = tid >> 6;
  const int wr = w >> 1, wc = w & 1;
  __shared__ ushort_t lA[3][128 * 32];
  __shared__ ushort_t lB[3][128 * 32];
  const size_t Abase = (size_t)mgrp * 128 * DM;
  const size_t Wbase = (size_t)ntile * 128 * DM;
  f32x4 acc[4][4] = {};

  // staging: each operand = 8 segs of 16 rows x 32k (1KB); wave w stages
  // segs {2w, 2w+1} of A and of B -> 4 global_load_lds per wave per K-tile.
  const int sub  = lane >> 2;                     // row within 16-row seg
  const int slt  = lane & 3;                      // 16B k-slot
  const int gcol = (slt ^ ((sub >> 1) & 3)) * 8;  // inverse-swizzled global k-off
  const int r0 = (w * 2)     * 16 + sub;
  const int r1 = (w * 2 + 1) * 16 + sub;

#define STAGE(T, BUF) do { int kt_ = (T) * 32;                                   \
    GLOAD_LDS(A + Abase + (size_t)r0 * DM + kt_ + gcol, &lA[BUF][(w*2)  *512]);  \
    GLOAD_LDS(A + Abase + (size_t)r1 * DM + kt_ + gcol, &lA[BUF][(w*2+1)*512]);  \
    GLOAD_LDS(W + Wbase + (size_t)r0 * DM + kt_ + gcol, &lB[BUF][(w*2)  *512]);  \
    GLOAD_LDS(W + Wbase + (size_t)r1 * DM + kt_ + gcol, &lB[BUF][(w*2+1)*512]);  \
  } while (0)

  const int fr    = lane & 15;
  const int rslot = ((lane >> 4) ^ ((fr >> 1) & 3)) * 8;  // swizzled read k-off

  STAGE(0, 0); STAGE(1, 1);            // 8 vmem instrs/wave in flight
  int cur = 0;
  for (int t = 0; t < 32; ++t) {
    // tile t landed <=> outstanding <= 4 (only stage t+1 in flight; after the
    // in-loop stage below, steady state has t+1 and t+2 = 8, drained to 4 here)
    if (t < 31) asm volatile("s_waitcnt vmcnt(4)" ::: "memory");
    else        asm volatile("s_waitcnt vmcnt(0)" ::: "memory");
    asm volatile("s_barrier" ::: "memory");
    if (t + 2 < 32) {
      int nb = cur + 2; if (nb >= 3) nb -= 3;
      STAGE(t + 2, nb);
    }
    const ushort_t* bA = lA[cur];
    const ushort_t* bB = lB[cur];
    bf16x8 av[4], bv[4];
#pragma unroll
    for (int m = 0; m < 4; ++m)
      av[m] = *(const bf16x8*)&bA[(wr * 64 + m * 16 + fr) * 32 + rslot];
#pragma unroll
    for (int n = 0; n < 4; ++n)
      bv[n] = *(const bf16x8*)&bB[(wc * 64 + n * 16 + fr) * 32 + rslot];
#pragma unroll
    for (int m = 0; m < 4; ++m)
#pragma unroll
      for (int n = 0; n < 4; ++n)
        acc[m][n] = __builtin_amdgcn_mfma_f32_16x16x32_bf16(av[m], bv[n], acc[m][n], 0, 0, 0);
    cur = (cur == 2) ? 0 : cur + 1;
  }
#undef STAGE

  // epilogue: C/D layout col=lane&15, row=(lane>>4)*4+reg  [m89-verified]
  int nfbv = (FBSCAT && isfb) ? *nfbp : 0;
#pragma unroll
  for (int n = 0; n < 4; ++n) {
    int col = ntile * 128 + wc * 64 + n * 16 + fr;
    float bb = bias[col];
#pragma unroll
    for (int m = 0; m < 4; ++m) {
      int row0 = mgrp * 128 + wr * 64 + m * 16 + (lane >> 4) * 4;
#pragma unroll
      for (int r = 0; r < 4; ++r) {
        float v = acc[m][n][r] + bb;
        if (RELU) v = v > 0.0f ? v : 0.0f;
        int row = row0 + r;
        if (FBSCAT && isfb) {
          if (row < nfbv) outF[(size_t)scat[row] * DM + col] = v;
        } else {
          C[(size_t)row * DM + col] = f2b(v);
        }
      }
    }
  }
}

// ---------------- combine accepted expert outputs per token ----------------
__global__ void combine_kernel(const ushort_t* __restrict__ Y, const int* __restrict__ slot,
                               float* __restrict__ out) {
  int t = blockIdx.x;
  int s0 = slot[2 * t], s1 = slot[2 * t + 1];
  int u = (s0 >= 0) + (s1 >= 0);
  if (u == 0) return;  // fallback GEMM scatter writes these rows
  int d = threadIdx.x * 4;
  float a0 = 0, a1 = 0, a2 = 0, a3 = 0;
  if (s0 >= 0) {
    ushort4 q = *(const ushort4*)(Y + (size_t)s0 * DM + d);
    a0 += b2f(q.x); a1 += b2f(q.y); a2 += b2f(q.z); a3 += b2f(q.w);
  }
  if (s1 >= 0) {
    ushort4 q = *(const ushort4*)(Y + (size_t)s1 * DM + d);
    a0 += b2f(q.x); a1 += b2f(q.y); a2 += b2f(q.z); a3 += b2f(q.w);
  }
  float inv = 1.0f / (float)u;
  float4 o = make_float4(a0 * inv, a1 * inv, a2 * inv, a3 * inv);
  *(float4*)(out + (size_t)t * DM + d) = o;
}

// ---------------- launch ----------------
extern "C" void kernel_launch(void* const* d_in, const int* in_sizes, int n_in,
                              void* d_out, int out_size, void* d_ws, size_t ws_size,
                              hipStream_t stream) {
  const float* x   = (const float*)d_in[0];
  const float* W1  = (const float*)d_in[1];
  const float* b1  = (const float*)d_in[2];
  const float* W2  = (const float*)d_in[3];
  const float* b2  = (const float*)d_in[4];
  const float* Wf1 = (const float*)d_in[5];
  const float* bf1 = (const float*)d_in[6];
  const float* Wf2 = (const float*)d_in[7];
  const float* bf2 = (const float*)d_in[8];
  const int* routes = (const int*)d_in[9];
  const int* capp   = (const int*)d_in[10];
  float* out = (float*)d_out;

  char* ws = (char*)d_ws;
  size_t off = 0;
  auto alloc = [&](size_t bytes) -> void* {
    void* p = ws + off; off += (bytes + 255) & ~255ull; return p;
  };
  ushort_t* W1b  = (ushort_t*)alloc((size_t)NEXP * DM * DM * 2);
  ushort_t* W2b  = (ushort_t*)alloc((size_t)NEXP * DM * DM * 2);
  ushort_t* Wf1b = (ushort_t*)alloc((size_t)DM * DM * 2);
  ushort_t* Wf2b = (ushort_t*)alloc((size_t)DM * DM * 2);
  ushort_t* xg   = (ushort_t*)alloc((size_t)MROWS * DM * 2);
  ushort_t* H    = (ushort_t*)alloc((size_t)MROWS * DM * 2);
  ushort_t* Y    = (ushort_t*)alloc((size_t)MROWS * DM * 2);
  ushort_t* xf   = (ushort_t*)alloc((size_t)BTOK * DM * 2);
  ushort_t* Hf   = (ushort_t*)alloc((size_t)BTOK * DM * 2);
  int* gidx   = (int*)alloc(MROWS * 4);
  int* slot   = (int*)alloc(NASSIGN * 4);
  int* counts = (int*)alloc(NEXP * 4);
  int* fbidx  = (int*)alloc(BTOK * 4);
  int* nfb    = (int*)alloc(4);

  route_kernel<<<NEXP, 1024, 0, stream>>>(routes, capp, gidx, slot, counts, nfb);
  fb_list_kernel<<<BTOK / 256, 256, 0, stream>>>(slot, fbidx, nfb);
  prep_kernel<<<36864, 256, 0, stream>>>(W1, W2, Wf1, Wf2, W1b, W2b, Wf1b, Wf2b,
                                         x, gidx, counts, xg, fbidx, nfb, xf);
  dim3 gl(MTILES, NTILES);
  layer_kernel<1, 0><<<gl, 256, 0, stream>>>(xg, W1b, b1, H, xf, Wf1b, bf1, Hf,
                                             nullptr, nullptr, nfb);
  layer_kernel<0, 1><<<gl, 256, 0, stream>>>(H, W2b, b2, Y, Hf, Wf2b, bf2, nullptr,
                                             out, fbidx, nfb);
  combine_kernel<<<BTOK, 256, 0, stream>>>(Y, slot, out);
}

// Round 6
// 156.006 us; speedup vs baseline: 1.3759x; 1.1082x over previous
//
#include <hip/hip_runtime.h>

// ---------------- problem constants ----------------
#define DM    1024          // d_model
#define NEXP  8             // experts
#define BTOK  8192          // tokens
#define KTOP  2             // routes per token
#define NASSIGN (BTOK*KTOP) // 16384
#define CAPC  1280          // capacity (5 * 256 -> tile-aligned)
#define MROWS (NEXP*CAPC)   // 10240 expert rows

// GEMM geometry: 256M x 256N tile, BK=64, 8 waves (2Mx4N), per-wave 128x64
#define MTILES_E (MROWS/256)   // 40
#define MTILES_F (BTOK/256)    // 32
#define MTILES   (MTILES_E+MTILES_F)  // 72
#define NTILES   (DM/256)      // 4

typedef unsigned short ushort_t;
typedef __attribute__((ext_vector_type(8))) __bf16 bf16x8;
typedef __attribute__((ext_vector_type(4))) float  f32x4;

__device__ __forceinline__ ushort_t f2b(float f) {  // f32 -> bf16 RNE
  union { float f; unsigned u; } a; a.f = f;
  unsigned u = a.u;
  return (ushort_t)((u + 0x7FFFu + ((u >> 16) & 1u)) >> 16);
}
__device__ __forceinline__ float b2f(ushort_t h) {
  union { unsigned u; float f; } a; a.u = ((unsigned)h) << 16;
  return a.f;
}

#define GLOAD_LDS(g, l) __builtin_amdgcn_global_load_lds( \
    (const __attribute__((address_space(1))) void*)(g),   \
    (__attribute__((address_space(3))) void*)(l), 16, 0, 0)

// ---------------- routing: exact sequential capacity semantics ----------------
__global__ void route_kernel(const int* __restrict__ routes, const int* __restrict__ capp,
                             int* __restrict__ gidx, int* __restrict__ slot,
                             int* __restrict__ counts, int* __restrict__ nfb) {
  const int e = blockIdx.x;
  const int t = threadIdx.x, lane = t & 63, w = t >> 6;
  int cap = *capp; if (cap > CAPC) cap = CAPC;
  if (e == 0 && t == 0) *nfb = 0;
  __shared__ int wtot[16];
  int base = 0;
  for (int i0 = 0; i0 < NASSIGN; i0 += 1024) {
    int i = i0 + t;
    int r = routes[i];
    bool mine = (r == e);
    unsigned long long mask = __ballot(mine);
    int pre = __popcll(mask & ((1ull << lane) - 1ull));
    if (lane == 0) wtot[w] = __popcll(mask);
    __syncthreads();
    int tot = 0;
#pragma unroll
    for (int j = 0; j < 16; ++j) { int c = wtot[j]; if (j < w) pre += c; tot += c; }
    if (e == 0 && (unsigned)r >= NEXP) slot[i] = -1;  // defensive (never triggers)
    if (mine) {
      int pos = base + pre;
      if (pos < cap) { gidx[e * CAPC + pos] = i >> 1; slot[i] = e * CAPC + pos; }
      else slot[i] = -1;
    }
    base += tot;
    __syncthreads();
  }
  if (t == 0) counts[e] = base < cap ? base : cap;
}

// ---------------- build fallback token list (used==0) ----------------
__global__ void fb_list_kernel(const int* __restrict__ slot, int* __restrict__ fbidx,
                               int* __restrict__ nfb) {
  int t = blockIdx.x * 256 + threadIdx.x;
  if (t >= BTOK) return;
  int u = (slot[2 * t] >= 0) + (slot[2 * t + 1] >= 0);
  if (u == 0) { int p = atomicAdd(nfb, 1); fbidx[p] = t; }
}

// ---------------- fused prep: weight cvt + both gathers ----------------
__global__ void prep_kernel(const float* __restrict__ W1, const float* __restrict__ W2,
                            const float* __restrict__ Wf1, const float* __restrict__ Wf2,
                            ushort_t* __restrict__ o1, ushort_t* __restrict__ o2,
                            ushort_t* __restrict__ of1, ushort_t* __restrict__ of2,
                            const float* __restrict__ x, const int* __restrict__ gidx,
                            const int* __restrict__ counts, ushort_t* __restrict__ xg,
                            const int* __restrict__ fbidx, const int* __restrict__ nfbp,
                            ushort_t* __restrict__ xf) {
  int b = blockIdx.x, t = threadIdx.x;
  if (b < 18432) {                       // weight f32 -> bf16
    const float* s; ushort_t* d; int idx;
    if (b < 8192)       { s = W1;  d = o1;  idx = b; }
    else if (b < 16384) { s = W2;  d = o2;  idx = b - 8192; }
    else if (b < 17408) { s = Wf1; d = of1; idx = b - 16384; }
    else                { s = Wf2; d = of2; idx = b - 17408; }
    int i = idx * 256 + t;
    float4 v = ((const float4*)s)[i];
    ushort4 o; o.x = f2b(v.x); o.y = f2b(v.y); o.z = f2b(v.z); o.w = f2b(v.w);
    ((ushort4*)d)[i] = o;
  } else if (b < 28672) {                // gather accepted rows -> xg
    int row = b - 18432;
    int e = row / CAPC, p = row % CAPC;
    int d = t * 4;
    ushort4 o = {0, 0, 0, 0};
    if (p < counts[e]) {
      int tok = gidx[row];
      float4 v = *(const float4*)(x + (size_t)tok * DM + d);
      o.x = f2b(v.x); o.y = f2b(v.y); o.z = f2b(v.z); o.w = f2b(v.w);
    }
    *(ushort4*)(xg + (size_t)row * DM + d) = o;
  } else {                               // gather fallback rows -> xf
    int row = b - 28672;
    int n = *nfbp;
    int nr = (n + 127) & ~127;
    if (row >= nr) return;
    int d = t * 4;
    ushort4 o = {0, 0, 0, 0};
    if (row < n) {
      int tok = fbidx[row];
      float4 v = *(const float4*)(x + (size_t)tok * DM + d);
      o.x = f2b(v.x); o.y = f2b(v.y); o.z = f2b(v.z); o.w = f2b(v.w);
    }
    *(ushort4*)(xf + (size_t)row * DM + d) = o;
  }
}

// ---------------- fused layer GEMM: expert part + fallback part ----------------
// C[m,n] = A[m,k]*W[n,k] + bias[n].  256x256 tile, BK=64, 8 waves (2Mx4N),
// per-wave 128x64 output (8x4 16x16x32 frags x 2 k-halves = 64 MFMA/K-step).
// Rationale (r5 post-mortem): per-CU staging BW caps MfmaUtil at
// ~BM*BN/(BM+BN); 128  -> 256-tile doubles FLOP per staged byte.  Full-tile
// double-buffer (128KB LDS, 1 block/CU), counted vmcnt(8) prefetch, stage
// t+2 issued after a second raw s_barrier that closes the read phase (race-
// free: all waves' ds_reads of buf[t&1] are lgkm-drained before their MFMAs,
// barrier orders that before the restage).  vmcnt never drained in-loop.
// LDS 16B-slot XOR swizzle: slot' = slot ^ (row&7), inverse-applied on the
// global source address (rule #21), linear LDS dest -> ds_read ~2-way (free).
// Grid (NTILES=4, MTILES=72) y-major: round-2 blocks are high fb tiles ->
// early-exit; ~208 working blocks at 1 block/CU = single round.
template <int RELU, int FBSCAT>
__global__ __launch_bounds__(512, 2) void layer_kernel(
    const ushort_t* __restrict__ Ae, const ushort_t* __restrict__ We,
    const float* __restrict__ be, ushort_t* __restrict__ Ce,
    const ushort_t* __restrict__ Af, const ushort_t* __restrict__ Wf,
    const float* __restrict__ bfp, ushort_t* __restrict__ Cf,
    float* __restrict__ outF, const int* __restrict__ scat,
    const int* __restrict__ nfbp) {
  const int ntile = blockIdx.x, mt = blockIdx.y;
  const ushort_t* A; const ushort_t* W; const float* bias; ushort_t* C;
  int mgrp; bool isfb;
  if (mt < MTILES_E) {
    mgrp = mt;
    int e = mgrp / (CAPC / 256);    // 5 M-tiles per expert
    A = Ae; W = We + (size_t)e * DM * DM; bias = be + e * DM; C = Ce; isfb = false;
  } else {
    mgrp = mt - MTILES_E;
    if (mgrp * 256 >= *nfbp) return;
    A = Af; W = Wf; bias = bfp; C = Cf; isfb = true;
  }
  const int tid = threadIdx.x, lane = tid & 63, w = tid >> 6;
  const int wr = w >> 2, wc = w & 3;
  __shared__ ushort_t lA[2][256 * 64];   // 64KB
  __shared__ ushort_t lB[2][256 * 64];   // 64KB
  const size_t Abase = (size_t)mgrp * 256 * DM;
  const size_t Wbase = (size_t)ntile * 256 * DM;
  f32x4 acc[8][4] = {};

  // staging: 8-row 1KB segments; wave w stages A rows [w*32,w*32+32) and the
  // same B rows -> 4+4 global_load_lds per wave per K-tile (8 in flight each).
  const int sub8 = lane >> 3;              // row within 8-row seg
  const int slt  = lane & 7;               // linear 16B slot this lane fills
  const int gcol = (slt ^ sub8) * 8;       // inverse-swizzled source k-offset

#define STAGE(T, BUF) do { int kt_ = (T) * 64;                                   \
    _Pragma("unroll")                                                            \
    for (int j_ = 0; j_ < 4; ++j_) {                                             \
      int seg_ = w * 4 + j_; int row_ = seg_ * 8 + sub8;                         \
      GLOAD_LDS(A + Abase + (size_t)row_ * DM + kt_ + gcol, &lA[BUF][seg_*512]); \
      GLOAD_LDS(W + Wbase + (size_t)row_ * DM + kt_ + gcol, &lB[BUF][seg_*512]); \
    } } while (0)

  const int fr = lane & 15, g = lane >> 4;
  const int s0 = ((g)     ^ (fr & 7)) * 8;   // swizzled 16B-slot, k-half 0
  const int s1 = ((4 + g) ^ (fr & 7)) * 8;   // swizzled 16B-slot, k-half 1

  STAGE(0, 0); STAGE(1, 1);                  // 16 vmem instrs/wave in flight
  for (int t = 0; t < 16; ++t) {
    // entry: stage(t) is the oldest batch; allow stage(t+1)'s 8 to fly
    if (t < 15) asm volatile("s_waitcnt vmcnt(8)" ::: "memory");
    else        asm volatile("s_waitcnt vmcnt(0)" ::: "memory");
    __builtin_amdgcn_s_barrier();            // tile t ready for ALL waves
    const ushort_t* bA = lA[t & 1];
    const ushort_t* bB = lB[t & 1];
    bf16x8 av[8], bv[4];
    // k-half 0
#pragma unroll
    for (int m = 0; m < 8; ++m)
      av[m] = *(const bf16x8*)&bA[(wr * 128 + m * 16 + fr) * 64 + s0];
#pragma unroll
    for (int n = 0; n < 4; ++n)
      bv[n] = *(const bf16x8*)&bB[(wc * 64 + n * 16 + fr) * 64 + s0];
#pragma unroll
    for (int m = 0; m < 8; ++m)
#pragma unroll
      for (int n = 0; n < 4; ++n)
        acc[m][n] = __builtin_amdgcn_mfma_f32_16x16x32_bf16(av[m], bv[n], acc[m][n], 0, 0, 0);
    // k-half 1
#pragma unroll
    for (int m = 0; m < 8; ++m)
      av[m] = *(const bf16x8*)&bA[(wr * 128 + m * 16 + fr) * 64 + s1];
#pragma unroll
    for (int n = 0; n < 4; ++n)
      bv[n] = *(const bf16x8*)&bB[(wc * 64 + n * 16 + fr) * 64 + s1];
#pragma unroll
    for (int m = 0; m < 8; ++m)
#pragma unroll
      for (int n = 0; n < 4; ++n)
        acc[m][n] = __builtin_amdgcn_mfma_f32_16x16x32_bf16(av[m], bv[n], acc[m][n], 0, 0, 0);
    // close read phase: every wave's ds_reads were lgkm-drained before its
    // MFMAs consumed them; barrier orders all reads before the restage.
    __builtin_amdgcn_s_barrier();
    __builtin_amdgcn_sched_barrier(0);
    if (t + 2 < 16) STAGE(t + 2, t & 1);
  }
#undef STAGE

  // epilogue: C/D layout col=lane&15, row=(lane>>4)*4+reg  [m89-verified]
  int nfbv = (FBSCAT && isfb) ? *nfbp : 0;
#pragma unroll
  for (int n = 0; n < 4; ++n) {
    int col = ntile * 256 + wc * 64 + n * 16 + fr;
    float bb = bias[col];
#pragma unroll
    for (int m = 0; m < 8; ++m) {
      int row0 = mgrp * 256 + wr * 128 + m * 16 + g * 4;
#pragma unroll
      for (int r = 0; r < 4; ++r) {
        float v = acc[m][n][r] + bb;
        if (RELU) v = v > 0.0f ? v : 0.0f;
        int row = row0 + r;
        if (FBSCAT && isfb) {
          if (row < nfbv) outF[(size_t)scat[row] * DM + col] = v;
        } else {
          C[(size_t)row * DM + col] = f2b(v);
        }
      }
    }
  }
}

// ---------------- combine accepted expert outputs per token ----------------
__global__ void combine_kernel(const ushort_t* __restrict__ Y, const int* __restrict__ slot,
                               float* __restrict__ out) {
  int t = blockIdx.x;
  int s0 = slot[2 * t], s1 = slot[2 * t + 1];
  int u = (s0 >= 0) + (s1 >= 0);
  if (u == 0) return;  // fallback GEMM scatter writes these rows
  int d = threadIdx.x * 4;
  float a0 = 0, a1 = 0, a2 = 0, a3 = 0;
  if (s0 >= 0) {
    ushort4 q = *(const ushort4*)(Y + (size_t)s0 * DM + d);
    a0 += b2f(q.x); a1 += b2f(q.y); a2 += b2f(q.z); a3 += b2f(q.w);
  }
  if (s1 >= 0) {
    ushort4 q = *(const ushort4*)(Y + (size_t)s1 * DM + d);
    a0 += b2f(q.x); a1 += b2f(q.y); a2 += b2f(q.z); a3 += b2f(q.w);
  }
  float inv = 1.0f / (float)u;
  float4 o = make_float4(a0 * inv, a1 * inv, a2 * inv, a3 * inv);
  *(float4*)(out + (size_t)t * DM + d) = o;
}

// ---------------- launch ----------------
extern "C" void kernel_launch(void* const* d_in, const int* in_sizes, int n_in,
                              void* d_out, int out_size, void* d_ws, size_t ws_size,
                              hipStream_t stream) {
  const float* x   = (const float*)d_in[0];
  const float* W1  = (const float*)d_in[1];
  const float* b1  = (const float*)d_in[2];
  const float* W2  = (const float*)d_in[3];
  const float* b2  = (const float*)d_in[4];
  const float* Wf1 = (const float*)d_in[5];
  const float* bf1 = (const float*)d_in[6];
  const float* Wf2 = (const float*)d_in[7];
  const float* bf2 = (const float*)d_in[8];
  const int* routes = (const int*)d_in[9];
  const int* capp   = (const int*)d_in[10];
  float* out = (float*)d_out;

  char* ws = (char*)d_ws;
  size_t off = 0;
  auto alloc = [&](size_t bytes) -> void* {
    void* p = ws + off; off += (bytes + 255) & ~255ull; return p;
  };
  ushort_t* W1b  = (ushort_t*)alloc((size_t)NEXP * DM * DM * 2);
  ushort_t* W2b  = (ushort_t*)alloc((size_t)NEXP * DM * DM * 2);
  ushort_t* Wf1b = (ushort_t*)alloc((size_t)DM * DM * 2);
  ushort_t* Wf2b = (ushort_t*)alloc((size_t)DM * DM * 2);
  ushort_t* xg   = (ushort_t*)alloc((size_t)MROWS * DM * 2);
  ushort_t* H    = (ushort_t*)alloc((size_t)MROWS * DM * 2);
  ushort_t* Y    = (ushort_t*)alloc((size_t)MROWS * DM * 2);
  ushort_t* xf   = (ushort_t*)alloc((size_t)BTOK * DM * 2);
  ushort_t* Hf   = (ushort_t*)alloc((size_t)BTOK * DM * 2);
  int* gidx   = (int*)alloc(MROWS * 4);
  int* slot   = (int*)alloc(NASSIGN * 4);
  int* counts = (int*)alloc(NEXP * 4);
  int* fbidx  = (int*)alloc(BTOK * 4);
  int* nfb    = (int*)alloc(4);

  route_kernel<<<NEXP, 1024, 0, stream>>>(routes, capp, gidx, slot, counts, nfb);
  fb_list_kernel<<<BTOK / 256, 256, 0, stream>>>(slot, fbidx, nfb);
  prep_kernel<<<36864, 256, 0, stream>>>(W1, W2, Wf1, Wf2, W1b, W2b, Wf1b, Wf2b,
                                         x, gidx, counts, xg, fbidx, nfb, xf);
  dim3 gl(NTILES, MTILES);
  layer_kernel<1, 0><<<gl, 512, 0, stream>>>(xg, W1b, b1, H, xf, Wf1b, bf1, Hf,
                                             nullptr, nullptr, nfb);
  layer_kernel<0, 1><<<gl, 512, 0, stream>>>(H, W2b, b2, Y, Hf, Wf2b, bf2, nullptr,
                                             out, fbidx, nfb);
  combine_kernel<<<BTOK, 256, 0, stream>>>(Y, slot, out);
}

// Round 7
// 152.123 us; speedup vs baseline: 1.4111x; 1.0255x over previous
//
#include <hip/hip_runtime.h>

// ---------------- problem constants ----------------
#define DM    1024          // d_model
#define NEXP  8             // experts
#define BTOK  8192          // tokens
#define KTOP  2             // routes per token
#define NASSIGN (BTOK*KTOP) // 16384
#define CAPC  1280          // capacity (5 * 256 -> tile-aligned)
#define MROWS (NEXP*CAPC)   // 10240 expert rows

// GEMM geometry: 256M x 256N tile, BK=64, 8 waves (2Mx4N), per-wave 128x64
#define MTILES_E (MROWS/256)   // 40
#define MTILES_F (BTOK/256)    // 32
#define NTILES   (DM/256)      // 4
#define SLOTS_E  (5*NTILES)    // 20 expert-tile slots per XCD
#define SLOTS_F  (MTILES_F*NTILES/8)  // 16 fb slots per XCD
#define SLOTS    (SLOTS_E+SLOTS_F)    // 36
#define GRID_L   (8*SLOTS)            // 288

typedef unsigned short ushort_t;
typedef __attribute__((ext_vector_type(8))) __bf16 bf16x8;
typedef __attribute__((ext_vector_type(4))) float  f32x4;

__device__ __forceinline__ ushort_t f2b(float f) {  // f32 -> bf16 RNE
  union { float f; unsigned u; } a; a.f = f;
  unsigned u = a.u;
  return (ushort_t)((u + 0x7FFFu + ((u >> 16) & 1u)) >> 16);
}
__device__ __forceinline__ float b2f(ushort_t h) {
  union { unsigned u; float f; } a; a.u = ((unsigned)h) << 16;
  return a.f;
}

#define GLOAD_LDS(g, l) __builtin_amdgcn_global_load_lds( \
    (const __attribute__((address_space(1))) void*)(g),   \
    (__attribute__((address_space(3))) void*)(l), 16, 0, 0)

// ---------------- routing: exact sequential capacity semantics ----------------
__global__ void route_kernel(const int* __restrict__ routes, const int* __restrict__ capp,
                             int* __restrict__ gidx, int* __restrict__ slot,
                             int* __restrict__ counts, int* __restrict__ nfb) {
  const int e = blockIdx.x;
  const int t = threadIdx.x, lane = t & 63, w = t >> 6;
  int cap = *capp; if (cap > CAPC) cap = CAPC;
  if (e == 0 && t == 0) *nfb = 0;
  __shared__ int wtot[16];
  int base = 0;
  for (int i0 = 0; i0 < NASSIGN; i0 += 1024) {
    int i = i0 + t;
    int r = routes[i];
    bool mine = (r == e);
    unsigned long long mask = __ballot(mine);
    int pre = __popcll(mask & ((1ull << lane) - 1ull));
    if (lane == 0) wtot[w] = __popcll(mask);
    __syncthreads();
    int tot = 0;
#pragma unroll
    for (int j = 0; j < 16; ++j) { int c = wtot[j]; if (j < w) pre += c; tot += c; }
    if (e == 0 && (unsigned)r >= NEXP) slot[i] = -1;  // defensive (never triggers)
    if (mine) {
      int pos = base + pre;
      if (pos < cap) { gidx[e * CAPC + pos] = i >> 1; slot[i] = e * CAPC + pos; }
      else slot[i] = -1;
    }
    base += tot;
    __syncthreads();
  }
  if (t == 0) counts[e] = base < cap ? base : cap;
}

// ---------------- build fallback token list (used==0) ----------------
__global__ void fb_list_kernel(const int* __restrict__ slot, int* __restrict__ fbidx,
                               int* __restrict__ nfb) {
  int t = blockIdx.x * 256 + threadIdx.x;
  if (t >= BTOK) return;
  int u = (slot[2 * t] >= 0) + (slot[2 * t + 1] >= 0);
  if (u == 0) { int p = atomicAdd(nfb, 1); fbidx[p] = t; }
}

// ---------------- fused prep: weight cvt + both gathers ----------------
__global__ void prep_kernel(const float* __restrict__ W1, const float* __restrict__ W2,
                            const float* __restrict__ Wf1, const float* __restrict__ Wf2,
                            ushort_t* __restrict__ o1, ushort_t* __restrict__ o2,
                            ushort_t* __restrict__ of1, ushort_t* __restrict__ of2,
                            const float* __restrict__ x, const int* __restrict__ gidx,
                            const int* __restrict__ counts, ushort_t* __restrict__ xg,
                            const int* __restrict__ fbidx, const int* __restrict__ nfbp,
                            ushort_t* __restrict__ xf) {
  int b = blockIdx.x, t = threadIdx.x;
  if (b < 18432) {                       // weight f32 -> bf16
    const float* s; ushort_t* d; int idx;
    if (b < 8192)       { s = W1;  d = o1;  idx = b; }
    else if (b < 16384) { s = W2;  d = o2;  idx = b - 8192; }
    else if (b < 17408) { s = Wf1; d = of1; idx = b - 16384; }
    else                { s = Wf2; d = of2; idx = b - 17408; }
    int i = idx * 256 + t;
    float4 v = ((const float4*)s)[i];
    ushort4 o; o.x = f2b(v.x); o.y = f2b(v.y); o.z = f2b(v.z); o.w = f2b(v.w);
    ((ushort4*)d)[i] = o;
  } else if (b < 28672) {                // gather accepted rows -> xg
    int row = b - 18432;
    int e = row / CAPC, p = row % CAPC;
    int d = t * 4;
    ushort4 o = {0, 0, 0, 0};
    if (p < counts[e]) {
      int tok = gidx[row];
      float4 v = *(const float4*)(x + (size_t)tok * DM + d);
      o.x = f2b(v.x); o.y = f2b(v.y); o.z = f2b(v.z); o.w = f2b(v.w);
    }
    *(ushort4*)(xg + (size_t)row * DM + d) = o;
  } else {                               // gather fallback rows -> xf
    int row = b - 28672;
    int n = *nfbp;
    int nr = (n + 127) & ~127;
    if (row >= nr) return;
    int d = t * 4;
    ushort4 o = {0, 0, 0, 0};
    if (row < n) {
      int tok = fbidx[row];
      float4 v = *(const float4*)(x + (size_t)tok * DM + d);
      o.x = f2b(v.x); o.y = f2b(v.y); o.z = f2b(v.z); o.w = f2b(v.w);
    }
    *(ushort4*)(xf + (size_t)row * DM + d) = o;
  }
}

// ---------------- fused layer GEMM: expert part + fallback part ----------------
// C[m,n] = A[m,k]*W[n,k] + bias[n].  256x256 tile, BK=64, 8 waves (2Mx4N),
// per-wave 128x64 output, full-tile double-buffer (128KB LDS), counted
// vmcnt(8), second barrier closes the read phase before restaging (r6,
// race-free, verified).  LDS 16B-slot XOR swizzle both-sides (conflicts 0).
//
// r7: EXPERT = XCD affinity.  HW dispatch round-robins blocks over the 8
// XCDs (b&7).  Slot layout per XCD x:
//   s in [0,20):  expert x tile: mgrp = x*5 + s/4, ntile = s&3
//     -> per-XCD L2 working set = W_x (2MB) + A_x (2.5MB): L2-resident,
//        each W byte enters exactly ONE XCD's L2 (r6 thrashed all 8).
//   s in [20,36): fb tile fl=(s-20)*8+x: mgrp=fl/4, ntile=fl&3 (=x&3:
//     one fb N-panel per XCD); active fb M-tiles spread across XCDs.
template <int RELU, int FBSCAT>
__global__ __launch_bounds__(512, 2) void layer_kernel(
    const ushort_t* __restrict__ Ae, const ushort_t* __restrict__ We,
    const float* __restrict__ be, ushort_t* __restrict__ Ce,
    const ushort_t* __restrict__ Af, const ushort_t* __restrict__ Wf,
    const float* __restrict__ bfp, ushort_t* __restrict__ Cf,
    float* __restrict__ outF, const int* __restrict__ scat,
    const int* __restrict__ nfbp) {
  const int b = blockIdx.x;
  const int xcd = b & 7, s = b >> 3;
  const ushort_t* A; const ushort_t* W; const float* bias; ushort_t* C;
  int mgrp, ntile; bool isfb;
  if (s < SLOTS_E) {
    const int e = xcd;
    mgrp = e * 5 + (s >> 2); ntile = s & 3;
    A = Ae; W = We + (size_t)e * DM * DM; bias = be + e * DM; C = Ce; isfb = false;
  } else {
    int fl = (s - SLOTS_E) * 8 + xcd;       // 0..127
    mgrp = fl >> 2; ntile = fl & 3;
    if (mgrp * 256 >= *nfbp) return;
    A = Af; W = Wf; bias = bfp; C = Cf; isfb = true;
  }
  const int tid = threadIdx.x, lane = tid & 63, w = tid >> 6;
  const int wr = w >> 2, wc = w & 3;
  __shared__ ushort_t lA[2][256 * 64];   // 64KB
  __shared__ ushort_t lB[2][256 * 64];   // 64KB
  const size_t Abase = (size_t)mgrp * 256 * DM;
  const size_t Wbase = (size_t)ntile * 256 * DM;
  f32x4 acc[8][4] = {};

  // staging: 8-row 1KB segments; wave w stages A rows [w*32,w*32+32) and the
  // same B rows -> 4+4 global_load_lds per wave per K-tile (8 in flight each).
  const int sub8 = lane >> 3;              // row within 8-row seg
  const int slt  = lane & 7;               // linear 16B slot this lane fills
  const int gcol = (slt ^ sub8) * 8;       // inverse-swizzled source k-offset

#define STAGE(T, BUF) do { int kt_ = (T) * 64;                                   \
    _Pragma("unroll")                                                            \
    for (int j_ = 0; j_ < 4; ++j_) {                                             \
      int seg_ = w * 4 + j_; int row_ = seg_ * 8 + sub8;                         \
      GLOAD_LDS(A + Abase + (size_t)row_ * DM + kt_ + gcol, &lA[BUF][seg_*512]); \
      GLOAD_LDS(W + Wbase + (size_t)row_ * DM + kt_ + gcol, &lB[BUF][seg_*512]); \
    } } while (0)

  const int fr = lane & 15, g = lane >> 4;
  const int s0 = ((g)     ^ (fr & 7)) * 8;   // swizzled 16B-slot, k-half 0
  const int s1 = ((4 + g) ^ (fr & 7)) * 8;   // swizzled 16B-slot, k-half 1

  STAGE(0, 0); STAGE(1, 1);                  // 16 vmem instrs/wave in flight
  for (int t = 0; t < 16; ++t) {
    if (t < 15) asm volatile("s_waitcnt vmcnt(8)" ::: "memory");
    else        asm volatile("s_waitcnt vmcnt(0)" ::: "memory");
    __builtin_amdgcn_s_barrier();            // tile t ready for ALL waves
    const ushort_t* bA = lA[t & 1];
    const ushort_t* bB = lB[t & 1];
    bf16x8 av[8], bv[4];
    // k-half 0
#pragma unroll
    for (int m = 0; m < 8; ++m)
      av[m] = *(const bf16x8*)&bA[(wr * 128 + m * 16 + fr) * 64 + s0];
#pragma unroll
    for (int n = 0; n < 4; ++n)
      bv[n] = *(const bf16x8*)&bB[(wc * 64 + n * 16 + fr) * 64 + s0];
#pragma unroll
    for (int m = 0; m < 8; ++m)
#pragma unroll
      for (int n = 0; n < 4; ++n)
        acc[m][n] = __builtin_amdgcn_mfma_f32_16x16x32_bf16(av[m], bv[n], acc[m][n], 0, 0, 0);
    // k-half 1
#pragma unroll
    for (int m = 0; m < 8; ++m)
      av[m] = *(const bf16x8*)&bA[(wr * 128 + m * 16 + fr) * 64 + s1];
#pragma unroll
    for (int n = 0; n < 4; ++n)
      bv[n] = *(const bf16x8*)&bB[(wc * 64 + n * 16 + fr) * 64 + s1];
#pragma unroll
    for (int m = 0; m < 8; ++m)
#pragma unroll
      for (int n = 0; n < 4; ++n)
        acc[m][n] = __builtin_amdgcn_mfma_f32_16x16x32_bf16(av[m], bv[n], acc[m][n], 0, 0, 0);
    // close read phase: all waves' ds_reads of buf[t&1] are consumed (lgkm
    // drained before their MFMAs); barrier orders reads before the restage.
    __builtin_amdgcn_s_barrier();
    __builtin_amdgcn_sched_barrier(0);
    if (t + 2 < 16) STAGE(t + 2, t & 1);
  }
#undef STAGE

  // epilogue: C/D layout col=lane&15, row=(lane>>4)*4+reg  [m89-verified]
  int nfbv = (FBSCAT && isfb) ? *nfbp : 0;
#pragma unroll
  for (int n = 0; n < 4; ++n) {
    int col = ntile * 256 + wc * 64 + n * 16 + fr;
    float bb = bias[col];
#pragma unroll
    for (int m = 0; m < 8; ++m) {
      int row0 = mgrp * 256 + wr * 128 + m * 16 + g * 4;
#pragma unroll
      for (int r = 0; r < 4; ++r) {
        float v = acc[m][n][r] + bb;
        if (RELU) v = v > 0.0f ? v : 0.0f;
        int row = row0 + r;
        if (FBSCAT && isfb) {
          if (row < nfbv) outF[(size_t)scat[row] * DM + col] = v;
        } else {
          C[(size_t)row * DM + col] = f2b(v);
        }
      }
    }
  }
}

// ---------------- combine accepted expert outputs per token ----------------
__global__ void combine_kernel(const ushort_t* __restrict__ Y, const int* __restrict__ slot,
                               float* __restrict__ out) {
  int t = blockIdx.x;
  int s0 = slot[2 * t], s1 = slot[2 * t + 1];
  int u = (s0 >= 0) + (s1 >= 0);
  if (u == 0) return;  // fallback GEMM scatter writes these rows
  int d = threadIdx.x * 4;
  float a0 = 0, a1 = 0, a2 = 0, a3 = 0;
  if (s0 >= 0) {
    ushort4 q = *(const ushort4*)(Y + (size_t)s0 * DM + d);
    a0 += b2f(q.x); a1 += b2f(q.y); a2 += b2f(q.z); a3 += b2f(q.w);
  }
  if (s1 >= 0) {
    ushort4 q = *(const ushort4*)(Y + (size_t)s1 * DM + d);
    a0 += b2f(q.x); a1 += b2f(q.y); a2 += b2f(q.z); a3 += b2f(q.w);
  }
  float inv = 1.0f / (float)u;
  float4 o = make_float4(a0 * inv, a1 * inv, a2 * inv, a3 * inv);
  *(float4*)(out + (size_t)t * DM + d) = o;
}

// ---------------- launch ----------------
extern "C" void kernel_launch(void* const* d_in, const int* in_sizes, int n_in,
                              void* d_out, int out_size, void* d_ws, size_t ws_size,
                              hipStream_t stream) {
  const float* x   = (const float*)d_in[0];
  const float* W1  = (const float*)d_in[1];
  const float* b1  = (const float*)d_in[2];
  const float* W2  = (const float*)d_in[3];
  const float* b2  = (const float*)d_in[4];
  const float* Wf1 = (const float*)d_in[5];
  const float* bf1 = (const float*)d_in[6];
  const float* Wf2 = (const float*)d_in[7];
  const float* bf2 = (const float*)d_in[8];
  const int* routes = (const int*)d_in[9];
  const int* capp   = (const int*)d_in[10];
  float* out = (float*)d_out;

  char* ws = (char*)d_ws;
  size_t off = 0;
  auto alloc = [&](size_t bytes) -> void* {
    void* p = ws + off; off += (bytes + 255) & ~255ull; return p;
  };
  ushort_t* W1b  = (ushort_t*)alloc((size_t)NEXP * DM * DM * 2);
  ushort_t* W2b  = (ushort_t*)alloc((size_t)NEXP * DM * DM * 2);
  ushort_t* Wf1b = (ushort_t*)alloc((size_t)DM * DM * 2);
  ushort_t* Wf2b = (ushort_t*)alloc((size_t)DM * DM * 2);
  ushort_t* xg   = (ushort_t*)alloc((size_t)MROWS * DM * 2);
  ushort_t* H    = (ushort_t*)alloc((size_t)MROWS * DM * 2);
  ushort_t* Y    = (ushort_t*)alloc((size_t)MROWS * DM * 2);
  ushort_t* xf   = (ushort_t*)alloc((size_t)BTOK * DM * 2);
  ushort_t* Hf   = (ushort_t*)alloc((size_t)BTOK * DM * 2);
  int* gidx   = (int*)alloc(MROWS * 4);
  int* slot   = (int*)alloc(NASSIGN * 4);
  int* counts = (int*)alloc(NEXP * 4);
  int* fbidx  = (int*)alloc(BTOK * 4);
  int* nfb    = (int*)alloc(4);

  route_kernel<<<NEXP, 1024, 0, stream>>>(routes, capp, gidx, slot, counts, nfb);
  fb_list_kernel<<<BTOK / 256, 256, 0, stream>>>(slot, fbidx, nfb);
  prep_kernel<<<36864, 256, 0, stream>>>(W1, W2, Wf1, Wf2, W1b, W2b, Wf1b, Wf2b,
                                         x, gidx, counts, xg, fbidx, nfb, xf);
  layer_kernel<1, 0><<<GRID_L, 512, 0, stream>>>(xg, W1b, b1, H, xf, Wf1b, bf1, Hf,
                                                 nullptr, nullptr, nfb);
  layer_kernel<0, 1><<<GRID_L, 512, 0, stream>>>(H, W2b, b2, Y, Hf, Wf2b, bf2, nullptr,
                                                 out, fbidx, nfb);
  combine_kernel<<<BTOK, 256, 0, stream>>>(Y, slot, out);
}

// Round 9
// 151.212 us; speedup vs baseline: 1.4195x; 1.0060x over previous
//
#include <hip/hip_runtime.h>

// ---------------- problem constants ----------------
#define DM    1024          // d_model
#define NEXP  8             // experts
#define BTOK  8192          // tokens
#define KTOP  2             // routes per token
#define NASSIGN (BTOK*KTOP) // 16384
#define CAPC  1280          // capacity (10 * 128 -> tile-aligned)
#define MROWS (NEXP*CAPC)   // 10240 expert rows

// GEMM geometry: 128x128 tile, BK=32, 4 waves (2x2), acc[4][4]
#define MTILES_E (MROWS/128)   // 80 (10 per expert)
#define MTILES_F (BTOK/128)    // 64
#define NTILES   (DM/128)      // 8
#define SLOTS_E  (10*NTILES)   // 80 expert-tile slots per XCD
#define SLOTS_F  (MTILES_F*NTILES/8)  // 64 fb slots per XCD
#define SLOTS    (SLOTS_E+SLOTS_F)    // 144
#define GRID_L   (8*SLOTS)            // 1152

typedef unsigned short ushort_t;
typedef __attribute__((ext_vector_type(8))) __bf16 bf16x8;
typedef __attribute__((ext_vector_type(4))) float  f32x4;

__device__ __forceinline__ ushort_t f2b(float f) {  // f32 -> bf16 RNE
  union { float f; unsigned u; } a; a.f = f;
  unsigned u = a.u;
  return (ushort_t)((u + 0x7FFFu + ((u >> 16) & 1u)) >> 16);
}
__device__ __forceinline__ float b2f(ushort_t h) {
  union { unsigned u; float f; } a; a.u = ((unsigned)h) << 16;
  return a.f;
}

#define GLOAD_LDS(g, l) __builtin_amdgcn_global_load_lds( \
    (const __attribute__((address_space(1))) void*)(g),   \
    (__attribute__((address_space(3))) void*)(l), 16, 0, 0)

// ---------------- routing: exact sequential capacity semantics ----------------
__global__ void route_kernel(const int* __restrict__ routes, const int* __restrict__ capp,
                             int* __restrict__ gidx, int* __restrict__ slot,
                             int* __restrict__ counts, int* __restrict__ nfb) {
  const int e = blockIdx.x;
  const int t = threadIdx.x, lane = t & 63, w = t >> 6;
  int cap = *capp; if (cap > CAPC) cap = CAPC;
  if (e == 0 && t == 0) *nfb = 0;
  __shared__ int wtot[16];
  int base = 0;
  for (int i0 = 0; i0 < NASSIGN; i0 += 1024) {
    int i = i0 + t;
    int r = routes[i];
    bool mine = (r == e);
    unsigned long long mask = __ballot(mine);
    int pre = __popcll(mask & ((1ull << lane) - 1ull));
    if (lane == 0) wtot[w] = __popcll(mask);
    __syncthreads();
    int tot = 0;
#pragma unroll
    for (int j = 0; j < 16; ++j) { int c = wtot[j]; if (j < w) pre += c; tot += c; }
    if (e == 0 && (unsigned)r >= NEXP) slot[i] = -1;  // defensive (never triggers)
    if (mine) {
      int pos = base + pre;
      if (pos < cap) { gidx[e * CAPC + pos] = i >> 1; slot[i] = e * CAPC + pos; }
      else slot[i] = -1;
    }
    base += tot;
    __syncthreads();
  }
  if (t == 0) counts[e] = base < cap ? base : cap;
}

// ---------------- build fallback token list (used==0) ----------------
__global__ void fb_list_kernel(const int* __restrict__ slot, int* __restrict__ fbidx,
                               int* __restrict__ nfb) {
  int t = blockIdx.x * 256 + threadIdx.x;
  if (t >= BTOK) return;
  int u = (slot[2 * t] >= 0) + (slot[2 * t + 1] >= 0);
  if (u == 0) { int p = atomicAdd(nfb, 1); fbidx[p] = t; }
}

// ---------------- fused prep: weight cvt + both gathers ----------------
__global__ void prep_kernel(const float* __restrict__ W1, const float* __restrict__ W2,
                            const float* __restrict__ Wf1, const float* __restrict__ Wf2,
                            ushort_t* __restrict__ o1, ushort_t* __restrict__ o2,
                            ushort_t* __restrict__ of1, ushort_t* __restrict__ of2,
                            const float* __restrict__ x, const int* __restrict__ gidx,
                            const int* __restrict__ counts, ushort_t* __restrict__ xg,
                            const int* __restrict__ fbidx, const int* __restrict__ nfbp,
                            ushort_t* __restrict__ xf) {
  int b = blockIdx.x, t = threadIdx.x;
  if (b < 18432) {                       // weight f32 -> bf16
    const float* s; ushort_t* d; int idx;
    if (b < 8192)       { s = W1;  d = o1;  idx = b; }
    else if (b < 16384) { s = W2;  d = o2;  idx = b - 8192; }
    else if (b < 17408) { s = Wf1; d = of1; idx = b - 16384; }
    else                { s = Wf2; d = of2; idx = b - 17408; }
    int i = idx * 256 + t;
    float4 v = ((const float4*)s)[i];
    ushort4 o; o.x = f2b(v.x); o.y = f2b(v.y); o.z = f2b(v.z); o.w = f2b(v.w);
    ((ushort4*)d)[i] = o;
  } else if (b < 28672) {                // gather accepted rows -> xg
    int row = b - 18432;
    int e = row / CAPC, p = row % CAPC;
    int d = t * 4;
    ushort4 o = {0, 0, 0, 0};
    if (p < counts[e]) {
      int tok = gidx[row];
      float4 v = *(const float4*)(x + (size_t)tok * DM + d);
      o.x = f2b(v.x); o.y = f2b(v.y); o.z = f2b(v.z); o.w = f2b(v.w);
    }
    *(ushort4*)(xg + (size_t)row * DM + d) = o;
  } else {                               // gather fallback rows -> xf
    int row = b - 28672;
    int n = *nfbp;
    int nr = (n + 127) & ~127;
    if (row >= nr) return;
    int d = t * 4;
    ushort4 o = {0, 0, 0, 0};
    if (row < n) {
      int tok = fbidx[row];
      float4 v = *(const float4*)(x + (size_t)tok * DM + d);
      o.x = f2b(v.x); o.y = f2b(v.y); o.z = f2b(v.z); o.w = f2b(v.w);
    }
    *(ushort4*)(xf + (size_t)row * DM + d) = o;
  }
}

// ---------------- fused layer GEMM: expert part + fallback part ----------------
// C[m,n] = A[m,k]*W[n,k] + bias[n].  128x128 tile, BK=32, 4 waves (2x2).
// r8 structure: SIMPLE 2-phase dbuf with ONE __syncthreads per K-step (its
// vmcnt(0) drain is the tile-ready guarantee), 32KB LDS, launch_bounds(256,3)
// -> ~3 blocks/CU (cross-block TLP that the 256^2 1-block/CU variants lost).
// Stage(t+1) issued right after the barrier into buf p^1 (its prior readers
// passed this barrier in iter t-1: race-free).  XCD expert affinity kept
// (r7: FETCH 72->33MB).  LDS XOR swizzle kept (conflicts 0).  LDS-staged
// coalesced epilogue kills the ~2x write amplification (r6/r7: 52-64MB vs
// 26MB unique).
template <int RELU, int FBSCAT>
__global__ __launch_bounds__(256, 3) void layer_kernel(
    const ushort_t* __restrict__ Ae, const ushort_t* __restrict__ We,
    const float* __restrict__ be, ushort_t* __restrict__ Ce,
    const ushort_t* __restrict__ Af, const ushort_t* __restrict__ Wf,
    const float* __restrict__ bfp, ushort_t* __restrict__ Cf,
    float* __restrict__ outF, const int* __restrict__ scat,
    const int* __restrict__ nfbp) {
  const int b = blockIdx.x;
  const int xcd = b & 7, s = b >> 3;
  const ushort_t* A; const ushort_t* W; const float* bias; ushort_t* C;
  int mgrp, ntile; bool isfb;
  if (s < SLOTS_E) {
    const int e = xcd;                       // expert = XCD (L2 affinity)
    mgrp = e * 10 + (s >> 3); ntile = s & 7; // N-fastest: W_e stays L2-hot
    A = Ae; W = We + (size_t)e * DM * DM; bias = be + e * DM; C = Ce; isfb = false;
  } else {
    int fl = (s - SLOTS_E) * 8 + xcd;        // 0..511 spread over XCDs
    mgrp = fl >> 3; ntile = fl & 7;
    if (mgrp * 128 >= *nfbp) return;
    A = Af; W = Wf; bias = bfp; C = Cf; isfb = true;
  }
  const int tid = threadIdx.x, lane = tid & 63, w = tid >> 6;
  const int wr = w >> 1, wc = w & 1;
  __shared__ ushort_t smem[16384];           // 32KB: dbuf A/B; reused for C
  const size_t Abase = (size_t)mgrp * 128 * DM;
  const size_t Wbase = (size_t)ntile * 128 * DM;
  f32x4 acc[4][4] = {};

  // staging: per operand 8 segs of 16 rows x 32k (1KB); wave w stages segs
  // {2w,2w+1} of A and of B -> 4 global_load_lds per wave per K-tile.
  const int sub  = lane >> 2;                     // row within 16-row seg
  const int slt  = lane & 3;                      // 16B k-slot
  const int gcol = (slt ^ ((sub >> 1) & 3)) * 8;  // inverse-swizzled source k-off
  const int r0 = (w * 2)     * 16 + sub;
  const int r1 = (w * 2 + 1) * 16 + sub;

  // LDS layout: buf0 A @0, buf1 A @4096, buf0 B @8192, buf1 B @12288 (elems)
#define STAGE(T, BUF) do { int kt_ = (T) * 32; int ao_ = (BUF) * 4096;          \
    GLOAD_LDS(A + Abase + (size_t)r0 * DM + kt_ + gcol, smem + ao_ + (w*2)  *512); \
    GLOAD_LDS(A + Abase + (size_t)r1 * DM + kt_ + gcol, smem + ao_ + (w*2+1)*512); \
    GLOAD_LDS(W + Wbase + (size_t)r0 * DM + kt_ + gcol, smem + 8192 + ao_ + (w*2)  *512); \
    GLOAD_LDS(W + Wbase + (size_t)r1 * DM + kt_ + gcol, smem + 8192 + ao_ + (w*2+1)*512); \
  } while (0)

  const int fr    = lane & 15, g = lane >> 4;
  const int rslot = (g ^ ((fr >> 1) & 3)) * 8;    // swizzled read k-off

  STAGE(0, 0);
  for (int t = 0; t < 32; ++t) {
    __syncthreads();                    // vmcnt(0) drain: tile t landed; and
                                        // buf[p^1]'s readers (iter t-1) passed
    if (t + 1 < 32) STAGE(t + 1, (t + 1) & 1);
    const ushort_t* bA = smem + (t & 1) * 4096;
    const ushort_t* bB = smem + 8192 + (t & 1) * 4096;
    bf16x8 av[4], bv[4];
#pragma unroll
    for (int m = 0; m < 4; ++m)
      av[m] = *(const bf16x8*)&bA[(wr * 64 + m * 16 + fr) * 32 + rslot];
#pragma unroll
    for (int n = 0; n < 4; ++n)
      bv[n] = *(const bf16x8*)&bB[(wc * 64 + n * 16 + fr) * 32 + rslot];
#pragma unroll
    for (int m = 0; m < 4; ++m)
#pragma unroll
      for (int n = 0; n < 4; ++n)
        acc[m][n] = __builtin_amdgcn_mfma_f32_16x16x32_bf16(av[m], bv[n], acc[m][n], 0, 0, 0);
  }
#undef STAGE

  // epilogue.  C/D layout col=lane&15, row=(lane>>4)*4+reg  [m89-verified]
  if (FBSCAT && isfb) {                 // fb layer-2: f32 scatter (small)
    int nfbv = *nfbp;
#pragma unroll
    for (int n = 0; n < 4; ++n) {
      int col = ntile * 128 + wc * 64 + n * 16 + fr;
      float bb = bias[col];
#pragma unroll
      for (int m = 0; m < 4; ++m) {
        int row0 = mgrp * 128 + wr * 64 + m * 16 + g * 4;
#pragma unroll
        for (int r = 0; r < 4; ++r) {
          int row = row0 + r;
          if (row < nfbv) outF[(size_t)scat[row] * DM + col] = acc[m][n][r] + bb;
        }
      }
    }
  } else {                              // bf16 C: LDS repack + coalesced store
    __syncthreads();                    // all staging reads done; reuse smem
#pragma unroll
    for (int n = 0; n < 4; ++n) {
      int col = wc * 64 + n * 16 + fr;
      float bb = bias[ntile * 128 + col];
#pragma unroll
      for (int m = 0; m < 4; ++m) {
        int lrow0 = wr * 64 + m * 16 + g * 4;
#pragma unroll
        for (int r = 0; r < 4; ++r) {
          float v = acc[m][n][r] + bb;
          if (RELU) v = v > 0.0f ? v : 0.0f;
          smem[(lrow0 + r) * 128 + col] = f2b(v);
        }
      }
    }
    __syncthreads();
    // linear copy: 2048 chunks of 16B; wave-contiguous global stores
    ushort_t* Cb = C + (size_t)mgrp * 128 * DM + ntile * 128;
#pragma unroll
    for (int q = 0; q < 8; ++q) {
      int chunk = q * 256 + tid;        // 0..2047
      int row = chunk >> 4, co = (chunk & 15) * 8;
      bf16x8 v = *(const bf16x8*)&smem[row * 128 + co];
      *(bf16x8*)(Cb + (size_t)row * DM + co) = v;
    }
  }
}

// ---------------- combine accepted expert outputs per token ----------------
__global__ void combine_kernel(const ushort_t* __restrict__ Y, const int* __restrict__ slot,
                               float* __restrict__ out) {
  int t = blockIdx.x;
  int s0 = slot[2 * t], s1 = slot[2 * t + 1];
  int u = (s0 >= 0) + (s1 >= 0);
  if (u == 0) return;  // fallback GEMM scatter writes these rows
  int d = threadIdx.x * 4;
  float a0 = 0, a1 = 0, a2 = 0, a3 = 0;
  if (s0 >= 0) {
    ushort4 q = *(const ushort4*)(Y + (size_t)s0 * DM + d);
    a0 += b2f(q.x); a1 += b2f(q.y); a2 += b2f(q.z); a3 += b2f(q.w);
  }
  if (s1 >= 0) {
    ushort4 q = *(const ushort4*)(Y + (size_t)s1 * DM + d);
    a0 += b2f(q.x); a1 += b2f(q.y); a2 += b2f(q.z); a3 += b2f(q.w);
  }
  float inv = 1.0f / (float)u;
  float4 o = make_float4(a0 * inv, a1 * inv, a2 * inv, a3 * inv);
  *(float4*)(out + (size_t)t * DM + d) = o;
}

// ---------------- launch ----------------
extern "C" void kernel_launch(void* const* d_in, const int* in_sizes, int n_in,
                              void* d_out, int out_size, void* d_ws, size_t ws_size,
                              hipStream_t stream) {
  const float* x   = (const float*)d_in[0];
  const float* W1  = (const float*)d_in[1];
  const float* b1  = (const float*)d_in[2];
  const float* W2  = (const float*)d_in[3];
  const float* b2  = (const float*)d_in[4];
  const float* Wf1 = (const float*)d_in[5];
  const float* bf1 = (const float*)d_in[6];
  const float* Wf2 = (const float*)d_in[7];
  const float* bf2 = (const float*)d_in[8];
  const int* routes = (const int*)d_in[9];
  const int* capp   = (const int*)d_in[10];
  float* out = (float*)d_out;

  char* ws = (char*)d_ws;
  size_t off = 0;
  auto alloc = [&](size_t bytes) -> void* {
    void* p = ws + off; off += (bytes + 255) & ~255ull; return p;
  };
  ushort_t* W1b  = (ushort_t*)alloc((size_t)NEXP * DM * DM * 2);
  ushort_t* W2b  = (ushort_t*)alloc((size_t)NEXP * DM * DM * 2);
  ushort_t* Wf1b = (ushort_t*)alloc((size_t)DM * DM * 2);
  ushort_t* Wf2b = (ushort_t*)alloc((size_t)DM * DM * 2);
  ushort_t* xg   = (ushort_t*)alloc((size_t)MROWS * DM * 2);
  ushort_t* H    = (ushort_t*)alloc((size_t)MROWS * DM * 2);
  ushort_t* Y    = (ushort_t*)alloc((size_t)MROWS * DM * 2);
  ushort_t* xf   = (ushort_t*)alloc((size_t)BTOK * DM * 2);
  ushort_t* Hf   = (ushort_t*)alloc((size_t)BTOK * DM * 2);
  int* gidx   = (int*)alloc(MROWS * 4);
  int* slot   = (int*)alloc(NASSIGN * 4);
  int* counts = (int*)alloc(NEXP * 4);
  int* fbidx  = (int*)alloc(BTOK * 4);
  int* nfb    = (int*)alloc(4);

  route_kernel<<<NEXP, 1024, 0, stream>>>(routes, capp, gidx, slot, counts, nfb);
  fb_list_kernel<<<BTOK / 256, 256, 0, stream>>>(slot, fbidx, nfb);
  prep_kernel<<<36864, 256, 0, stream>>>(W1, W2, Wf1, Wf2, W1b, W2b, Wf1b, Wf2b,
                                         x, gidx, counts, xg, fbidx, nfb, xf);
  layer_kernel<1, 0><<<GRID_L, 256, 0, stream>>>(xg, W1b, b1, H, xf, Wf1b, bf1, Hf,
                                                 nullptr, nullptr, nfb);
  layer_kernel<0, 1><<<GRID_L, 256, 0, stream>>>(H, W2b, b2, Y, Hf, Wf2b, bf2, nullptr,
                                                 out, fbidx, nfb);
  combine_kernel<<<BTOK, 256, 0, stream>>>(Y, slot, out);
}

// Round 10
// 149.919 us; speedup vs baseline: 1.4318x; 1.0086x over previous
//
#include <hip/hip_runtime.h>

// ---------------- problem constants ----------------
#define DM    1024          // d_model
#define NEXP  8             // experts
#define BTOK  8192          // tokens
#define KTOP  2             // routes per token
#define NASSIGN (BTOK*KTOP) // 16384
#define CAPC  1280          // capacity (10 * 128 -> tile-aligned)
#define MROWS (NEXP*CAPC)   // 10240 expert rows

// GEMM geometry: 128x128 tile, BK=32, 4 waves (2x2), acc[4][4]
#define MTILES_E (MROWS/128)   // 80 (10 per expert)
#define MTILES_F (BTOK/128)    // 64
#define NTILES   (DM/128)      // 8
#define SLOTS_E  (10*NTILES)   // 80 expert-tile slots per XCD
#define SLOTS_F  (MTILES_F*NTILES/8)  // 64 fb slots per XCD
#define SLOTS    (SLOTS_E+SLOTS_F)    // 144
#define GRID_L   (8*SLOTS)            // 1152

typedef unsigned short ushort_t;
typedef __attribute__((ext_vector_type(8))) __bf16 bf16x8;
typedef __attribute__((ext_vector_type(4))) float  f32x4;

__device__ __forceinline__ ushort_t f2b(float f) {  // f32 -> bf16 RNE
  union { float f; unsigned u; } a; a.f = f;
  unsigned u = a.u;
  return (ushort_t)((u + 0x7FFFu + ((u >> 16) & 1u)) >> 16);
}
__device__ __forceinline__ float b2f(ushort_t h) {
  union { unsigned u; float f; } a; a.u = ((unsigned)h) << 16;
  return a.f;
}

#define GLOAD_LDS(g, l) __builtin_amdgcn_global_load_lds( \
    (const __attribute__((address_space(1))) void*)(g),   \
    (__attribute__((address_space(3))) void*)(l), 16, 0, 0)

// ---------------- routing: exact sequential capacity semantics ----------------
__global__ void route_kernel(const int* __restrict__ routes, const int* __restrict__ capp,
                             int* __restrict__ gidx, int* __restrict__ slot,
                             int* __restrict__ counts, int* __restrict__ nfb) {
  const int e = blockIdx.x;
  const int t = threadIdx.x, lane = t & 63, w = t >> 6;
  int cap = *capp; if (cap > CAPC) cap = CAPC;
  if (e == 0 && t == 0) *nfb = 0;
  __shared__ int wtot[16];
  int base = 0;
  for (int i0 = 0; i0 < NASSIGN; i0 += 1024) {
    int i = i0 + t;
    int r = routes[i];
    bool mine = (r == e);
    unsigned long long mask = __ballot(mine);
    int pre = __popcll(mask & ((1ull << lane) - 1ull));
    if (lane == 0) wtot[w] = __popcll(mask);
    __syncthreads();
    int tot = 0;
#pragma unroll
    for (int j = 0; j < 16; ++j) { int c = wtot[j]; if (j < w) pre += c; tot += c; }
    if (e == 0 && (unsigned)r >= NEXP) slot[i] = -1;  // defensive (never triggers)
    if (mine) {
      int pos = base + pre;
      if (pos < cap) { gidx[e * CAPC + pos] = i >> 1; slot[i] = e * CAPC + pos; }
      else slot[i] = -1;
    }
    base += tot;
    __syncthreads();
  }
  if (t == 0) counts[e] = base < cap ? base : cap;
}

// ---------------- build fallback token list (used==0) ----------------
__global__ void fb_list_kernel(const int* __restrict__ slot, int* __restrict__ fbidx,
                               int* __restrict__ nfb) {
  int t = blockIdx.x * 256 + threadIdx.x;
  if (t >= BTOK) return;
  int u = (slot[2 * t] >= 0) + (slot[2 * t + 1] >= 0);
  if (u == 0) { int p = atomicAdd(nfb, 1); fbidx[p] = t; }
}

// ---------------- fused prep: weight cvt + both gathers ----------------
__global__ void prep_kernel(const float* __restrict__ W1, const float* __restrict__ W2,
                            const float* __restrict__ Wf1, const float* __restrict__ Wf2,
                            ushort_t* __restrict__ o1, ushort_t* __restrict__ o2,
                            ushort_t* __restrict__ of1, ushort_t* __restrict__ of2,
                            const float* __restrict__ x, const int* __restrict__ gidx,
                            const int* __restrict__ counts, ushort_t* __restrict__ xg,
                            const int* __restrict__ fbidx, const int* __restrict__ nfbp,
                            ushort_t* __restrict__ xf) {
  int b = blockIdx.x, t = threadIdx.x;
  if (b < 18432) {                       // weight f32 -> bf16
    const float* s; ushort_t* d; int idx;
    if (b < 8192)       { s = W1;  d = o1;  idx = b; }
    else if (b < 16384) { s = W2;  d = o2;  idx = b - 8192; }
    else if (b < 17408) { s = Wf1; d = of1; idx = b - 16384; }
    else                { s = Wf2; d = of2; idx = b - 17408; }
    int i = idx * 256 + t;
    float4 v = ((const float4*)s)[i];
    ushort4 o; o.x = f2b(v.x); o.y = f2b(v.y); o.z = f2b(v.z); o.w = f2b(v.w);
    ((ushort4*)d)[i] = o;
  } else if (b < 28672) {                // gather accepted rows -> xg
    int row = b - 18432;
    int e = row / CAPC, p = row % CAPC;
    int d = t * 4;
    ushort4 o = {0, 0, 0, 0};
    if (p < counts[e]) {
      int tok = gidx[row];
      float4 v = *(const float4*)(x + (size_t)tok * DM + d);
      o.x = f2b(v.x); o.y = f2b(v.y); o.z = f2b(v.z); o.w = f2b(v.w);
    }
    *(ushort4*)(xg + (size_t)row * DM + d) = o;
  } else {                               // gather fallback rows -> xf
    int row = b - 28672;
    int n = *nfbp;
    int nr = (n + 127) & ~127;
    if (row >= nr) return;
    int d = t * 4;
    ushort4 o = {0, 0, 0, 0};
    if (row < n) {
      int tok = fbidx[row];
      float4 v = *(const float4*)(x + (size_t)tok * DM + d);
      o.x = f2b(v.x); o.y = f2b(v.y); o.z = f2b(v.z); o.w = f2b(v.w);
    }
    *(ushort4*)(xf + (size_t)row * DM + d) = o;
  }
}

// ---------------- fused layer GEMM: expert part + fallback part ----------------
// C[m,n] = A[m,k]*W[n,k] + bias[n].  128x128 tile, BK=32, 4 waves (2x2).
// r10 = r9 + RING-3 distance-2 prefetch with counted vmcnt (one variable):
//   48KB LDS (3 bufs x {A 8KB, B 8KB}), still 3 blocks/CU (144KB <= 160KB).
//   Per iter: s_waitcnt vmcnt(4) (t+1's 4 loads may stay in flight; tile t
//   guaranteed landed) -> raw s_barrier -> stage(t+2) into buf (t+2)%3 =
//   (t-1)%3, whose readers (tile t-1) passed the barrier just crossed ->
//   ds_read tile t -> MFMA.  Never drains vmcnt to 0 until the last iters.
//   This gives the staging loads a 2-iteration (~1200cy) window, covering
//   the L2-hit latency that r9's __syncthreads drain exposed every iter
//   (r5 tried this without XCD affinity -> HBM-class latency, inconclusive).
// XCD expert affinity kept (FETCH 72->33/45MB).  LDS XOR swizzle kept.
// LDS-staged coalesced epilogue kept (WRITE 52->33MB).
template <int RELU, int FBSCAT>
__global__ __launch_bounds__(256, 3) void layer_kernel(
    const ushort_t* __restrict__ Ae, const ushort_t* __restrict__ We,
    const float* __restrict__ be, ushort_t* __restrict__ Ce,
    const ushort_t* __restrict__ Af, const ushort_t* __restrict__ Wf,
    const float* __restrict__ bfp, ushort_t* __restrict__ Cf,
    float* __restrict__ outF, const int* __restrict__ scat,
    const int* __restrict__ nfbp) {
  const int b = blockIdx.x;
  const int xcd = b & 7, s = b >> 3;
  const ushort_t* A; const ushort_t* W; const float* bias; ushort_t* C;
  int mgrp, ntile; bool isfb;
  if (s < SLOTS_E) {
    const int e = xcd;                       // expert = XCD (L2 affinity)
    mgrp = e * 10 + (s >> 3); ntile = s & 7; // N-fastest: W_e stays L2-hot
    A = Ae; W = We + (size_t)e * DM * DM; bias = be + e * DM; C = Ce; isfb = false;
  } else {
    int fl = (s - SLOTS_E) * 8 + xcd;        // 0..511 spread over XCDs
    mgrp = fl >> 3; ntile = fl & 7;
    if (mgrp * 128 >= *nfbp) return;
    A = Af; W = Wf; bias = bfp; C = Cf; isfb = true;
  }
  const int tid = threadIdx.x, lane = tid & 63, w = tid >> 6;
  const int wr = w >> 1, wc = w & 1;
  __shared__ ushort_t smem[24576];           // 48KB: 3-ring A/B; reused for C
  const size_t Abase = (size_t)mgrp * 128 * DM;
  const size_t Wbase = (size_t)ntile * 128 * DM;
  f32x4 acc[4][4] = {};

  // staging: per operand 8 segs of 16 rows x 32k (1KB); wave w stages segs
  // {2w,2w+1} of A and of B -> 4 global_load_lds per wave per K-tile.
  const int sub  = lane >> 2;                     // row within 16-row seg
  const int slt  = lane & 3;                      // 16B k-slot
  const int gcol = (slt ^ ((sub >> 1) & 3)) * 8;  // inverse-swizzled source k-off
  const int r0 = (w * 2)     * 16 + sub;
  const int r1 = (w * 2 + 1) * 16 + sub;

  // LDS layout (elems): A bufs @ {0,4096,8192}; B bufs @ 12288 + {0,4096,8192}
#define STAGE(T, BUF) do { int kt_ = (T) * 32; int ao_ = (BUF) * 4096;          \
    GLOAD_LDS(A + Abase + (size_t)r0 * DM + kt_ + gcol, smem + ao_ + (w*2)  *512); \
    GLOAD_LDS(A + Abase + (size_t)r1 * DM + kt_ + gcol, smem + ao_ + (w*2+1)*512); \
    GLOAD_LDS(W + Wbase + (size_t)r0 * DM + kt_ + gcol, smem + 12288 + ao_ + (w*2)  *512); \
    GLOAD_LDS(W + Wbase + (size_t)r1 * DM + kt_ + gcol, smem + 12288 + ao_ + (w*2+1)*512); \
  } while (0)

  const int fr    = lane & 15, g = lane >> 4;
  const int rslot = (g ^ ((fr >> 1) & 3)) * 8;    // swizzled read k-off

  STAGE(0, 0); STAGE(1, 1);                 // 8 loads/wave in flight
  int cur = 0;                              // buf holding tile t
  for (int t = 0; t < 32; ++t) {
    // tile t landed <=> outstanding <= 4 (only stage(t+1)'s 4 may remain)
    if (t < 31) asm volatile("s_waitcnt vmcnt(4)" ::: "memory");
    else        asm volatile("s_waitcnt vmcnt(0)" ::: "memory");
    __builtin_amdgcn_s_barrier();           // readers of buf (t-1)%3 passed
    __builtin_amdgcn_sched_barrier(0);      // no read hoisting above barrier
    if (t + 2 < 32) {
      int nb = cur + 2; if (nb >= 3) nb -= 3;
      STAGE(t + 2, nb);                     // targets buf (t-1)%3: race-free
    }
    const ushort_t* bA = smem + cur * 4096;
    const ushort_t* bB = smem + 12288 + cur * 4096;
    bf16x8 av[4], bv[4];
#pragma unroll
    for (int m = 0; m < 4; ++m)
      av[m] = *(const bf16x8*)&bA[(wr * 64 + m * 16 + fr) * 32 + rslot];
#pragma unroll
    for (int n = 0; n < 4; ++n)
      bv[n] = *(const bf16x8*)&bB[(wc * 64 + n * 16 + fr) * 32 + rslot];
#pragma unroll
    for (int m = 0; m < 4; ++m)
#pragma unroll
      for (int n = 0; n < 4; ++n)
        acc[m][n] = __builtin_amdgcn_mfma_f32_16x16x32_bf16(av[m], bv[n], acc[m][n], 0, 0, 0);
    cur = (cur == 2) ? 0 : cur + 1;
  }
#undef STAGE

  // epilogue.  C/D layout col=lane&15, row=(lane>>4)*4+reg  [m89-verified]
  if (FBSCAT && isfb) {                 // fb layer-2: f32 scatter (small)
    int nfbv = *nfbp;
#pragma unroll
    for (int n = 0; n < 4; ++n) {
      int col = ntile * 128 + wc * 64 + n * 16 + fr;
      float bb = bias[col];
#pragma unroll
      for (int m = 0; m < 4; ++m) {
        int row0 = mgrp * 128 + wr * 64 + m * 16 + g * 4;
#pragma unroll
        for (int r = 0; r < 4; ++r) {
          int row = row0 + r;
          if (row < nfbv) outF[(size_t)scat[row] * DM + col] = acc[m][n][r] + bb;
        }
      }
    }
  } else {                              // bf16 C: LDS repack + coalesced store
    __syncthreads();                    // all staging reads done; reuse smem
#pragma unroll
    for (int n = 0; n < 4; ++n) {
      int col = wc * 64 + n * 16 + fr;
      float bb = bias[ntile * 128 + col];
#pragma unroll
      for (int m = 0; m < 4; ++m) {
        int lrow0 = wr * 64 + m * 16 + g * 4;
#pragma unroll
        for (int r = 0; r < 4; ++r) {
          float v = acc[m][n][r] + bb;
          if (RELU) v = v > 0.0f ? v : 0.0f;
          smem[(lrow0 + r) * 128 + col] = f2b(v);
        }
      }
    }
    __syncthreads();
    // linear copy: 2048 chunks of 16B; wave-contiguous global stores
    ushort_t* Cb = C + (size_t)mgrp * 128 * DM + ntile * 128;
#pragma unroll
    for (int q = 0; q < 8; ++q) {
      int chunk = q * 256 + tid;        // 0..2047
      int row = chunk >> 4, co = (chunk & 15) * 8;
      bf16x8 v = *(const bf16x8*)&smem[row * 128 + co];
      *(bf16x8*)(Cb + (size_t)row * DM + co) = v;
    }
  }
}

// ---------------- combine accepted expert outputs per token ----------------
__global__ void combine_kernel(const ushort_t* __restrict__ Y, const int* __restrict__ slot,
                               float* __restrict__ out) {
  int t = blockIdx.x;
  int s0 = slot[2 * t], s1 = slot[2 * t + 1];
  int u = (s0 >= 0) + (s1 >= 0);
  if (u == 0) return;  // fallback GEMM scatter writes these rows
  int d = threadIdx.x * 4;
  float a0 = 0, a1 = 0, a2 = 0, a3 = 0;
  if (s0 >= 0) {
    ushort4 q = *(const ushort4*)(Y + (size_t)s0 * DM + d);
    a0 += b2f(q.x); a1 += b2f(q.y); a2 += b2f(q.z); a3 += b2f(q.w);
  }
  if (s1 >= 0) {
    ushort4 q = *(const ushort4*)(Y + (size_t)s1 * DM + d);
    a0 += b2f(q.x); a1 += b2f(q.y); a2 += b2f(q.z); a3 += b2f(q.w);
  }
  float inv = 1.0f / (float)u;
  float4 o = make_float4(a0 * inv, a1 * inv, a2 * inv, a3 * inv);
  *(float4*)(out + (size_t)t * DM + d) = o;
}

// ---------------- launch ----------------
extern "C" void kernel_launch(void* const* d_in, const int* in_sizes, int n_in,
                              void* d_out, int out_size, void* d_ws, size_t ws_size,
                              hipStream_t stream) {
  const float* x   = (const float*)d_in[0];
  const float* W1  = (const float*)d_in[1];
  const float* b1  = (const float*)d_in[2];
  const float* W2  = (const float*)d_in[3];
  const float* b2  = (const float*)d_in[4];
  const float* Wf1 = (const float*)d_in[5];
  const float* bf1 = (const float*)d_in[6];
  const float* Wf2 = (const float*)d_in[7];
  const float* bf2 = (const float*)d_in[8];
  const int* routes = (const int*)d_in[9];
  const int* capp   = (const int*)d_in[10];
  float* out = (float*)d_out;

  char* ws = (char*)d_ws;
  size_t off = 0;
  auto alloc = [&](size_t bytes) -> void* {
    void* p = ws + off; off += (bytes + 255) & ~255ull; return p;
  };
  ushort_t* W1b  = (ushort_t*)alloc((size_t)NEXP * DM * DM * 2);
  ushort_t* W2b  = (ushort_t*)alloc((size_t)NEXP * DM * DM * 2);
  ushort_t* Wf1b = (ushort_t*)alloc((size_t)DM * DM * 2);
  ushort_t* Wf2b = (ushort_t*)alloc((size_t)DM * DM * 2);
  ushort_t* xg   = (ushort_t*)alloc((size_t)MROWS * DM * 2);
  ushort_t* H    = (ushort_t*)alloc((size_t)MROWS * DM * 2);
  ushort_t* Y    = (ushort_t*)alloc((size_t)MROWS * DM * 2);
  ushort_t* xf   = (ushort_t*)alloc((size_t)BTOK * DM * 2);
  ushort_t* Hf   = (ushort_t*)alloc((size_t)BTOK * DM * 2);
  int* gidx   = (int*)alloc(MROWS * 4);
  int* slot   = (int*)alloc(NASSIGN * 4);
  int* counts = (int*)alloc(NEXP * 4);
  int* fbidx  = (int*)alloc(BTOK * 4);
  int* nfb    = (int*)alloc(4);

  route_kernel<<<NEXP, 1024, 0, stream>>>(routes, capp, gidx, slot, counts, nfb);
  fb_list_kernel<<<BTOK / 256, 256, 0, stream>>>(slot, fbidx, nfb);
  prep_kernel<<<36864, 256, 0, stream>>>(W1, W2, Wf1, Wf2, W1b, W2b, Wf1b, Wf2b,
                                         x, gidx, counts, xg, fbidx, nfb, xf);
  layer_kernel<1, 0><<<GRID_L, 256, 0, stream>>>(xg, W1b, b1, H, xf, Wf1b, bf1, Hf,
                                                 nullptr, nullptr, nfb);
  layer_kernel<0, 1><<<GRID_L, 256, 0, stream>>>(H, W2b, b2, Y, Hf, Wf2b, bf2, nullptr,
                                                 out, fbidx, nfb);
  combine_kernel<<<BTOK, 256, 0, stream>>>(Y, slot, out);
}

// Round 11
// 149.239 us; speedup vs baseline: 1.4383x; 1.0046x over previous
//
#include <hip/hip_runtime.h>

// ---------------- problem constants ----------------
#define DM    1024          // d_model
#define NEXP  8             // experts
#define BTOK  8192          // tokens
#define KTOP  2             // routes per token
#define NASSIGN (BTOK*KTOP) // 16384
#define CAPC  1280          // capacity (10 * 128 -> tile-aligned)
#define MROWS (NEXP*CAPC)   // 10240 expert rows

// GEMM geometry: 128x128 tile, BK=32, 4 waves (2x2), acc[4][4]
#define MTILES_E (MROWS/128)   // 80 (10 per expert)
#define MTILES_F (BTOK/128)    // 64
#define NTILES   (DM/128)      // 8
#define SLOTS_E  (10*NTILES)   // 80 expert-tile slots per XCD
#define SLOTS_F  (MTILES_F*NTILES/8)  // 64 fb slots per XCD
#define SLOTS    (SLOTS_E+SLOTS_F)    // 144
#define GRID_L   (8*SLOTS)            // 1152

typedef unsigned short ushort_t;
typedef __attribute__((ext_vector_type(8))) __bf16 bf16x8;
typedef __attribute__((ext_vector_type(4))) float  f32x4;

__device__ __forceinline__ ushort_t f2b(float f) {  // f32 -> bf16 RNE
  union { float f; unsigned u; } a; a.f = f;
  unsigned u = a.u;
  return (ushort_t)((u + 0x7FFFu + ((u >> 16) & 1u)) >> 16);
}
__device__ __forceinline__ float b2f(ushort_t h) {
  union { unsigned u; float f; } a; a.u = ((unsigned)h) << 16;
  return a.f;
}

#define GLOAD_LDS(g, l) __builtin_amdgcn_global_load_lds( \
    (const __attribute__((address_space(1))) void*)(g),   \
    (__attribute__((address_space(3))) void*)(l), 16, 0, 0)

// ---------------- merged: routing (blocks 0..7) + weight cvt (blocks 8..) ----
// Routing is 8 latency-bound blocks; cvt is HBM-bound with 4608 blocks.
// Merging lets routing's serial latency hide under the cvt stream.
// cvt blocks: 1024 thr x 1 float4.  W1: 2048 blks, W2: 2048, Wf1/Wf2: 256 ea.
__global__ void route_cvt_kernel(const int* __restrict__ routes, const int* __restrict__ capp,
                                 int* __restrict__ gidx, int* __restrict__ slot,
                                 int* __restrict__ counts, int* __restrict__ nfb,
                                 const float* __restrict__ W1, const float* __restrict__ W2,
                                 const float* __restrict__ Wf1, const float* __restrict__ Wf2,
                                 ushort_t* __restrict__ o1, ushort_t* __restrict__ o2,
                                 ushort_t* __restrict__ of1, ushort_t* __restrict__ of2) {
  const int b = blockIdx.x, t = threadIdx.x;
  if (b >= 8) {                          // weight f32 -> bf16
    const float* s; ushort_t* d; int idx;
    int c = b - 8;
    if (c < 2048)      { s = W1;  d = o1;  idx = c; }
    else if (c < 4096) { s = W2;  d = o2;  idx = c - 2048; }
    else if (c < 4352) { s = Wf1; d = of1; idx = c - 4096; }
    else               { s = Wf2; d = of2; idx = c - 4352; }
    int i = idx * 1024 + t;
    float4 v = ((const float4*)s)[i];
    ushort4 o; o.x = f2b(v.x); o.y = f2b(v.y); o.z = f2b(v.z); o.w = f2b(v.w);
    ((ushort4*)d)[i] = o;
    return;
  }
  // ---- routing: exact sequential capacity semantics (block e = expert) ----
  const int e = b;
  const int lane = t & 63, w = t >> 6;
  int cap = *capp; if (cap > CAPC) cap = CAPC;
  if (e == 0 && t == 0) *nfb = 0;
  __shared__ int wtot[16];
  int base = 0;
  for (int i0 = 0; i0 < NASSIGN; i0 += 1024) {
    int i = i0 + t;
    int r = routes[i];
    bool mine = (r == e);
    unsigned long long mask = __ballot(mine);
    int pre = __popcll(mask & ((1ull << lane) - 1ull));
    if (lane == 0) wtot[w] = __popcll(mask);
    __syncthreads();
    int tot = 0;
#pragma unroll
    for (int j = 0; j < 16; ++j) { int c = wtot[j]; if (j < w) pre += c; tot += c; }
    if (e == 0 && (unsigned)r >= NEXP) slot[i] = -1;  // defensive (never triggers)
    if (mine) {
      int pos = base + pre;
      if (pos < cap) { gidx[e * CAPC + pos] = i >> 1; slot[i] = e * CAPC + pos; }
      else slot[i] = -1;
    }
    base += tot;
    __syncthreads();
  }
  if (t == 0) counts[e] = base < cap ? base : cap;
}

// ---------------- merged: fb_list (blocks 0..31) + gather_xg (blocks 32..) ----
__global__ void fblist_gxg_kernel(const int* __restrict__ slot, int* __restrict__ fbidx,
                                  int* __restrict__ nfb,
                                  const float* __restrict__ x, const int* __restrict__ gidx,
                                  const int* __restrict__ counts, ushort_t* __restrict__ xg) {
  int b = blockIdx.x, t = threadIdx.x;
  if (b < 32) {                          // fallback token list (used==0)
    int tok = b * 256 + t;
    int u = (slot[2 * tok] >= 0) + (slot[2 * tok + 1] >= 0);
    if (u == 0) { int p = atomicAdd(nfb, 1); fbidx[p] = tok; }
    return;
  }
  int row = b - 32;                      // gather accepted rows -> xg
  int e = row / CAPC, p = row % CAPC;
  int d = t * 4;
  ushort4 o = {0, 0, 0, 0};
  if (p < counts[e]) {
    int tok = gidx[row];
    float4 v = *(const float4*)(x + (size_t)tok * DM + d);
    o.x = f2b(v.x); o.y = f2b(v.y); o.z = f2b(v.z); o.w = f2b(v.w);
  }
  *(ushort4*)(xg + (size_t)row * DM + d) = o;
}

// ---------------- gather fallback token rows -> xf (bf16), zero pad to 128 ----
__global__ void gather_xf_kernel(const float* __restrict__ x, const int* __restrict__ fbidx,
                                 const int* __restrict__ nfbp, ushort_t* __restrict__ xf) {
  int row = blockIdx.x;
  int n = *nfbp;
  int nr = (n + 127) & ~127;
  if (row >= nr) return;
  int d = threadIdx.x * 4;
  ushort4 o = {0, 0, 0, 0};
  if (row < n) {
    int tok = fbidx[row];
    float4 v = *(const float4*)(x + (size_t)tok * DM + d);
    o.x = f2b(v.x); o.y = f2b(v.y); o.z = f2b(v.z); o.w = f2b(v.w);
  }
  *(ushort4*)(xf + (size_t)row * DM + d) = o;
}

// ---------------- fused layer GEMM: expert part + fallback part ----------------
// C[m,n] = A[m,k]*W[n,k] + bias[n].  128x128 tile, BK=32, 4 waves (2x2).
// r11 = r9 structure (proven best: simple 2-phase dbuf, ONE __syncthreads per
// K-step whose vmcnt(0) drain is the tile-ready guarantee) with the occupancy
// cap lifted: __launch_bounds__(256,5).  32KB LDS -> 5 blocks/CU fit; grid
// 1152 <= 5*256=1280 resident slots -> SINGLE dispatch round (r9's (256,3)
// forced 1.5 rounds, measured occupancy 20% vs 37% structural).  18-20
// waves/CU of cross-block TLP is what hides the staging latency in this
// structure (counted-vmcnt grafts r2/r5/r10 all null/negative -- dropped).
// XCD expert affinity kept (FETCH 72->45MB).  LDS XOR swizzle kept
// (staging conflicts 0).  LDS-staged coalesced epilogue kept (WRITE 52->33MB).
template <int RELU, int FBSCAT>
__global__ __launch_bounds__(256, 5) void layer_kernel(
    const ushort_t* __restrict__ Ae, const ushort_t* __restrict__ We,
    const float* __restrict__ be, ushort_t* __restrict__ Ce,
    const ushort_t* __restrict__ Af, const ushort_t* __restrict__ Wf,
    const float* __restrict__ bfp, ushort_t* __restrict__ Cf,
    float* __restrict__ outF, const int* __restrict__ scat,
    const int* __restrict__ nfbp) {
  const int b = blockIdx.x;
  const int xcd = b & 7, s = b >> 3;
  const ushort_t* A; const ushort_t* W; const float* bias; ushort_t* C;
  int mgrp, ntile; bool isfb;
  if (s < SLOTS_E) {
    const int e = xcd;                       // expert = XCD (L2 affinity)
    mgrp = e * 10 + (s >> 3); ntile = s & 7; // N-fastest: W_e stays L2-hot
    A = Ae; W = We + (size_t)e * DM * DM; bias = be + e * DM; C = Ce; isfb = false;
  } else {
    int fl = (s - SLOTS_E) * 8 + xcd;        // 0..511 spread over XCDs
    mgrp = fl >> 3; ntile = fl & 7;
    if (mgrp * 128 >= *nfbp) return;
    A = Af; W = Wf; bias = bfp; C = Cf; isfb = true;
  }
  const int tid = threadIdx.x, lane = tid & 63, w = tid >> 6;
  const int wr = w >> 1, wc = w & 1;
  __shared__ ushort_t smem[16384];           // 32KB: dbuf A/B; reused for C
  const size_t Abase = (size_t)mgrp * 128 * DM;
  const size_t Wbase = (size_t)ntile * 128 * DM;
  f32x4 acc[4][4] = {};

  // staging: per operand 8 segs of 16 rows x 32k (1KB); wave w stages segs
  // {2w,2w+1} of A and of B -> 4 global_load_lds per wave per K-tile.
  const int sub  = lane >> 2;                     // row within 16-row seg
  const int slt  = lane & 3;                      // 16B k-slot
  const int gcol = (slt ^ ((sub >> 1) & 3)) * 8;  // inverse-swizzled source k-off
  const int r0 = (w * 2)     * 16 + sub;
  const int r1 = (w * 2 + 1) * 16 + sub;

  // LDS layout: buf0 A @0, buf1 A @4096, buf0 B @8192, buf1 B @12288 (elems)
#define STAGE(T, BUF) do { int kt_ = (T) * 32; int ao_ = (BUF) * 4096;          \
    GLOAD_LDS(A + Abase + (size_t)r0 * DM + kt_ + gcol, smem + ao_ + (w*2)  *512); \
    GLOAD_LDS(A + Abase + (size_t)r1 * DM + kt_ + gcol, smem + ao_ + (w*2+1)*512); \
    GLOAD_LDS(W + Wbase + (size_t)r0 * DM + kt_ + gcol, smem + 8192 + ao_ + (w*2)  *512); \
    GLOAD_LDS(W + Wbase + (size_t)r1 * DM + kt_ + gcol, smem + 8192 + ao_ + (w*2+1)*512); \
  } while (0)

  const int fr    = lane & 15, g = lane >> 4;
  const int rslot = (g ^ ((fr >> 1) & 3)) * 8;    // swizzled read k-off

  STAGE(0, 0);
  for (int t = 0; t < 32; ++t) {
    __syncthreads();                    // vmcnt(0) drain: tile t landed; and
                                        // buf[p^1]'s readers (iter t-1) passed
    if (t + 1 < 32) STAGE(t + 1, (t + 1) & 1);
    const ushort_t* bA = smem + (t & 1) * 4096;
    const ushort_t* bB = smem + 8192 + (t & 1) * 4096;
    bf16x8 av[4], bv[4];
#pragma unroll
    for (int m = 0; m < 4; ++m)
      av[m] = *(const bf16x8*)&bA[(wr * 64 + m * 16 + fr) * 32 + rslot];
#pragma unroll
    for (int n = 0; n < 4; ++n)
      bv[n] = *(const bf16x8*)&bB[(wc * 64 + n * 16 + fr) * 32 + rslot];
#pragma unroll
    for (int m = 0; m < 4; ++m)
#pragma unroll
      for (int n = 0; n < 4; ++n)
        acc[m][n] = __builtin_amdgcn_mfma_f32_16x16x32_bf16(av[m], bv[n], acc[m][n], 0, 0, 0);
  }
#undef STAGE

  // epilogue.  C/D layout col=lane&15, row=(lane>>4)*4+reg  [m89-verified]
  if (FBSCAT && isfb) {                 // fb layer-2: f32 scatter (small)
    int nfbv = *nfbp;
#pragma unroll
    for (int n = 0; n < 4; ++n) {
      int col = ntile * 128 + wc * 64 + n * 16 + fr;
      float bb = bias[col];
#pragma unroll
      for (int m = 0; m < 4; ++m) {
        int row0 = mgrp * 128 + wr * 64 + m * 16 + g * 4;
#pragma unroll
        for (int r = 0; r < 4; ++r) {
          int row = row0 + r;
          if (row < nfbv) outF[(size_t)scat[row] * DM + col] = acc[m][n][r] + bb;
        }
      }
    }
  } else {                              // bf16 C: LDS repack + coalesced store
    __syncthreads();                    // all staging reads done; reuse smem
#pragma unroll
    for (int n = 0; n < 4; ++n) {
      int col = wc * 64 + n * 16 + fr;
      float bb = bias[ntile * 128 + col];
#pragma unroll
      for (int m = 0; m < 4; ++m) {
        int lrow0 = wr * 64 + m * 16 + g * 4;
#pragma unroll
        for (int r = 0; r < 4; ++r) {
          float v = acc[m][n][r] + bb;
          if (RELU) v = v > 0.0f ? v : 0.0f;
          smem[(lrow0 + r) * 128 + col] = f2b(v);
        }
      }
    }
    __syncthreads();
    // linear copy: 2048 chunks of 16B; wave-contiguous global stores
    ushort_t* Cb = C + (size_t)mgrp * 128 * DM + ntile * 128;
#pragma unroll
    for (int q = 0; q < 8; ++q) {
      int chunk = q * 256 + tid;        // 0..2047
      int row = chunk >> 4, co = (chunk & 15) * 8;
      bf16x8 v = *(const bf16x8*)&smem[row * 128 + co];
      *(bf16x8*)(Cb + (size_t)row * DM + co) = v;
    }
  }
}

// ---------------- combine accepted expert outputs per token ----------------
__global__ void combine_kernel(const ushort_t* __restrict__ Y, const int* __restrict__ slot,
                               float* __restrict__ out) {
  int t = blockIdx.x;
  int s0 = slot[2 * t], s1 = slot[2 * t + 1];
  int u = (s0 >= 0) + (s1 >= 0);
  if (u == 0) return;  // fallback GEMM scatter writes these rows
  int d = threadIdx.x * 4;
  float a0 = 0, a1 = 0, a2 = 0, a3 = 0;
  if (s0 >= 0) {
    ushort4 q = *(const ushort4*)(Y + (size_t)s0 * DM + d);
    a0 += b2f(q.x); a1 += b2f(q.y); a2 += b2f(q.z); a3 += b2f(q.w);
  }
  if (s1 >= 0) {
    ushort4 q = *(const ushort4*)(Y + (size_t)s1 * DM + d);
    a0 += b2f(q.x); a1 += b2f(q.y); a2 += b2f(q.z); a3 += b2f(q.w);
  }
  float inv = 1.0f / (float)u;
  float4 o = make_float4(a0 * inv, a1 * inv, a2 * inv, a3 * inv);
  *(float4*)(out + (size_t)t * DM + d) = o;
}

// ---------------- launch ----------------
extern "C" void kernel_launch(void* const* d_in, const int* in_sizes, int n_in,
                              void* d_out, int out_size, void* d_ws, size_t ws_size,
                              hipStream_t stream) {
  const float* x   = (const float*)d_in[0];
  const float* W1  = (const float*)d_in[1];
  const float* b1  = (const float*)d_in[2];
  const float* W2  = (const float*)d_in[3];
  const float* b2  = (const float*)d_in[4];
  const float* Wf1 = (const float*)d_in[5];
  const float* bf1 = (const float*)d_in[6];
  const float* Wf2 = (const float*)d_in[7];
  const float* bf2 = (const float*)d_in[8];
  const int* routes = (const int*)d_in[9];
  const int* capp   = (const int*)d_in[10];
  float* out = (float*)d_out;

  char* ws = (char*)d_ws;
  size_t off = 0;
  auto alloc = [&](size_t bytes) -> void* {
    void* p = ws + off; off += (bytes + 255) & ~255ull; return p;
  };
  ushort_t* W1b  = (ushort_t*)alloc((size_t)NEXP * DM * DM * 2);
  ushort_t* W2b  = (ushort_t*)alloc((size_t)NEXP * DM * DM * 2);
  ushort_t* Wf1b = (ushort_t*)alloc((size_t)DM * DM * 2);
  ushort_t* Wf2b = (ushort_t*)alloc((size_t)DM * DM * 2);
  ushort_t* xg   = (ushort_t*)alloc((size_t)MROWS * DM * 2);
  ushort_t* H    = (ushort_t*)alloc((size_t)MROWS * DM * 2);
  ushort_t* Y    = (ushort_t*)alloc((size_t)MROWS * DM * 2);
  ushort_t* xf   = (ushort_t*)alloc((size_t)BTOK * DM * 2);
  ushort_t* Hf   = (ushort_t*)alloc((size_t)BTOK * DM * 2);
  int* gidx   = (int*)alloc(MROWS * 4);
  int* slot   = (int*)alloc(NASSIGN * 4);
  int* counts = (int*)alloc(NEXP * 4);
  int* fbidx  = (int*)alloc(BTOK * 4);
  int* nfb    = (int*)alloc(4);

  route_cvt_kernel<<<8 + 4608, 1024, 0, stream>>>(routes, capp, gidx, slot, counts, nfb,
                                                  W1, W2, Wf1, Wf2, W1b, W2b, Wf1b, Wf2b);
  fblist_gxg_kernel<<<32 + MROWS, 256, 0, stream>>>(slot, fbidx, nfb, x, gidx, counts, xg);
  gather_xf_kernel<<<BTOK, 256, 0, stream>>>(x, fbidx, nfb, xf);
  layer_kernel<1, 0><<<GRID_L, 256, 0, stream>>>(xg, W1b, b1, H, xf, Wf1b, bf1, Hf,
                                                 nullptr, nullptr, nfb);
  layer_kernel<0, 1><<<GRID_L, 256, 0, stream>>>(H, W2b, b2, Y, Hf, Wf2b, bf2, nullptr,
                                                 out, fbidx, nfb);
  combine_kernel<<<BTOK, 256, 0, stream>>>(Y, slot, out);
}

// Round 12
// 140.336 us; speedup vs baseline: 1.5296x; 1.0634x over previous
//
#include <hip/hip_runtime.h>

// ---------------- problem constants ----------------
#define DM    1024          // d_model
#define NEXP  8             // experts
#define BTOK  8192          // tokens
#define KTOP  2             // routes per token
#define NASSIGN (BTOK*KTOP) // 16384
#define CAPC  1280          // capacity (10 * 128 -> tile-aligned)
#define MROWS (NEXP*CAPC)   // 10240 expert rows

// GEMM geometry: 128x128 tile, BK=32, 4 waves (2x2), acc[4][4]
#define MTILES_E (MROWS/128)   // 80 (10 per expert)
#define MTILES_F (BTOK/128)    // 64
#define NTILES   (DM/128)      // 8
#define SLOTS_E  (10*NTILES)   // 80 expert-tile slots per XCD
#define SLOTS_F  (MTILES_F*NTILES/8)  // 64 fb slots per XCD
#define SLOTS    (SLOTS_E+SLOTS_F)    // 144
#define GRID_L   (8*SLOTS)            // 1152

typedef unsigned short ushort_t;
typedef __attribute__((ext_vector_type(8))) __bf16 bf16x8;
typedef __attribute__((ext_vector_type(4))) float  f32x4;

__device__ __forceinline__ ushort_t f2b(float f) {  // f32 -> bf16 RNE
  union { float f; unsigned u; } a; a.f = f;
  unsigned u = a.u;
  return (ushort_t)((u + 0x7FFFu + ((u >> 16) & 1u)) >> 16);
}
__device__ __forceinline__ float b2f(ushort_t h) {
  union { unsigned u; float f; } a; a.u = ((unsigned)h) << 16;
  return a.f;
}

#define GLOAD_LDS(g, l) __builtin_amdgcn_global_load_lds( \
    (const __attribute__((address_space(1))) void*)(g),   \
    (__attribute__((address_space(3))) void*)(l), 16, 0, 0)

// ---------------- merged: routing (blocks 0..7) + weight cvt (blocks 8..) ----
__global__ void route_cvt_kernel(const int* __restrict__ routes, const int* __restrict__ capp,
                                 int* __restrict__ gidx, int* __restrict__ slot,
                                 int* __restrict__ counts, int* __restrict__ nfb,
                                 const float* __restrict__ W1, const float* __restrict__ W2,
                                 const float* __restrict__ Wf1, const float* __restrict__ Wf2,
                                 ushort_t* __restrict__ o1, ushort_t* __restrict__ o2,
                                 ushort_t* __restrict__ of1, ushort_t* __restrict__ of2) {
  const int b = blockIdx.x, t = threadIdx.x;
  if (b >= 8) {                          // weight f32 -> bf16
    const float* s; ushort_t* d; int idx;
    int c = b - 8;
    if (c < 2048)      { s = W1;  d = o1;  idx = c; }
    else if (c < 4096) { s = W2;  d = o2;  idx = c - 2048; }
    else if (c < 4352) { s = Wf1; d = of1; idx = c - 4096; }
    else               { s = Wf2; d = of2; idx = c - 4352; }
    int i = idx * 1024 + t;
    float4 v = ((const float4*)s)[i];
    ushort4 o; o.x = f2b(v.x); o.y = f2b(v.y); o.z = f2b(v.z); o.w = f2b(v.w);
    ((ushort4*)d)[i] = o;
    return;
  }
  // ---- routing: exact sequential capacity semantics (block e = expert) ----
  const int e = b;
  const int lane = t & 63, w = t >> 6;
  int cap = *capp; if (cap > CAPC) cap = CAPC;
  if (e == 0 && t == 0) *nfb = 0;
  __shared__ int wtot[16];
  int base = 0;
  for (int i0 = 0; i0 < NASSIGN; i0 += 1024) {
    int i = i0 + t;
    int r = routes[i];
    bool mine = (r == e);
    unsigned long long mask = __ballot(mine);
    int pre = __popcll(mask & ((1ull << lane) - 1ull));
    if (lane == 0) wtot[w] = __popcll(mask);
    __syncthreads();
    int tot = 0;
#pragma unroll
    for (int j = 0; j < 16; ++j) { int c = wtot[j]; if (j < w) pre += c; tot += c; }
    if (e == 0 && (unsigned)r >= NEXP) slot[i] = -1;  // defensive (never triggers)
    if (mine) {
      int pos = base + pre;
      if (pos < cap) { gidx[e * CAPC + pos] = i >> 1; slot[i] = e * CAPC + pos; }
      else slot[i] = -1;
    }
    base += tot;
    __syncthreads();
  }
  if (t == 0) counts[e] = base < cap ? base : cap;
}

// ---------------- merged: fb_list (blocks 0..31) + gather_xg (blocks 32..) ----
__global__ void fblist_gxg_kernel(const int* __restrict__ slot, int* __restrict__ fbidx,
                                  int* __restrict__ nfb,
                                  const float* __restrict__ x, const int* __restrict__ gidx,
                                  const int* __restrict__ counts, ushort_t* __restrict__ xg) {
  int b = blockIdx.x, t = threadIdx.x;
  if (b < 32) {                          // fallback token list (used==0)
    int tok = b * 256 + t;
    int u = (slot[2 * tok] >= 0) + (slot[2 * tok + 1] >= 0);
    if (u == 0) { int p = atomicAdd(nfb, 1); fbidx[p] = tok; }
    return;
  }
  int row = b - 32;                      // gather accepted rows -> xg
  int e = row / CAPC, p = row % CAPC;
  int d = t * 4;
  ushort4 o = {0, 0, 0, 0};
  if (p < counts[e]) {
    int tok = gidx[row];
    float4 v = *(const float4*)(x + (size_t)tok * DM + d);
    o.x = f2b(v.x); o.y = f2b(v.y); o.z = f2b(v.z); o.w = f2b(v.w);
  }
  *(ushort4*)(xg + (size_t)row * DM + d) = o;
}

// ---------------- gather fallback token rows -> xf (bf16), zero pad to 128 ----
__global__ void gather_xf_kernel(const float* __restrict__ x, const int* __restrict__ fbidx,
                                 const int* __restrict__ nfbp, ushort_t* __restrict__ xf) {
  int row = blockIdx.x;
  int n = *nfbp;
  int nr = (n + 127) & ~127;
  if (row >= nr) return;
  int d = threadIdx.x * 4;
  ushort4 o = {0, 0, 0, 0};
  if (row < n) {
    int tok = fbidx[row];
    float4 v = *(const float4*)(x + (size_t)tok * DM + d);
    o.x = f2b(v.x); o.y = f2b(v.y); o.z = f2b(v.z); o.w = f2b(v.w);
  }
  *(ushort4*)(xf + (size_t)row * DM + d) = o;
}

// ---------------- fused layer GEMM: expert part + fallback part ----------------
// C[m,n] = A[m,k]*W[n,k] + bias[n].  128x128 tile, BK=32, 4 waves (2x2).
// r12 = r9's proven loop (simple 2-phase dbuf, ONE __syncthreads per K-step)
// at __launch_bounds__(256,4): VGPR cap 128/wave -> compiler keeps the r9
// schedule (~56 VGPR), LDS admits 4 blocks/CU (128KB).  r11's (256,5) squeezed
// VGPR to 48 and cost 15% -- reverted.  Counted-vmcnt grafts (r2/r5/r10) all
// null/negative -- permanently dropped.  XCD expert affinity kept (FETCH
// 72->45MB).  LDS XOR swizzle kept (staging conflicts 0).  LDS-staged
// coalesced epilogue kept (WRITE 52->33MB).
template <int RELU, int FBSCAT>
__global__ __launch_bounds__(256, 4) void layer_kernel(
    const ushort_t* __restrict__ Ae, const ushort_t* __restrict__ We,
    const float* __restrict__ be, ushort_t* __restrict__ Ce,
    const ushort_t* __restrict__ Af, const ushort_t* __restrict__ Wf,
    const float* __restrict__ bfp, ushort_t* __restrict__ Cf,
    float* __restrict__ outF, const int* __restrict__ scat,
    const int* __restrict__ nfbp) {
  const int b = blockIdx.x;
  const int xcd = b & 7, s = b >> 3;
  const ushort_t* A; const ushort_t* W; const float* bias; ushort_t* C;
  int mgrp, ntile; bool isfb;
  if (s < SLOTS_E) {
    const int e = xcd;                       // expert = XCD (L2 affinity)
    mgrp = e * 10 + (s >> 3); ntile = s & 7; // N-fastest: W_e stays L2-hot
    A = Ae; W = We + (size_t)e * DM * DM; bias = be + e * DM; C = Ce; isfb = false;
  } else {
    int fl = (s - SLOTS_E) * 8 + xcd;        // 0..511 spread over XCDs
    mgrp = fl >> 3; ntile = fl & 7;
    if (mgrp * 128 >= *nfbp) return;
    A = Af; W = Wf; bias = bfp; C = Cf; isfb = true;
  }
  const int tid = threadIdx.x, lane = tid & 63, w = tid >> 6;
  const int wr = w >> 1, wc = w & 1;
  __shared__ ushort_t smem[16384];           // 32KB: dbuf A/B; reused for C
  const size_t Abase = (size_t)mgrp * 128 * DM;
  const size_t Wbase = (size_t)ntile * 128 * DM;
  f32x4 acc[4][4] = {};

  // staging: per operand 8 segs of 16 rows x 32k (1KB); wave w stages segs
  // {2w,2w+1} of A and of B -> 4 global_load_lds per wave per K-tile.
  const int sub  = lane >> 2;                     // row within 16-row seg
  const int slt  = lane & 3;                      // 16B k-slot
  const int gcol = (slt ^ ((sub >> 1) & 3)) * 8;  // inverse-swizzled source k-off
  const int r0 = (w * 2)     * 16 + sub;
  const int r1 = (w * 2 + 1) * 16 + sub;

  // LDS layout: buf0 A @0, buf1 A @4096, buf0 B @8192, buf1 B @12288 (elems)
#define STAGE(T, BUF) do { int kt_ = (T) * 32; int ao_ = (BUF) * 4096;          \
    GLOAD_LDS(A + Abase + (size_t)r0 * DM + kt_ + gcol, smem + ao_ + (w*2)  *512); \
    GLOAD_LDS(A + Abase + (size_t)r1 * DM + kt_ + gcol, smem + ao_ + (w*2+1)*512); \
    GLOAD_LDS(W + Wbase + (size_t)r0 * DM + kt_ + gcol, smem + 8192 + ao_ + (w*2)  *512); \
    GLOAD_LDS(W + Wbase + (size_t)r1 * DM + kt_ + gcol, smem + 8192 + ao_ + (w*2+1)*512); \
  } while (0)

  const int fr    = lane & 15, g = lane >> 4;
  const int rslot = (g ^ ((fr >> 1) & 3)) * 8;    // swizzled read k-off

  STAGE(0, 0);
  for (int t = 0; t < 32; ++t) {
    __syncthreads();                    // vmcnt(0) drain: tile t landed; and
                                        // buf[p^1]'s readers (iter t-1) passed
    if (t + 1 < 32) STAGE(t + 1, (t + 1) & 1);
    const ushort_t* bA = smem + (t & 1) * 4096;
    const ushort_t* bB = smem + 8192 + (t & 1) * 4096;
    bf16x8 av[4], bv[4];
#pragma unroll
    for (int m = 0; m < 4; ++m)
      av[m] = *(const bf16x8*)&bA[(wr * 64 + m * 16 + fr) * 32 + rslot];
#pragma unroll
    for (int n = 0; n < 4; ++n)
      bv[n] = *(const bf16x8*)&bB[(wc * 64 + n * 16 + fr) * 32 + rslot];
#pragma unroll
    for (int m = 0; m < 4; ++m)
#pragma unroll
      for (int n = 0; n < 4; ++n)
        acc[m][n] = __builtin_amdgcn_mfma_f32_16x16x32_bf16(av[m], bv[n], acc[m][n], 0, 0, 0);
  }
#undef STAGE

  // epilogue.  C/D layout col=lane&15, row=(lane>>4)*4+reg  [m89-verified]
  if (FBSCAT && isfb) {                 // fb layer-2: f32 scatter (small)
    int nfbv = *nfbp;
#pragma unroll
    for (int n = 0; n < 4; ++n) {
      int col = ntile * 128 + wc * 64 + n * 16 + fr;
      float bb = bias[col];
#pragma unroll
      for (int m = 0; m < 4; ++m) {
        int row0 = mgrp * 128 + wr * 64 + m * 16 + g * 4;
#pragma unroll
        for (int r = 0; r < 4; ++r) {
          int row = row0 + r;
          if (row < nfbv) outF[(size_t)scat[row] * DM + col] = acc[m][n][r] + bb;
        }
      }
    }
  } else {                              // bf16 C: LDS repack + coalesced store
    __syncthreads();                    // all staging reads done; reuse smem
#pragma unroll
    for (int n = 0; n < 4; ++n) {
      int col = wc * 64 + n * 16 + fr;
      float bb = bias[ntile * 128 + col];
#pragma unroll
      for (int m = 0; m < 4; ++m) {
        int lrow0 = wr * 64 + m * 16 + g * 4;
#pragma unroll
        for (int r = 0; r < 4; ++r) {
          float v = acc[m][n][r] + bb;
          if (RELU) v = v > 0.0f ? v : 0.0f;
          smem[(lrow0 + r) * 128 + col] = f2b(v);
        }
      }
    }
    __syncthreads();
    // linear copy: 2048 chunks of 16B; wave-contiguous global stores
    ushort_t* Cb = C + (size_t)mgrp * 128 * DM + ntile * 128;
#pragma unroll
    for (int q = 0; q < 8; ++q) {
      int chunk = q * 256 + tid;        // 0..2047
      int row = chunk >> 4, co = (chunk & 15) * 8;
      bf16x8 v = *(const bf16x8*)&smem[row * 128 + co];
      *(bf16x8*)(Cb + (size_t)row * DM + co) = v;
    }
  }
}

// ---------------- combine accepted expert outputs per token ----------------
__global__ void combine_kernel(const ushort_t* __restrict__ Y, const int* __restrict__ slot,
                               float* __restrict__ out) {
  int t = blockIdx.x;
  int s0 = slot[2 * t], s1 = slot[2 * t + 1];
  int u = (s0 >= 0) + (s1 >= 0);
  if (u == 0) return;  // fallback GEMM scatter writes these rows
  int d = threadIdx.x * 4;
  float a0 = 0, a1 = 0, a2 = 0, a3 = 0;
  if (s0 >= 0) {
    ushort4 q = *(const ushort4*)(Y + (size_t)s0 * DM + d);
    a0 += b2f(q.x); a1 += b2f(q.y); a2 += b2f(q.z); a3 += b2f(q.w);
  }
  if (s1 >= 0) {
    ushort4 q = *(const ushort4*)(Y + (size_t)s1 * DM + d);
    a0 += b2f(q.x); a1 += b2f(q.y); a2 += b2f(q.z); a3 += b2f(q.w);
  }
  float inv = 1.0f / (float)u;
  float4 o = make_float4(a0 * inv, a1 * inv, a2 * inv, a3 * inv);
  *(float4*)(out + (size_t)t * DM + d) = o;
}

// ---------------- launch ----------------
extern "C" void kernel_launch(void* const* d_in, const int* in_sizes, int n_in,
                              void* d_out, int out_size, void* d_ws, size_t ws_size,
                              hipStream_t stream) {
  const float* x   = (const float*)d_in[0];
  const float* W1  = (const float*)d_in[1];
  const float* b1  = (const float*)d_in[2];
  const float* W2  = (const float*)d_in[3];
  const float* b2  = (const float*)d_in[4];
  const float* Wf1 = (const float*)d_in[5];
  const float* bf1 = (const float*)d_in[6];
  const float* Wf2 = (const float*)d_in[7];
  const float* bf2 = (const float*)d_in[8];
  const int* routes = (const int*)d_in[9];
  const int* capp   = (const int*)d_in[10];
  float* out = (float*)d_out;

  char* ws = (char*)d_ws;
  size_t off = 0;
  auto alloc = [&](size_t bytes) -> void* {
    void* p = ws + off; off += (bytes + 255) & ~255ull; return p;
  };
  ushort_t* W1b  = (ushort_t*)alloc((size_t)NEXP * DM * DM * 2);
  ushort_t* W2b  = (ushort_t*)alloc((size_t)NEXP * DM * DM * 2);
  ushort_t* Wf1b = (ushort_t*)alloc((size_t)DM * DM * 2);
  ushort_t* Wf2b = (ushort_t*)alloc((size_t)DM * DM * 2);
  ushort_t* xg   = (ushort_t*)alloc((size_t)MROWS * DM * 2);
  ushort_t* H    = (ushort_t*)alloc((size_t)MROWS * DM * 2);
  ushort_t* Y    = (ushort_t*)alloc((size_t)MROWS * DM * 2);
  ushort_t* xf   = (ushort_t*)alloc((size_t)BTOK * DM * 2);
  ushort_t* Hf   = (ushort_t*)alloc((size_t)BTOK * DM * 2);
  int* gidx   = (int*)alloc(MROWS * 4);
  int* slot   = (int*)alloc(NASSIGN * 4);
  int* counts = (int*)alloc(NEXP * 4);
  int* fbidx  = (int*)alloc(BTOK * 4);
  int* nfb    = (int*)alloc(4);

  route_cvt_kernel<<<8 + 4608, 1024, 0, stream>>>(routes, capp, gidx, slot, counts, nfb,
                                                  W1, W2, Wf1, Wf2, W1b, W2b, Wf1b, Wf2b);
  fblist_gxg_kernel<<<32 + MROWS, 256, 0, stream>>>(slot, fbidx, nfb, x, gidx, counts, xg);
  gather_xf_kernel<<<BTOK, 256, 0, stream>>>(x, fbidx, nfb, xf);
  layer_kernel<1, 0><<<GRID_L, 256, 0, stream>>>(xg, W1b, b1, H, xf, Wf1b, bf1, Hf,
                                                 nullptr, nullptr, nfb);
  layer_kernel<0, 1><<<GRID_L, 256, 0, stream>>>(H, W2b, b2, Y, Hf, Wf2b, bf2, nullptr,
                                                 out, fbidx, nfb);
  combine_kernel<<<BTOK, 256, 0, stream>>>(Y, slot, out);
}

// Round 13
// 135.510 us; speedup vs baseline: 1.5840x; 1.0356x over previous
//
#include <hip/hip_runtime.h>

// ---------------- problem constants ----------------
#define DM    1024          // d_model
#define NEXP  8             // experts
#define BTOK  8192          // tokens
#define KTOP  2             // routes per token
#define NASSIGN (BTOK*KTOP) // 16384
#define CAPC  1280          // capacity (5 * 256 -> tile-aligned)
#define MROWS (NEXP*CAPC)   // 10240 expert rows

// GEMM geometry: 256x256 tile, BK=64 (2 k-halves of 32), 8 waves (2Mx4N)
#define SLOTS_E  20                   // 5 M x 4 N expert tiles per XCD
#define SLOTS_F  16                   // fb slots per XCD (32 Mtiles x 4 N / 8)
#define SLOTS    (SLOTS_E+SLOTS_F)    // 36
#define GRID_L   (8*SLOTS)            // 288 (blocks 256+ all early-exit)

typedef unsigned short ushort_t;
typedef __attribute__((ext_vector_type(8))) __bf16 bf16x8;
typedef __attribute__((ext_vector_type(4))) float  f32x4;

__device__ __forceinline__ ushort_t f2b(float f) {  // f32 -> bf16 RNE
  union { float f; unsigned u; } a; a.f = f;
  unsigned u = a.u;
  return (ushort_t)((u + 0x7FFFu + ((u >> 16) & 1u)) >> 16);
}
__device__ __forceinline__ float b2f(ushort_t h) {
  union { unsigned u; float f; } a; a.u = ((unsigned)h) << 16;
  return a.f;
}

#define GLOAD_LDS(g, l) __builtin_amdgcn_global_load_lds( \
    (const __attribute__((address_space(1))) void*)(g),   \
    (__attribute__((address_space(3))) void*)(l), 16, 0, 0)

// ---------------- merged: routing (blocks 0..7) + weight cvt (blocks 8..) ----
__global__ void route_cvt_kernel(const int* __restrict__ routes, const int* __restrict__ capp,
                                 int* __restrict__ gidx, int* __restrict__ slot,
                                 int* __restrict__ counts, int* __restrict__ nfb,
                                 const float* __restrict__ W1, const float* __restrict__ W2,
                                 const float* __restrict__ Wf1, const float* __restrict__ Wf2,
                                 ushort_t* __restrict__ o1, ushort_t* __restrict__ o2,
                                 ushort_t* __restrict__ of1, ushort_t* __restrict__ of2) {
  const int b = blockIdx.x, t = threadIdx.x;
  if (b >= 8) {                          // weight f32 -> bf16
    const float* s; ushort_t* d; int idx;
    int c = b - 8;
    if (c < 2048)      { s = W1;  d = o1;  idx = c; }
    else if (c < 4096) { s = W2;  d = o2;  idx = c - 2048; }
    else if (c < 4352) { s = Wf1; d = of1; idx = c - 4096; }
    else               { s = Wf2; d = of2; idx = c - 4352; }
    int i = idx * 1024 + t;
    float4 v = ((const float4*)s)[i];
    ushort4 o; o.x = f2b(v.x); o.y = f2b(v.y); o.z = f2b(v.z); o.w = f2b(v.w);
    ((ushort4*)d)[i] = o;
    return;
  }
  // ---- routing: exact sequential capacity semantics (block e = expert) ----
  const int e = b;
  const int lane = t & 63, w = t >> 6;
  int cap = *capp; if (cap > CAPC) cap = CAPC;
  if (e == 0 && t == 0) *nfb = 0;
  __shared__ int wtot[16];
  int base = 0;
  for (int i0 = 0; i0 < NASSIGN; i0 += 1024) {
    int i = i0 + t;
    int r = routes[i];
    bool mine = (r == e);
    unsigned long long mask = __ballot(mine);
    int pre = __popcll(mask & ((1ull << lane) - 1ull));
    if (lane == 0) wtot[w] = __popcll(mask);
    __syncthreads();
    int tot = 0;
#pragma unroll
    for (int j = 0; j < 16; ++j) { int c = wtot[j]; if (j < w) pre += c; tot += c; }
    if (e == 0 && (unsigned)r >= NEXP) slot[i] = -1;  // defensive (never triggers)
    if (mine) {
      int pos = base + pre;
      if (pos < cap) { gidx[e * CAPC + pos] = i >> 1; slot[i] = e * CAPC + pos; }
      else slot[i] = -1;
    }
    base += tot;
    __syncthreads();
  }
  if (t == 0) counts[e] = base < cap ? base : cap;
}

// ---------------- merged: fb_list (blocks 0..31) + gather_xg (blocks 32..) ----
__global__ void fblist_gxg_kernel(const int* __restrict__ slot, int* __restrict__ fbidx,
                                  int* __restrict__ nfb,
                                  const float* __restrict__ x, const int* __restrict__ gidx,
                                  const int* __restrict__ counts, ushort_t* __restrict__ xg) {
  int b = blockIdx.x, t = threadIdx.x;
  if (b < 32) {                          // fallback token list (used==0)
    int tok = b * 256 + t;
    int u = (slot[2 * tok] >= 0) + (slot[2 * tok + 1] >= 0);
    if (u == 0) { int p = atomicAdd(nfb, 1); fbidx[p] = tok; }
    return;
  }
  int row = b - 32;                      // gather accepted rows -> xg
  int e = row / CAPC, p = row % CAPC;
  int d = t * 4;
  ushort4 o = {0, 0, 0, 0};
  if (p < counts[e]) {
    int tok = gidx[row];
    float4 v = *(const float4*)(x + (size_t)tok * DM + d);
    o.x = f2b(v.x); o.y = f2b(v.y); o.z = f2b(v.z); o.w = f2b(v.w);
  }
  *(ushort4*)(xg + (size_t)row * DM + d) = o;
}

// ---------------- gather fallback token rows -> xf (bf16), zero pad to 128 ----
__global__ void gather_xf_kernel(const float* __restrict__ x, const int* __restrict__ fbidx,
                                 const int* __restrict__ nfbp, ushort_t* __restrict__ xf) {
  int row = blockIdx.x;
  int n = *nfbp;
  int nr = (n + 127) & ~127;
  if (row >= nr) return;
  int d = threadIdx.x * 4;
  ushort4 o = {0, 0, 0, 0};
  if (row < n) {
    int tok = fbidx[row];
    float4 v = *(const float4*)(x + (size_t)tok * DM + d);
    o.x = f2b(v.x); o.y = f2b(v.y); o.z = f2b(v.z); o.w = f2b(v.w);
  }
  *(ushort4*)(xf + (size_t)row * DM + d) = o;
}

// ---------------- 256^2 8-phase layer GEMM (expert + fallback fused) ----------
// C[m,n] = A[m,k]*W[n,k] + bias[n].  BM=BN=256, BK=64 (2 k-halves), 8 waves
// (2Mx4N), per-wave 128x64 C.  LDS 128KB: per operand 2 bufs x [2 kh][256][32]
// (even K-tiles -> buf0, odd -> buf1).  8 phases per iter (2 K-tiles), phase =
// (m-half, k-half): 8 ds_read_b128 + stage + barrier + 16 MFMA + barrier.
// Counted vmcnt(2)+barrier at q3/q7 tops only (never drains in main loop).
// Stage slots (derived, race-free: each target's readers passed a barrier
// >=1 phase before issue; each half vmcnt-confirmed >=1 phase before first
// read; windows 5-6 phases):
//   q0: B-kh1(2j+1)  q1: A-kh1(2j+1)  q2: A-kh0(2j+2)  q3: B-kh0(2j+2)
//   q4: A-kh1(2j+2)+B-kh1(2j+2)       q6: A-kh0(2j+3)  q7: B-kh0(2j+3)
// Tail stages wrap (&15) as dummies for uniform vmcnt counts.
// XCD expert affinity kept; r12 LDS XOR swizzle kept; LDS-repack epilogue.
#define BAR() do { asm volatile("s_barrier" ::: "memory"); \
                   __builtin_amdgcn_sched_barrier(0); } while (0)

template <int RELU, int FBSCAT>
__global__ __launch_bounds__(512, 2) void layer_kernel(
    const ushort_t* __restrict__ Ae, const ushort_t* __restrict__ We,
    const float* __restrict__ be, ushort_t* __restrict__ Ce,
    const ushort_t* __restrict__ Af, const ushort_t* __restrict__ Wf,
    const float* __restrict__ bfp, ushort_t* __restrict__ Cf,
    float* __restrict__ outF, const int* __restrict__ scat,
    const int* __restrict__ nfbp) {
  const int b = blockIdx.x;
  const int xcd = b & 7, s = b >> 3;
  const ushort_t* A; const ushort_t* W; const float* bias; ushort_t* C;
  int mgrp, ntile; bool isfb;
  if (s < SLOTS_E) {
    const int e = xcd;                      // expert = XCD (L2 affinity)
    mgrp = e * 5 + (s >> 2); ntile = s & 3;
    A = Ae; W = We + (size_t)e * DM * DM; bias = be + e * DM; C = Ce; isfb = false;
  } else {
    int fl = (s - SLOTS_E) * 8 + xcd;       // 0..127
    mgrp = fl >> 2; ntile = fl & 3;
    if (mgrp * 256 >= *nfbp) return;        // uniform early-exit (no barriers yet)
    A = Af; W = Wf; bias = bfp; C = Cf; isfb = true;
  }
  const int tid = threadIdx.x, lane = tid & 63, w = tid >> 6;  // w 0..7
  const int wr = w >> 2, wc = w & 3;
  __shared__ ushort_t smem[65536];          // 128KB; reused for C repack
  const size_t Abase = (size_t)mgrp * 256 * DM;
  const size_t Wbase = (size_t)ntile * 256 * DM;
  f32x4 acc[8][4] = {};

  // staging lanes (r12-proven swizzle pair): seg = 16 rows x 32k (1KB)
  const int sub  = lane >> 2;                     // row within seg
  const int slt  = lane & 3;                      // 16B k-slot
  const int gcol = (slt ^ ((sub >> 1) & 3)) * 8;  // inverse-swizzled source k-off
  // LDS elem offsets: A[buf][kh] = buf*16384 + kh*8192 ; B = 32768 + same
#define ALB(BUF, KH) ((BUF)*16384 + (KH)*8192)
#define BLB(BUF, KH) (32768 + (BUF)*16384 + (KH)*8192)
  // stage one half (16KB): wave w stages segs 2w, 2w+1 (2 loads/thread)
#define STAGEH(P, GB, T, KH, LB) do { int kt_ = (T)*64 + (KH)*32;                    \
    GLOAD_LDS(P + GB + (size_t)((w*2  )*16 + sub)*DM + kt_ + gcol, smem + (LB) + (w*2  )*512); \
    GLOAD_LDS(P + GB + (size_t)((w*2+1)*16 + sub)*DM + kt_ + gcol, smem + (LB) + (w*2+1)*512); \
  } while (0)

  const int fr = lane & 15, g = lane >> 4;
  const int rslot = (g ^ ((fr >> 1) & 3)) * 8;    // swizzled read k-off
  bf16x8 av[4], bv[4];
#define LOADFRAGS(BUF, MH, KH) do {                                                  \
    const ushort_t* pa_ = smem + ALB(BUF, KH);                                       \
    const ushort_t* pb_ = smem + BLB(BUF, KH);                                       \
    _Pragma("unroll")                                                                \
    for (int i_ = 0; i_ < 4; ++i_)                                                   \
      av[i_] = *(const bf16x8*)&pa_[(wr*128 + ((MH)*4 + i_)*16 + fr)*32 + rslot];    \
    _Pragma("unroll")                                                                \
    for (int n_ = 0; n_ < 4; ++n_)                                                   \
      bv[n_] = *(const bf16x8*)&pb_[(wc*64 + n_*16 + fr)*32 + rslot];                \
  } while (0)
#define DOMFMA(MH) do { __builtin_amdgcn_s_setprio(1);                               \
    _Pragma("unroll")                                                                \
    for (int i_ = 0; i_ < 4; ++i_)                                                   \
      _Pragma("unroll")                                                              \
      for (int n_ = 0; n_ < 4; ++n_)                                                 \
        acc[(MH)*4 + i_][n_] = __builtin_amdgcn_mfma_f32_16x16x32_bf16(              \
            av[i_], bv[n_], acc[(MH)*4 + i_][n_], 0, 0, 0);                          \
    __builtin_amdgcn_s_setprio(0); } while (0)
#define VM2() do { asm volatile("s_waitcnt vmcnt(2)" ::: "memory");                  \
                   __builtin_amdgcn_sched_barrier(0); } while (0)

  // prologue: tile0 all halves + tile1 kh0 (steady-state tail of iter -1)
  STAGEH(A, Abase, 0, 0, ALB(0,0));  STAGEH(W, Wbase, 0, 0, BLB(0,0));
  STAGEH(A, Abase, 0, 1, ALB(0,1));  STAGEH(W, Wbase, 0, 1, BLB(0,1));
  STAGEH(A, Abase, 1, 0, ALB(1,0));  STAGEH(W, Wbase, 1, 0, BLB(1,0));
  asm volatile("s_waitcnt vmcnt(4)" ::: "memory");  // tile0 fully landed
  BAR();

  for (int j = 0; j < 8; ++j) {
    const int bT = 2*j + 1, cT = (2*j + 2) & 15, dT = (2*j + 3) & 15;
    // q0: (buf0, mh0, kh0)
    LOADFRAGS(0, 0, 0);
    STAGEH(W, Wbase, bT, 1, BLB(1,1));
    BAR(); DOMFMA(0); BAR();
    // q1: (buf0, mh1, kh0)
    LOADFRAGS(0, 1, 0);
    STAGEH(A, Abase, bT, 1, ALB(1,1));
    BAR(); DOMFMA(1); BAR();
    // q2: (buf0, mh0, kh1)
    LOADFRAGS(0, 0, 1);
    STAGEH(A, Abase, cT, 0, ALB(0,0));
    BAR(); DOMFMA(0); BAR();
    // q3: (buf0, mh1, kh1)  [counted vmcnt]
    VM2();
    LOADFRAGS(0, 1, 1);
    STAGEH(W, Wbase, cT, 0, BLB(0,0));
    BAR(); DOMFMA(1); BAR();
    // q4: (buf1, mh0, kh0)
    LOADFRAGS(1, 0, 0);
    STAGEH(A, Abase, cT, 1, ALB(0,1));
    STAGEH(W, Wbase, cT, 1, BLB(0,1));
    BAR(); DOMFMA(0); BAR();
    // q5: (buf1, mh1, kh0)
    LOADFRAGS(1, 1, 0);
    BAR(); DOMFMA(1); BAR();
    // q6: (buf1, mh0, kh1)
    LOADFRAGS(1, 0, 1);
    STAGEH(A, Abase, dT, 0, ALB(1,0));
    BAR(); DOMFMA(0); BAR();
    // q7: (buf1, mh1, kh1)  [counted vmcnt]
    VM2();
    LOADFRAGS(1, 1, 1);
    STAGEH(W, Wbase, dT, 0, BLB(1,0));
    BAR(); DOMFMA(1); BAR();
  }
  asm volatile("s_waitcnt vmcnt(0)" ::: "memory");  // drain dummy stages
  BAR();

  // epilogue.  C/D layout col=lane&15, row=(lane>>4)*4+reg  [m89-verified]
  if (FBSCAT && isfb) {                 // fb layer-2: f32 scatter (small)
    int nfbv = *nfbp;
#pragma unroll
    for (int n = 0; n < 4; ++n) {
      int col = ntile * 256 + wc * 64 + n * 16 + fr;
      float bb = bias[col];
#pragma unroll
      for (int m = 0; m < 8; ++m) {
        int row0 = mgrp * 256 + wr * 128 + m * 16 + g * 4;
#pragma unroll
        for (int r = 0; r < 4; ++r) {
          int row = row0 + r;
          if (row < nfbv) outF[(size_t)scat[row] * DM + col] = acc[m][n][r] + bb;
        }
      }
    }
  } else {                              // bf16 C: LDS repack + coalesced store
#pragma unroll
    for (int n = 0; n < 4; ++n) {
      int col = wc * 64 + n * 16 + fr;
      float bb = bias[ntile * 256 + col];
#pragma unroll
      for (int m = 0; m < 8; ++m) {
        int lrow0 = wr * 128 + m * 16 + g * 4;
#pragma unroll
        for (int r = 0; r < 4; ++r) {
          float v = acc[m][n][r] + bb;
          if (RELU) v = v > 0.0f ? v : 0.0f;
          smem[(lrow0 + r) * 256 + col] = f2b(v);
        }
      }
    }
    __syncthreads();
    // linear copy: 8192 chunks of 16B; wave-contiguous global stores
    ushort_t* Cb = C + (size_t)mgrp * 256 * DM + ntile * 256;
#pragma unroll
    for (int q = 0; q < 16; ++q) {
      int chunk = q * 512 + tid;        // 0..8191
      int row = chunk >> 5, co = (chunk & 31) * 8;
      bf16x8 v = *(const bf16x8*)&smem[row * 256 + co];
      *(bf16x8*)(Cb + (size_t)row * DM + co) = v;
    }
  }
}

// ---------------- combine accepted expert outputs per token ----------------
__global__ void combine_kernel(const ushort_t* __restrict__ Y, const int* __restrict__ slot,
                               float* __restrict__ out) {
  int t = blockIdx.x;
  int s0 = slot[2 * t], s1 = slot[2 * t + 1];
  int u = (s0 >= 0) + (s1 >= 0);
  if (u == 0) return;  // fallback GEMM scatter writes these rows
  int d = threadIdx.x * 4;
  float a0 = 0, a1 = 0, a2 = 0, a3 = 0;
  if (s0 >= 0) {
    ushort4 q = *(const ushort4*)(Y + (size_t)s0 * DM + d);
    a0 += b2f(q.x); a1 += b2f(q.y); a2 += b2f(q.z); a3 += b2f(q.w);
  }
  if (s1 >= 0) {
    ushort4 q = *(const ushort4*)(Y + (size_t)s1 * DM + d);
    a0 += b2f(q.x); a1 += b2f(q.y); a2 += b2f(q.z); a3 += b2f(q.w);
  }
  float inv = 1.0f / (float)u;
  float4 o = make_float4(a0 * inv, a1 * inv, a2 * inv, a3 * inv);
  *(float4*)(out + (size_t)t * DM + d) = o;
}

// ---------------- launch ----------------
extern "C" void kernel_launch(void* const* d_in, const int* in_sizes, int n_in,
                              void* d_out, int out_size, void* d_ws, size_t ws_size,
                              hipStream_t stream) {
  const float* x   = (const float*)d_in[0];
  const float* W1  = (const float*)d_in[1];
  const float* b1  = (const float*)d_in[2];
  const float* W2  = (const float*)d_in[3];
  const float* b2  = (const float*)d_in[4];
  const float* Wf1 = (const float*)d_in[5];
  const float* bf1 = (const float*)d_in[6];
  const float* Wf2 = (const float*)d_in[7];
  const float* bf2 = (const float*)d_in[8];
  const int* routes = (const int*)d_in[9];
  const int* capp   = (const int*)d_in[10];
  float* out = (float*)d_out;

  char* ws = (char*)d_ws;
  size_t off = 0;
  auto alloc = [&](size_t bytes) -> void* {
    void* p = ws + off; off += (bytes + 255) & ~255ull; return p;
  };
  ushort_t* W1b  = (ushort_t*)alloc((size_t)NEXP * DM * DM * 2);
  ushort_t* W2b  = (ushort_t*)alloc((size_t)NEXP * DM * DM * 2);
  ushort_t* Wf1b = (ushort_t*)alloc((size_t)DM * DM * 2);
  ushort_t* Wf2b = (ushort_t*)alloc((size_t)DM * DM * 2);
  ushort_t* xg   = (ushort_t*)alloc((size_t)MROWS * DM * 2);
  ushort_t* H    = (ushort_t*)alloc((size_t)MROWS * DM * 2);
  ushort_t* Y    = (ushort_t*)alloc((size_t)MROWS * DM * 2);
  ushort_t* xf   = (ushort_t*)alloc((size_t)BTOK * DM * 2);
  ushort_t* Hf   = (ushort_t*)alloc((size_t)BTOK * DM * 2);
  int* gidx   = (int*)alloc(MROWS * 4);
  int* slot   = (int*)alloc(NASSIGN * 4);
  int* counts = (int*)alloc(NEXP * 4);
  int* fbidx  = (int*)alloc(BTOK * 4);
  int* nfb    = (int*)alloc(4);

  route_cvt_kernel<<<8 + 4608, 1024, 0, stream>>>(routes, capp, gidx, slot, counts, nfb,
                                                  W1, W2, Wf1, Wf2, W1b, W2b, Wf1b, Wf2b);
  fblist_gxg_kernel<<<32 + MROWS, 256, 0, stream>>>(slot, fbidx, nfb, x, gidx, counts, xg);
  gather_xf_kernel<<<BTOK, 256, 0, stream>>>(x, fbidx, nfb, xf);
  layer_kernel<1, 0><<<GRID_L, 512, 0, stream>>>(xg, W1b, b1, H, xf, Wf1b, bf1, Hf,
                                                 nullptr, nullptr, nfb);
  layer_kernel<0, 1><<<GRID_L, 512, 0, stream>>>(H, W2b, b2, Y, Hf, Wf2b, bf2, nullptr,
                                                 out, fbidx, nfb);
  combine_kernel<<<BTOK, 256, 0, stream>>>(Y, slot, out);
}

// Round 14
// 134.286 us; speedup vs baseline: 1.5985x; 1.0091x over previous
//
#include <hip/hip_runtime.h>

// ---------------- problem constants ----------------
#define DM    1024          // d_model
#define NEXP  8             // experts
#define BTOK  8192          // tokens
#define KTOP  2             // routes per token
#define NASSIGN (BTOK*KTOP) // 16384
#define CAPC  1280          // capacity (5 * 256 -> tile-aligned)
#define MROWS (NEXP*CAPC)   // 10240 expert rows

// GEMM geometry: 256x256 tile, BK=64 (2 k-halves of 32), 8 waves (2Mx4N)
#define SLOTS_E  20                   // 5 M x 4 N expert tiles per XCD
#define SLOTS_F  16                   // fb slots per XCD (32 Mtiles x 4 N / 8)
#define SLOTS    (SLOTS_E+SLOTS_F)    // 36
#define GRID_L   (8*SLOTS)            // 288 (blocks 256+ all early-exit)

typedef unsigned short ushort_t;
typedef __attribute__((ext_vector_type(8))) __bf16 bf16x8;
typedef __attribute__((ext_vector_type(4))) float  f32x4;

__device__ __forceinline__ ushort_t f2b(float f) {  // f32 -> bf16 RNE
  union { float f; unsigned u; } a; a.f = f;
  unsigned u = a.u;
  return (ushort_t)((u + 0x7FFFu + ((u >> 16) & 1u)) >> 16);
}
__device__ __forceinline__ float b2f(ushort_t h) {
  union { unsigned u; float f; } a; a.u = ((unsigned)h) << 16;
  return a.f;
}

#define GLOAD_LDS(g, l) __builtin_amdgcn_global_load_lds( \
    (const __attribute__((address_space(1))) void*)(g),   \
    (__attribute__((address_space(3))) void*)(l), 16, 0, 0)

// ---------------- merged: routing (blocks 0..7) + weight cvt (blocks 8..) ----
__global__ void route_cvt_kernel(const int* __restrict__ routes, const int* __restrict__ capp,
                                 int* __restrict__ gidx, int* __restrict__ slot,
                                 int* __restrict__ counts, int* __restrict__ nfb,
                                 const float* __restrict__ W1, const float* __restrict__ W2,
                                 const float* __restrict__ Wf1, const float* __restrict__ Wf2,
                                 ushort_t* __restrict__ o1, ushort_t* __restrict__ o2,
                                 ushort_t* __restrict__ of1, ushort_t* __restrict__ of2) {
  const int b = blockIdx.x, t = threadIdx.x;
  if (b >= 8) {                          // weight f32 -> bf16
    const float* s; ushort_t* d; int idx;
    int c = b - 8;
    if (c < 2048)      { s = W1;  d = o1;  idx = c; }
    else if (c < 4096) { s = W2;  d = o2;  idx = c - 2048; }
    else if (c < 4352) { s = Wf1; d = of1; idx = c - 4096; }
    else               { s = Wf2; d = of2; idx = c - 4352; }
    int i = idx * 1024 + t;
    float4 v = ((const float4*)s)[i];
    ushort4 o; o.x = f2b(v.x); o.y = f2b(v.y); o.z = f2b(v.z); o.w = f2b(v.w);
    ((ushort4*)d)[i] = o;
    return;
  }
  // ---- routing: exact sequential capacity semantics (block e = expert) ----
  const int e = b;
  const int lane = t & 63, w = t >> 6;
  int cap = *capp; if (cap > CAPC) cap = CAPC;
  if (e == 0 && t == 0) *nfb = 0;
  __shared__ int wtot[16];
  int base = 0;
  for (int i0 = 0; i0 < NASSIGN; i0 += 1024) {
    int i = i0 + t;
    int r = routes[i];
    bool mine = (r == e);
    unsigned long long mask = __ballot(mine);
    int pre = __popcll(mask & ((1ull << lane) - 1ull));
    if (lane == 0) wtot[w] = __popcll(mask);
    __syncthreads();
    int tot = 0;
#pragma unroll
    for (int j = 0; j < 16; ++j) { int c = wtot[j]; if (j < w) pre += c; tot += c; }
    if (e == 0 && (unsigned)r >= NEXP) slot[i] = -1;  // defensive (never triggers)
    if (mine) {
      int pos = base + pre;
      if (pos < cap) { gidx[e * CAPC + pos] = i >> 1; slot[i] = e * CAPC + pos; }
      else slot[i] = -1;
    }
    base += tot;
    __syncthreads();
  }
  if (t == 0) counts[e] = base < cap ? base : cap;
}

// ---------------- merged: fb_list (blocks 0..31) + gather_xg (blocks 32..) ----
__global__ void fblist_gxg_kernel(const int* __restrict__ slot, int* __restrict__ fbidx,
                                  int* __restrict__ nfb,
                                  const float* __restrict__ x, const int* __restrict__ gidx,
                                  const int* __restrict__ counts, ushort_t* __restrict__ xg) {
  int b = blockIdx.x, t = threadIdx.x;
  if (b < 32) {                          // fallback token list (used==0)
    int tok = b * 256 + t;
    int u = (slot[2 * tok] >= 0) + (slot[2 * tok + 1] >= 0);
    if (u == 0) { int p = atomicAdd(nfb, 1); fbidx[p] = tok; }
    return;
  }
  int row = b - 32;                      // gather accepted rows -> xg
  int e = row / CAPC, p = row % CAPC;
  int d = t * 4;
  ushort4 o = {0, 0, 0, 0};
  if (p < counts[e]) {
    int tok = gidx[row];
    float4 v = *(const float4*)(x + (size_t)tok * DM + d);
    o.x = f2b(v.x); o.y = f2b(v.y); o.z = f2b(v.z); o.w = f2b(v.w);
  }
  *(ushort4*)(xg + (size_t)row * DM + d) = o;
}

// ---------------- gather fallback token rows -> xf (bf16), zero pad to 128 ----
__global__ void gather_xf_kernel(const float* __restrict__ x, const int* __restrict__ fbidx,
                                 const int* __restrict__ nfbp, ushort_t* __restrict__ xf) {
  int row = blockIdx.x;
  int n = *nfbp;
  int nr = (n + 127) & ~127;
  if (row >= nr) return;
  int d = threadIdx.x * 4;
  ushort4 o = {0, 0, 0, 0};
  if (row < n) {
    int tok = fbidx[row];
    float4 v = *(const float4*)(x + (size_t)tok * DM + d);
    o.x = f2b(v.x); o.y = f2b(v.y); o.z = f2b(v.z); o.w = f2b(v.w);
  }
  *(ushort4*)(xf + (size_t)row * DM + d) = o;
}

// ---------------- 256^2 8-phase layer GEMM (expert + fallback fused) ----------
// r14 = r13 with ALL sched_barrier(0) pins removed (m141 lesson: order-pinning
// defeats the compiler scheduler; m201's template does not pin).  Barriers
// keep "memory" clobbers -> LDS/global ops cannot cross; MFMA's register deps
// on ds_read results get compiler-inserted lgkmcnt waits (ds_reads are
// compiler-generated loads, so rule #18's inline-asm hazard does not apply).
// Schedule (verified correct in r13): 2 K-tiles/iter, 8 phases, counted
// vmcnt(2) at q3/q7 only; stage slots q0:B-kh1(2j+1) q1:A-kh1(2j+1)
// q2:A-kh0(2j+2) q3:B-kh0(2j+2) q4:A+B-kh1(2j+2) q6:A-kh0(2j+3)
// q7:B-kh0(2j+3); tail stages wrap (&15) as dummies.
#define BAR() asm volatile("s_barrier" ::: "memory")

template <int RELU, int FBSCAT>
__global__ __launch_bounds__(512, 2) void layer_kernel(
    const ushort_t* __restrict__ Ae, const ushort_t* __restrict__ We,
    const float* __restrict__ be, ushort_t* __restrict__ Ce,
    const ushort_t* __restrict__ Af, const ushort_t* __restrict__ Wf,
    const float* __restrict__ bfp, ushort_t* __restrict__ Cf,
    float* __restrict__ outF, const int* __restrict__ scat,
    const int* __restrict__ nfbp) {
  const int b = blockIdx.x;
  const int xcd = b & 7, s = b >> 3;
  const ushort_t* A; const ushort_t* W; const float* bias; ushort_t* C;
  int mgrp, ntile; bool isfb;
  if (s < SLOTS_E) {
    const int e = xcd;                      // expert = XCD (L2 affinity)
    mgrp = e * 5 + (s >> 2); ntile = s & 3;
    A = Ae; W = We + (size_t)e * DM * DM; bias = be + e * DM; C = Ce; isfb = false;
  } else {
    int fl = (s - SLOTS_E) * 8 + xcd;       // 0..127
    mgrp = fl >> 2; ntile = fl & 3;
    if (mgrp * 256 >= *nfbp) return;        // uniform early-exit (no barriers yet)
    A = Af; W = Wf; bias = bfp; C = Cf; isfb = true;
  }
  const int tid = threadIdx.x, lane = tid & 63, w = tid >> 6;  // w 0..7
  const int wr = w >> 2, wc = w & 3;
  __shared__ ushort_t smem[65536];          // 128KB; reused for C repack
  const size_t Abase = (size_t)mgrp * 256 * DM;
  const size_t Wbase = (size_t)ntile * 256 * DM;
  f32x4 acc[8][4] = {};

  // staging lanes (r12-proven swizzle pair): seg = 16 rows x 32k (1KB)
  const int sub  = lane >> 2;                     // row within seg
  const int slt  = lane & 3;                      // 16B k-slot
  const int gcol = (slt ^ ((sub >> 1) & 3)) * 8;  // inverse-swizzled source k-off
  // LDS elem offsets: A[buf][kh] = buf*16384 + kh*8192 ; B = 32768 + same
#define ALB(BUF, KH) ((BUF)*16384 + (KH)*8192)
#define BLB(BUF, KH) (32768 + (BUF)*16384 + (KH)*8192)
  // stage one half (16KB): wave w stages segs 2w, 2w+1 (2 loads/thread)
#define STAGEH(P, GB, T, KH, LB) do { int kt_ = (T)*64 + (KH)*32;                    \
    GLOAD_LDS(P + GB + (size_t)((w*2  )*16 + sub)*DM + kt_ + gcol, smem + (LB) + (w*2  )*512); \
    GLOAD_LDS(P + GB + (size_t)((w*2+1)*16 + sub)*DM + kt_ + gcol, smem + (LB) + (w*2+1)*512); \
  } while (0)

  const int fr = lane & 15, g = lane >> 4;
  const int rslot = (g ^ ((fr >> 1) & 3)) * 8;    // swizzled read k-off
  bf16x8 av[4], bv[4];
#define LOADFRAGS(BUF, MH, KH) do {                                                  \
    const ushort_t* pa_ = smem + ALB(BUF, KH);                                       \
    const ushort_t* pb_ = smem + BLB(BUF, KH);                                       \
    _Pragma("unroll")                                                                \
    for (int i_ = 0; i_ < 4; ++i_)                                                   \
      av[i_] = *(const bf16x8*)&pa_[(wr*128 + ((MH)*4 + i_)*16 + fr)*32 + rslot];    \
    _Pragma("unroll")                                                                \
    for (int n_ = 0; n_ < 4; ++n_)                                                   \
      bv[n_] = *(const bf16x8*)&pb_[(wc*64 + n_*16 + fr)*32 + rslot];                \
  } while (0)
#define DOMFMA(MH) do { __builtin_amdgcn_s_setprio(1);                               \
    _Pragma("unroll")                                                                \
    for (int i_ = 0; i_ < 4; ++i_)                                                   \
      _Pragma("unroll")                                                              \
      for (int n_ = 0; n_ < 4; ++n_)                                                 \
        acc[(MH)*4 + i_][n_] = __builtin_amdgcn_mfma_f32_16x16x32_bf16(              \
            av[i_], bv[n_], acc[(MH)*4 + i_][n_], 0, 0, 0);                          \
    __builtin_amdgcn_s_setprio(0); } while (0)
#define VM2() asm volatile("s_waitcnt vmcnt(2)" ::: "memory")

  // prologue: tile0 all halves + tile1 kh0 (steady-state tail of iter -1)
  STAGEH(A, Abase, 0, 0, ALB(0,0));  STAGEH(W, Wbase, 0, 0, BLB(0,0));
  STAGEH(A, Abase, 0, 1, ALB(0,1));  STAGEH(W, Wbase, 0, 1, BLB(0,1));
  STAGEH(A, Abase, 1, 0, ALB(1,0));  STAGEH(W, Wbase, 1, 0, BLB(1,0));
  asm volatile("s_waitcnt vmcnt(4)" ::: "memory");  // tile0 fully landed
  BAR();

  for (int j = 0; j < 8; ++j) {
    const int bT = 2*j + 1, cT = (2*j + 2) & 15, dT = (2*j + 3) & 15;
    // q0: (buf0, mh0, kh0)
    LOADFRAGS(0, 0, 0);
    STAGEH(W, Wbase, bT, 1, BLB(1,1));
    BAR(); DOMFMA(0); BAR();
    // q1: (buf0, mh1, kh0)
    LOADFRAGS(0, 1, 0);
    STAGEH(A, Abase, bT, 1, ALB(1,1));
    BAR(); DOMFMA(1); BAR();
    // q2: (buf0, mh0, kh1)
    LOADFRAGS(0, 0, 1);
    STAGEH(A, Abase, cT, 0, ALB(0,0));
    BAR(); DOMFMA(0); BAR();
    // q3: (buf0, mh1, kh1)  [counted vmcnt]
    VM2();
    LOADFRAGS(0, 1, 1);
    STAGEH(W, Wbase, cT, 0, BLB(0,0));
    BAR(); DOMFMA(1); BAR();
    // q4: (buf1, mh0, kh0)
    LOADFRAGS(1, 0, 0);
    STAGEH(A, Abase, cT, 1, ALB(0,1));
    STAGEH(W, Wbase, cT, 1, BLB(0,1));
    BAR(); DOMFMA(0); BAR();
    // q5: (buf1, mh1, kh0)
    LOADFRAGS(1, 1, 0);
    BAR(); DOMFMA(1); BAR();
    // q6: (buf1, mh0, kh1)
    LOADFRAGS(1, 0, 1);
    STAGEH(A, Abase, dT, 0, ALB(1,0));
    BAR(); DOMFMA(0); BAR();
    // q7: (buf1, mh1, kh1)  [counted vmcnt]
    VM2();
    LOADFRAGS(1, 1, 1);
    STAGEH(W, Wbase, dT, 0, BLB(1,0));
    BAR(); DOMFMA(1); BAR();
  }
  asm volatile("s_waitcnt vmcnt(0)" ::: "memory");  // drain dummy stages
  BAR();

  // epilogue.  C/D layout col=lane&15, row=(lane>>4)*4+reg  [m89-verified]
  if (FBSCAT && isfb) {                 // fb layer-2: f32 scatter (small)
    int nfbv = *nfbp;
#pragma unroll
    for (int n = 0; n < 4; ++n) {
      int col = ntile * 256 + wc * 64 + n * 16 + fr;
      float bb = bias[col];
#pragma unroll
      for (int m = 0; m < 8; ++m) {
        int row0 = mgrp * 256 + wr * 128 + m * 16 + g * 4;
#pragma unroll
        for (int r = 0; r < 4; ++r) {
          int row = row0 + r;
          if (row < nfbv) outF[(size_t)scat[row] * DM + col] = acc[m][n][r] + bb;
        }
      }
    }
  } else {                              // bf16 C: LDS repack + coalesced store
#pragma unroll
    for (int n = 0; n < 4; ++n) {
      int col = wc * 64 + n * 16 + fr;
      float bb = bias[ntile * 256 + col];
#pragma unroll
      for (int m = 0; m < 8; ++m) {
        int lrow0 = wr * 128 + m * 16 + g * 4;
#pragma unroll
        for (int r = 0; r < 4; ++r) {
          float v = acc[m][n][r] + bb;
          if (RELU) v = v > 0.0f ? v : 0.0f;
          smem[(lrow0 + r) * 256 + col] = f2b(v);
        }
      }
    }
    __syncthreads();
    // linear copy: 8192 chunks of 16B; wave-contiguous global stores
    ushort_t* Cb = C + (size_t)mgrp * 256 * DM + ntile * 256;
#pragma unroll
    for (int q = 0; q < 16; ++q) {
      int chunk = q * 512 + tid;        // 0..8191
      int row = chunk >> 5, co = (chunk & 31) * 8;
      bf16x8 v = *(const bf16x8*)&smem[row * 256 + co];
      *(bf16x8*)(Cb + (size_t)row * DM + co) = v;
    }
  }
}

// ---------------- combine accepted expert outputs per token ----------------
__global__ void combine_kernel(const ushort_t* __restrict__ Y, const int* __restrict__ slot,
                               float* __restrict__ out) {
  int t = blockIdx.x;
  int s0 = slot[2 * t], s1 = slot[2 * t + 1];
  int u = (s0 >= 0) + (s1 >= 0);
  if (u == 0) return;  // fallback GEMM scatter writes these rows
  int d = threadIdx.x * 4;
  float a0 = 0, a1 = 0, a2 = 0, a3 = 0;
  if (s0 >= 0) {
    ushort4 q = *(const ushort4*)(Y + (size_t)s0 * DM + d);
    a0 += b2f(q.x); a1 += b2f(q.y); a2 += b2f(q.z); a3 += b2f(q.w);
  }
  if (s1 >= 0) {
    ushort4 q = *(const ushort4*)(Y + (size_t)s1 * DM + d);
    a0 += b2f(q.x); a1 += b2f(q.y); a2 += b2f(q.z); a3 += b2f(q.w);
  }
  float inv = 1.0f / (float)u;
  float4 o = make_float4(a0 * inv, a1 * inv, a2 * inv, a3 * inv);
  *(float4*)(out + (size_t)t * DM + d) = o;
}

// ---------------- launch ----------------
extern "C" void kernel_launch(void* const* d_in, const int* in_sizes, int n_in,
                              void* d_out, int out_size, void* d_ws, size_t ws_size,
                              hipStream_t stream) {
  const float* x   = (const float*)d_in[0];
  const float* W1  = (const float*)d_in[1];
  const float* b1  = (const float*)d_in[2];
  const float* W2  = (const float*)d_in[3];
  const float* b2  = (const float*)d_in[4];
  const float* Wf1 = (const float*)d_in[5];
  const float* bf1 = (const float*)d_in[6];
  const float* Wf2 = (const float*)d_in[7];
  const float* bf2 = (const float*)d_in[8];
  const int* routes = (const int*)d_in[9];
  const int* capp   = (const int*)d_in[10];
  float* out = (float*)d_out;

  char* ws = (char*)d_ws;
  size_t off = 0;
  auto alloc = [&](size_t bytes) -> void* {
    void* p = ws + off; off += (bytes + 255) & ~255ull; return p;
  };
  ushort_t* W1b  = (ushort_t*)alloc((size_t)NEXP * DM * DM * 2);
  ushort_t* W2b  = (ushort_t*)alloc((size_t)NEXP * DM * DM * 2);
  ushort_t* Wf1b = (ushort_t*)alloc((size_t)DM * DM * 2);
  ushort_t* Wf2b = (ushort_t*)alloc((size_t)DM * DM * 2);
  ushort_t* xg   = (ushort_t*)alloc((size_t)MROWS * DM * 2);
  ushort_t* H    = (ushort_t*)alloc((size_t)MROWS * DM * 2);
  ushort_t* Y    = (ushort_t*)alloc((size_t)MROWS * DM * 2);
  ushort_t* xf   = (ushort_t*)alloc((size_t)BTOK * DM * 2);
  ushort_t* Hf   = (ushort_t*)alloc((size_t)BTOK * DM * 2);
  int* gidx   = (int*)alloc(MROWS * 4);
  int* slot   = (int*)alloc(NASSIGN * 4);
  int* counts = (int*)alloc(NEXP * 4);
  int* fbidx  = (int*)alloc(BTOK * 4);
  int* nfb    = (int*)alloc(4);

  route_cvt_kernel<<<8 + 4608, 1024, 0, stream>>>(routes, capp, gidx, slot, counts, nfb,
                                                  W1, W2, Wf1, Wf2, W1b, W2b, Wf1b, Wf2b);
  fblist_gxg_kernel<<<32 + MROWS, 256, 0, stream>>>(slot, fbidx, nfb, x, gidx, counts, xg);
  gather_xf_kernel<<<BTOK, 256, 0, stream>>>(x, fbidx, nfb, xf);
  layer_kernel<1, 0><<<GRID_L, 512, 0, stream>>>(xg, W1b, b1, H, xf, Wf1b, bf1, Hf,
                                                 nullptr, nullptr, nfb);
  layer_kernel<0, 1><<<GRID_L, 512, 0, stream>>>(H, W2b, b2, Y, Hf, Wf2b, bf2, nullptr,
                                                 out, fbidx, nfb);
  combine_kernel<<<BTOK, 256, 0, stream>>>(Y, slot, out);
}

// Round 15
// 127.912 us; speedup vs baseline: 1.6781x; 1.0498x over previous
//
#include <hip/hip_runtime.h>

// ---------------- problem constants ----------------
#define DM    1024          // d_model
#define NEXP  8             // experts
#define BTOK  8192          // tokens
#define KTOP  2             // routes per token
#define NASSIGN (BTOK*KTOP) // 16384
#define CAPC  1280          // capacity (5 * 256 -> tile-aligned)
#define MROWS (NEXP*CAPC)   // 10240 expert rows

// GEMM geometry: 256M x 128N tile, BK=32, 8 waves (4Mx2N), per-wave 64x64
#define NTILES   (DM/128)      // 8
#define SLOTS_E  (5*NTILES)    // 40 expert slots per XCD (5 Mtiles x 8 N)
#define SLOTS_F  (32*NTILES/8) // 32 fb slots per XCD
#define SLOTS    (SLOTS_E+SLOTS_F)    // 72
#define GRID_L   (8*SLOTS)            // 576

typedef unsigned short ushort_t;
typedef __attribute__((ext_vector_type(8))) __bf16 bf16x8;
typedef __attribute__((ext_vector_type(4))) float  f32x4;

__device__ __forceinline__ ushort_t f2b(float f) {  // f32 -> bf16 RNE
  union { float f; unsigned u; } a; a.f = f;
  unsigned u = a.u;
  return (ushort_t)((u + 0x7FFFu + ((u >> 16) & 1u)) >> 16);
}
__device__ __forceinline__ float b2f(ushort_t h) {
  union { unsigned u; float f; } a; a.u = ((unsigned)h) << 16;
  return a.f;
}

#define GLOAD_LDS(g, l) __builtin_amdgcn_global_load_lds( \
    (const __attribute__((address_space(1))) void*)(g),   \
    (__attribute__((address_space(3))) void*)(l), 16, 0, 0)

// ---------------- merged: routing (blocks 0..7) + weight cvt (blocks 8..) ----
__global__ void route_cvt_kernel(const int* __restrict__ routes, const int* __restrict__ capp,
                                 int* __restrict__ gidx, int* __restrict__ slot,
                                 int* __restrict__ counts, int* __restrict__ nfb,
                                 const float* __restrict__ W1, const float* __restrict__ W2,
                                 const float* __restrict__ Wf1, const float* __restrict__ Wf2,
                                 ushort_t* __restrict__ o1, ushort_t* __restrict__ o2,
                                 ushort_t* __restrict__ of1, ushort_t* __restrict__ of2) {
  const int b = blockIdx.x, t = threadIdx.x;
  if (b >= 8) {                          // weight f32 -> bf16
    const float* s; ushort_t* d; int idx;
    int c = b - 8;
    if (c < 2048)      { s = W1;  d = o1;  idx = c; }
    else if (c < 4096) { s = W2;  d = o2;  idx = c - 2048; }
    else if (c < 4352) { s = Wf1; d = of1; idx = c - 4096; }
    else               { s = Wf2; d = of2; idx = c - 4352; }
    int i = idx * 1024 + t;
    float4 v = ((const float4*)s)[i];
    ushort4 o; o.x = f2b(v.x); o.y = f2b(v.y); o.z = f2b(v.z); o.w = f2b(v.w);
    ((ushort4*)d)[i] = o;
    return;
  }
  // ---- routing: exact sequential capacity semantics (block e = expert) ----
  const int e = b;
  const int lane = t & 63, w = t >> 6;
  int cap = *capp; if (cap > CAPC) cap = CAPC;
  if (e == 0 && t == 0) *nfb = 0;
  __shared__ int wtot[16];
  int base = 0;
  for (int i0 = 0; i0 < NASSIGN; i0 += 1024) {
    int i = i0 + t;
    int r = routes[i];
    bool mine = (r == e);
    unsigned long long mask = __ballot(mine);
    int pre = __popcll(mask & ((1ull << lane) - 1ull));
    if (lane == 0) wtot[w] = __popcll(mask);
    __syncthreads();
    int tot = 0;
#pragma unroll
    for (int j = 0; j < 16; ++j) { int c = wtot[j]; if (j < w) pre += c; tot += c; }
    if (e == 0 && (unsigned)r >= NEXP) slot[i] = -1;  // defensive (never triggers)
    if (mine) {
      int pos = base + pre;
      if (pos < cap) { gidx[e * CAPC + pos] = i >> 1; slot[i] = e * CAPC + pos; }
      else slot[i] = -1;
    }
    base += tot;
    __syncthreads();
  }
  if (t == 0) counts[e] = base < cap ? base : cap;
}

// ---------------- merged: fb_list (blocks 0..31) + gather_xg (blocks 32..) ----
__global__ void fblist_gxg_kernel(const int* __restrict__ slot, int* __restrict__ fbidx,
                                  int* __restrict__ nfb,
                                  const float* __restrict__ x, const int* __restrict__ gidx,
                                  const int* __restrict__ counts, ushort_t* __restrict__ xg) {
  int b = blockIdx.x, t = threadIdx.x;
  if (b < 32) {                          // fallback token list (used==0)
    int tok = b * 256 + t;
    int u = (slot[2 * tok] >= 0) + (slot[2 * tok + 1] >= 0);
    if (u == 0) { int p = atomicAdd(nfb, 1); fbidx[p] = tok; }
    return;
  }
  int row = b - 32;                      // gather accepted rows -> xg
  int e = row / CAPC, p = row % CAPC;
  int d = t * 4;
  ushort4 o = {0, 0, 0, 0};
  if (p < counts[e]) {
    int tok = gidx[row];
    float4 v = *(const float4*)(x + (size_t)tok * DM + d);
    o.x = f2b(v.x); o.y = f2b(v.y); o.z = f2b(v.z); o.w = f2b(v.w);
  }
  *(ushort4*)(xg + (size_t)row * DM + d) = o;
}

// ---------------- gather fallback token rows -> xf (bf16), zero pad to 128 ----
__global__ void gather_xf_kernel(const float* __restrict__ x, const int* __restrict__ fbidx,
                                 const int* __restrict__ nfbp, ushort_t* __restrict__ xf) {
  int row = blockIdx.x;
  int n = *nfbp;
  int nr = (n + 127) & ~127;
  if (row >= nr) return;
  int d = threadIdx.x * 4;
  ushort4 o = {0, 0, 0, 0};
  if (row < n) {
    int tok = fbidx[row];
    float4 v = *(const float4*)(x + (size_t)tok * DM + d);
    o.x = f2b(v.x); o.y = f2b(v.y); o.z = f2b(v.z); o.w = f2b(v.w);
  }
  *(ushort4*)(xf + (size_t)row * DM + d) = o;
}

// ---------------- fused layer GEMM: expert part + fallback part ----------------
// C[m,n] = A[m,k]*W[n,k] + bias[n].  r15: 256x128 tile, BK=32, 8 waves (4Mx2N),
// per-wave 64x64 (acc[4][4] in AGPRs -- r12's VGPR=56 + 64 AGPR = 120 total
// <= 128 quantum -> 4 waves/SIMD).  Same proven r12 loop: simple 2-phase dbuf,
// ONE __syncthreads per K-step (vmcnt(0) drain = tile-ready), stage(t+1)
// right after the barrier.  48KB LDS -> 2 blocks/CU (16 waves/CU TLP kept).
// vs r12: 2x MFMA per barrier (32/wave), 1.33x fewer staged bytes per FLOP.
// 8-phase experiments (r13/r14) were 1-block/CU lockstep-bound -- abandoned.
// XCD expert affinity kept.  LDS XOR swizzle kept.  LDS-repack epilogue kept
// (done in two 128-row halves: C tile 64KB > 48KB LDS).
template <int RELU, int FBSCAT>
__global__ __launch_bounds__(512, 4) void layer_kernel(
    const ushort_t* __restrict__ Ae, const ushort_t* __restrict__ We,
    const float* __restrict__ be, ushort_t* __restrict__ Ce,
    const ushort_t* __restrict__ Af, const ushort_t* __restrict__ Wf,
    const float* __restrict__ bfp, ushort_t* __restrict__ Cf,
    float* __restrict__ outF, const int* __restrict__ scat,
    const int* __restrict__ nfbp) {
  const int b = blockIdx.x;
  const int xcd = b & 7, s = b >> 3;
  const ushort_t* A; const ushort_t* W; const float* bias; ushort_t* C;
  int mgrp, ntile; bool isfb;
  if (s < SLOTS_E) {
    const int e = xcd;                       // expert = XCD (L2 affinity)
    mgrp = e * 5 + (s >> 3); ntile = s & 7;  // N-fastest
    A = Ae; W = We + (size_t)e * DM * DM; bias = be + e * DM; C = Ce; isfb = false;
  } else {
    int fl = (s - SLOTS_E) * 8 + xcd;        // 0..255 spread over XCDs
    mgrp = fl >> 3; ntile = fl & 7;
    if (mgrp * 256 >= *nfbp) return;
    A = Af; W = Wf; bias = bfp; C = Cf; isfb = true;
  }
  const int tid = threadIdx.x, lane = tid & 63, w = tid >> 6;  // w 0..7
  const int wr = w >> 1, wc = w & 1;        // 4Mx2N wave grid
  __shared__ ushort_t smem[24576];          // 48KB: A dbuf 2x16KB, B dbuf 2x8KB
  const size_t Abase = (size_t)mgrp * 256 * DM;
  const size_t Wbase = (size_t)ntile * 128 * DM;
  f32x4 acc[4][4] = {};

  // staging: A = 16 segs of 16 rows x 32k (1KB), wave w stages segs 2w,2w+1;
  // B = 8 segs, wave w stages seg w.  3 global_load_lds per thread per K-step.
  const int sub  = lane >> 2;                     // row within 16-row seg
  const int slt  = lane & 3;                      // 16B k-slot
  const int gcol = (slt ^ ((sub >> 1) & 3)) * 8;  // inverse-swizzled source k-off
  const int ra0 = (w * 2)     * 16 + sub;
  const int ra1 = (w * 2 + 1) * 16 + sub;
  const int rbw = w * 16 + sub;

  // LDS elems: A buf0 @0, A buf1 @8192, B buf0 @16384, B buf1 @20480
#define STAGE(T, BUF) do { int kt_ = (T) * 32;                                        \
    GLOAD_LDS(A + Abase + (size_t)ra0 * DM + kt_ + gcol, smem + (BUF)*8192 + (w*2)  *512); \
    GLOAD_LDS(A + Abase + (size_t)ra1 * DM + kt_ + gcol, smem + (BUF)*8192 + (w*2+1)*512); \
    GLOAD_LDS(W + Wbase + (size_t)rbw * DM + kt_ + gcol, smem + 16384 + (BUF)*4096 + w*512); \
  } while (0)

  const int fr    = lane & 15, g = lane >> 4;
  const int rslot = (g ^ ((fr >> 1) & 3)) * 8;    // swizzled read k-off

  STAGE(0, 0);
  for (int t = 0; t < 32; ++t) {
    __syncthreads();                    // vmcnt(0) drain: tile t landed; and
                                        // buf[p^1]'s readers (iter t-1) passed
    if (t + 1 < 32) STAGE(t + 1, (t + 1) & 1);
    const ushort_t* bA = smem + (t & 1) * 8192;
    const ushort_t* bB = smem + 16384 + (t & 1) * 4096;
    bf16x8 av[4], bv[4];
#pragma unroll
    for (int m = 0; m < 4; ++m)
      av[m] = *(const bf16x8*)&bA[(wr * 64 + m * 16 + fr) * 32 + rslot];
#pragma unroll
    for (int n = 0; n < 4; ++n)
      bv[n] = *(const bf16x8*)&bB[(wc * 64 + n * 16 + fr) * 32 + rslot];
#pragma unroll
    for (int m = 0; m < 4; ++m)
#pragma unroll
      for (int n = 0; n < 4; ++n)
        acc[m][n] = __builtin_amdgcn_mfma_f32_16x16x32_bf16(av[m], bv[n], acc[m][n], 0, 0, 0);
  }
#undef STAGE

  // epilogue.  C/D layout col=lane&15, row=(lane>>4)*4+reg  [m89-verified]
  if (FBSCAT && isfb) {                 // fb layer-2: f32 scatter (small)
    int nfbv = *nfbp;
#pragma unroll
    for (int n = 0; n < 4; ++n) {
      int col = ntile * 128 + wc * 64 + n * 16 + fr;
      float bb = bias[col];
#pragma unroll
      for (int m = 0; m < 4; ++m) {
        int row0 = mgrp * 256 + wr * 64 + m * 16 + g * 4;
#pragma unroll
        for (int r = 0; r < 4; ++r) {
          int row = row0 + r;
          if (row < nfbv) outF[(size_t)scat[row] * DM + col] = acc[m][n][r] + bb;
        }
      }
    }
  } else {                              // bf16 C: LDS repack in 2 halves
    ushort_t* Cb = C + (size_t)mgrp * 256 * DM + ntile * 128;
#pragma unroll
    for (int h = 0; h < 2; ++h) {
      __syncthreads();                  // staging reads (h=0) / prior copy (h=1) done
      if ((wr >> 1) == h) {             // waves wr={2h,2h+1} own these 128 rows
#pragma unroll
        for (int n = 0; n < 4; ++n) {
          int col = wc * 64 + n * 16 + fr;
          float bb = bias[ntile * 128 + col];
#pragma unroll
          for (int m = 0; m < 4; ++m) {
            int lrow0 = (wr & 1) * 64 + m * 16 + g * 4;
#pragma unroll
            for (int r = 0; r < 4; ++r) {
              float v = acc[m][n][r] + bb;
              if (RELU) v = v > 0.0f ? v : 0.0f;
              smem[(lrow0 + r) * 128 + col] = f2b(v);
            }
          }
        }
      }
      __syncthreads();
      // copy 128x128 bf16 half-tile: 2048 chunks of 16B, 512 thr x 4
#pragma unroll
      for (int q = 0; q < 4; ++q) {
        int chunk = q * 512 + tid;      // 0..2047
        int row = chunk >> 4, co = (chunk & 15) * 8;
        bf16x8 v = *(const bf16x8*)&smem[row * 128 + co];
        *(bf16x8*)(Cb + (size_t)(h * 128 + row) * DM + co) = v;
      }
    }
  }
}

// ---------------- combine accepted expert outputs per token ----------------
__global__ void combine_kernel(const ushort_t* __restrict__ Y, const int* __restrict__ slot,
                               float* __restrict__ out) {
  int t = blockIdx.x;
  int s0 = slot[2 * t], s1 = slot[2 * t + 1];
  int u = (s0 >= 0) + (s1 >= 0);
  if (u == 0) return;  // fallback GEMM scatter writes these rows
  int d = threadIdx.x * 4;
  float a0 = 0, a1 = 0, a2 = 0, a3 = 0;
  if (s0 >= 0) {
    ushort4 q = *(const ushort4*)(Y + (size_t)s0 * DM + d);
    a0 += b2f(q.x); a1 += b2f(q.y); a2 += b2f(q.z); a3 += b2f(q.w);
  }
  if (s1 >= 0) {
    ushort4 q = *(const ushort4*)(Y + (size_t)s1 * DM + d);
    a0 += b2f(q.x); a1 += b2f(q.y); a2 += b2f(q.z); a3 += b2f(q.w);
  }
  float inv = 1.0f / (float)u;
  float4 o = make_float4(a0 * inv, a1 * inv, a2 * inv, a3 * inv);
  *(float4*)(out + (size_t)t * DM + d) = o;
}

// ---------------- launch ----------------
extern "C" void kernel_launch(void* const* d_in, const int* in_sizes, int n_in,
                              void* d_out, int out_size, void* d_ws, size_t ws_size,
                              hipStream_t stream) {
  const float* x   = (const float*)d_in[0];
  const float* W1  = (const float*)d_in[1];
  const float* b1  = (const float*)d_in[2];
  const float* W2  = (const float*)d_in[3];
  const float* b2  = (const float*)d_in[4];
  const float* Wf1 = (const float*)d_in[5];
  const float* bf1 = (const float*)d_in[6];
  const float* Wf2 = (const float*)d_in[7];
  const float* bf2 = (const float*)d_in[8];
  const int* routes = (const int*)d_in[9];
  const int* capp   = (const int*)d_in[10];
  float* out = (float*)d_out;

  char* ws = (char*)d_ws;
  size_t off = 0;
  auto alloc = [&](size_t bytes) -> void* {
    void* p = ws + off; off += (bytes + 255) & ~255ull; return p;
  };
  ushort_t* W1b  = (ushort_t*)alloc((size_t)NEXP * DM * DM * 2);
  ushort_t* W2b  = (ushort_t*)alloc((size_t)NEXP * DM * DM * 2);
  ushort_t* Wf1b = (ushort_t*)alloc((size_t)DM * DM * 2);
  ushort_t* Wf2b = (ushort_t*)alloc((size_t)DM * DM * 2);
  ushort_t* xg   = (ushort_t*)alloc((size_t)MROWS * DM * 2);
  ushort_t* H    = (ushort_t*)alloc((size_t)MROWS * DM * 2);
  ushort_t* Y    = (ushort_t*)alloc((size_t)MROWS * DM * 2);
  ushort_t* xf   = (ushort_t*)alloc((size_t)BTOK * DM * 2);
  ushort_t* Hf   = (ushort_t*)alloc((size_t)BTOK * DM * 2);
  int* gidx   = (int*)alloc(MROWS * 4);
  int* slot   = (int*)alloc(NASSIGN * 4);
  int* counts = (int*)alloc(NEXP * 4);
  int* fbidx  = (int*)alloc(BTOK * 4);
  int* nfb    = (int*)alloc(4);

  route_cvt_kernel<<<8 + 4608, 1024, 0, stream>>>(routes, capp, gidx, slot, counts, nfb,
                                                  W1, W2, Wf1, Wf2, W1b, W2b, Wf1b, Wf2b);
  fblist_gxg_kernel<<<32 + MROWS, 256, 0, stream>>>(slot, fbidx, nfb, x, gidx, counts, xg);
  gather_xf_kernel<<<BTOK, 256, 0, stream>>>(x, fbidx, nfb, xf);
  layer_kernel<1, 0><<<GRID_L, 512, 0, stream>>>(xg, W1b, b1, H, xf, Wf1b, bf1, Hf,
                                                 nullptr, nullptr, nfb);
  layer_kernel<0, 1><<<GRID_L, 512, 0, stream>>>(H, W2b, b2, Y, Hf, Wf2b, bf2, nullptr,
                                                 out, fbidx, nfb);
  combine_kernel<<<BTOK, 256, 0, stream>>>(Y, slot, out);
}